// Round 17
// baseline (203.867 us; speedup 1.0000x reference)
//
#include <hip/hip_runtime.h>
#include <hip/hip_bf16.h>

typedef __attribute__((ext_vector_type(8))) _Float16 f16x8;
typedef __attribute__((ext_vector_type(2))) _Float16 f16x2;
typedef __attribute__((ext_vector_type(8))) short short8;
typedef __attribute__((ext_vector_type(4))) short short4v;
typedef __attribute__((ext_vector_type(4))) float f32x4;

#define LDP 72   // LDS row stride (shorts) for reg-staged GEMM tiles

typedef const __attribute__((address_space(1))) unsigned int* gas_ptr;
typedef __attribute__((address_space(3))) unsigned int* las_ptr;
#define GLDS16(gp, lp) \
  __builtin_amdgcn_global_load_lds((gas_ptr)(gp), (las_ptr)(lp), 16, 0, 0)

#if __has_builtin(__builtin_amdgcn_fdot2)
#define FDOT2(a, b, c) __builtin_amdgcn_fdot2((a), (b), (c), false)
#else
__device__ __forceinline__ float FDOT2(f16x2 a, f16x2 b, float c) {
  return c + (float)a[0] * (float)b[0] + (float)a[1] * (float)b[1];
}
#endif

union h8u {
  f16x8 v;
  f16x2 h[4];
};

__device__ __forceinline__ short f2h(float f) {
  union { _Float16 h; short s; } u; u.h = (_Float16)f; return u.s;
}
__device__ __forceinline__ float h2f(short s) {
  union { short s; _Float16 h; } u; u.s = s; return (float)u.h;
}

// ---------------- weight transpose + f32->f16 ----------------
__global__ __launch_bounds__(256) void k_tw(const float* __restrict__ W,
                                            const float* __restrict__ Wo,
                                            short* __restrict__ WT,
                                            short* __restrict__ WoT) {
  int idx = blockIdx.x * 256 + threadIdx.x;
  if (idx < 3 * 512 * 128) {
    int l = idx >> 16, rem = idx & 65535;
    int c = rem >> 7, k = rem & 127;
    int h = c >> 7, o = c & 127;
    WT[idx] = f2h(W[(((l * 4 + h) * 128 + k) << 7) + o]);
  } else {
    int j = idx - 3 * 512 * 128;
    int l = j >> 16, rem = j & 65535;
    int d = rem >> 9, c = rem & 511;
    WoT[j] = f2h(Wo[((l * 512 + c) << 7) + d]);
  }
}

// ---------------- input projection ----------------
__global__ __launch_bounds__(256) void k_inproj(const float* __restrict__ nf,
                                                const float* __restrict__ Wp,
                                                const float* __restrict__ bp,
                                                short* __restrict__ xh) {
  int idx = blockIdx.x * 256 + threadIdx.x;
  int bn = idx >> 7, d = idx & 127;
  float acc = bp[d];
  const float* nr = nf + bn * 7;
#pragma unroll
  for (int i = 0; i < 7; ++i) acc += nr[i] * Wp[(i << 7) + d];
  xh[idx] = f2h(acc);
}

// ---------------- head projection + fused s1/s2 ----------------
__global__ __launch_bounds__(256) void k_gemm_h(const short* __restrict__ xh,
                                                const short* __restrict__ WT,
                                                short* __restrict__ hT,
                                                const float* __restrict__ a1,
                                                const float* __restrict__ a2,
                                                float* __restrict__ s1g,
                                                float* __restrict__ s2g) {
  __shared__ __align__(16) short As[128 * LDP];
  __shared__ __align__(16) short Bs[128 * LDP];
  __shared__ float sred[2][2][128];
  const int t = threadIdx.x;
  const int bn0 = blockIdx.x << 7;
  const int head = blockIdx.y;
  const int c0 = head << 7;
  const int w = t >> 6, lane = t & 63, lr = lane & 15, lq = lane >> 4;
  const int wr = w >> 1, wc = w & 1;
  f32x4 acc[4][4] = {};
  for (int k0 = 0; k0 < 128; k0 += 64) {
    const int row = t >> 1, half = (t & 1) << 5;
    {
      const short* sa = xh + ((bn0 + row) << 7) + k0 + half;
      short* da = As + row * LDP + half;
      *(short8*)(da) = *(const short8*)(sa);
      *(short8*)(da + 8) = *(const short8*)(sa + 8);
      *(short8*)(da + 16) = *(const short8*)(sa + 16);
      *(short8*)(da + 24) = *(const short8*)(sa + 24);
      const short* sb = WT + ((c0 + row) << 7) + k0 + half;
      short* db = Bs + row * LDP + half;
      *(short8*)(db) = *(const short8*)(sb);
      *(short8*)(db + 8) = *(const short8*)(sb + 8);
      *(short8*)(db + 16) = *(const short8*)(sb + 16);
      *(short8*)(db + 24) = *(const short8*)(sb + 24);
    }
    __syncthreads();
#pragma unroll
    for (int kk = 0; kk < 2; ++kk) {
      f16x8 a[4], b[4];
#pragma unroll
      for (int m = 0; m < 4; ++m)
        a[m] = *(const f16x8*)(As + (wr * 64 + m * 16 + lr) * LDP + (kk << 5) + (lq << 3));
#pragma unroll
      for (int n = 0; n < 4; ++n)
        b[n] = *(const f16x8*)(Bs + (wc * 64 + n * 16 + lr) * LDP + (kk << 5) + (lq << 3));
#pragma unroll
      for (int m = 0; m < 4; ++m)
#pragma unroll
        for (int n = 0; n < 4; ++n)
          acc[m][n] = __builtin_amdgcn_mfma_f32_16x16x32_f16(a[m], b[n], acc[m][n], 0, 0, 0);
    }
    __syncthreads();
  }
  const int b = bn0 >> 10;
  const int nb = bn0 & 1023;
  float a1v[4], a2v[4];
#pragma unroll
  for (int n = 0; n < 4; ++n) {
    int d = wc * 64 + n * 16 + lr;
    a1v[n] = a1[(head << 7) + d];
    a2v[n] = a2[(head << 7) + d];
  }
#pragma unroll
  for (int m = 0; m < 4; ++m)
#pragma unroll
    for (int r = 0; r < 4; ++r) {
      float v1 = 0.f, v2 = 0.f;
#pragma unroll
      for (int n = 0; n < 4; ++n) {
        v1 += acc[m][n][r] * a1v[n];
        v2 += acc[m][n][r] * a2v[n];
      }
#pragma unroll
      for (int off = 1; off < 16; off <<= 1) {
        v1 += __shfl_xor(v1, off);
        v2 += __shfl_xor(v2, off);
      }
      if (lr == 0) {
        int row = wr * 64 + m * 16 + (lq << 2) + r;
        sred[wc][0][row] = v1;
        sred[wc][1][row] = v2;
      }
    }
#pragma unroll
  for (int m = 0; m < 4; ++m) {
    int nrow = nb + wr * 64 + m * 16 + (lq << 2);
#pragma unroll
    for (int n = 0; n < 4; ++n) {
      int d = wc * 64 + n * 16 + lr;
      long base = ((long)((((b << 2) + head) << 7) + d) << 10) + nrow;
      short4v v;
      v[0] = f2h(acc[m][n][0]); v[1] = f2h(acc[m][n][1]);
      v[2] = f2h(acc[m][n][2]); v[3] = f2h(acc[m][n][3]);
      *(short4v*)(hT + base) = v;
    }
  }
  __syncthreads();
  {
    const int bh_ = (b << 2) + head;
    if (t < 128)
      s1g[(bh_ << 10) + nb + t] = sred[0][0][t] + sred[1][0][t];
    else
      s2g[(bh_ << 10) + nb + (t - 128)] = sred[0][1][t - 128] + sred[1][1][t - 128];
  }
}

// ---------------- tiny: s2 -> max, E=exp(s2-max) f16, F=exp(.2(s2-max)) f16 ----
__global__ __launch_bounds__(256) void k_ef(const float* __restrict__ s2g,
                                            float* __restrict__ s2m,
                                            short* __restrict__ Eh,
                                            short* __restrict__ Fh) {
  const int bh = blockIdx.x, t = threadIdx.x;
  __shared__ float red[4];
  f32x4 v = *(const f32x4*)&s2g[(bh << 10) + (t << 2)];
  float mx = fmaxf(fmaxf(v[0], v[1]), fmaxf(v[2], v[3]));
#pragma unroll
  for (int off = 1; off < 64; off <<= 1) mx = fmaxf(mx, __shfl_xor(mx, off));
  if ((t & 63) == 0) red[t >> 6] = mx;
  __syncthreads();
  const float smax = fmaxf(fmaxf(red[0], red[1]), fmaxf(red[2], red[3]));
  if (t == 0) s2m[bh] = smax;
  short4v e, f;
#pragma unroll
  for (int q = 0; q < 4; ++q) {
    e[q] = f2h(__expf(v[q] - smax));
    f[q] = f2h(__expf(0.2f * (v[q] - smax)));
  }
  *(short4v*)&Eh[(bh << 10) + (t << 2)] = e;
  *(short4v*)&Fh[(bh << 10) + (t << 2)] = f;
}

// ---------------- attention ----------------
// grid (64 bh, 8 it), 512 thr = 8 waves -> 2 blocks/CU (52 KB), 16 waves/CU.
// 128-row tiles; waves split 2x4: wm in {0,1} owns 64 rows (m=4), wn in
// {0..3} owns 32 d (n=2) -> per-wave ds_read_b128 per tile = 4 (1/4 of r7),
// halving total LDS traffic. 3-buffer pipeline, prefetch distance 2, counted
// s_waitcnt vmcnt(4) (2 glds/wave/stage), raw s_barrier. Diag: j-tile
// (it<<1)+wm (wave-uniform), kk half = m>>1 (compile-time).
__global__ __launch_bounds__(512) void k_attn(const short* __restrict__ hT,
                                              const float* __restrict__ s1,
                                              const short* __restrict__ Eh,
                                              const short* __restrict__ Fh,
                                              const float* __restrict__ s2max,
                                              short* __restrict__ attn) {
  __shared__ __align__(16) short Hs[3][128 * 64];
  __shared__ __align__(16) _Float16 Esh[1024];
  __shared__ __align__(16) _Float16 Fsh[1024];
  const int bh = blockIdx.x, it = blockIdx.y;
  const int i0 = it << 7;
  const int t = threadIdx.x;
  const int w = t >> 6, lane = t & 63, lr = lane & 15, lq = lane >> 4;
  const int wm = w & 1, wn = w >> 1;

  const short* hTb = hT + ((long)bh << 17);
  // stage: wave w covers d-rows [w*16, w*16+16); 16B chunk pre-swizzled
  const int grow = (w << 4) + (lane >> 3);
  const int gcol = ((lane & 7) ^ (lane >> 3)) << 3;
  const short* gsrc = hTb + ((long)grow << 10) + gcol;

#define STAGE(buf, J0)                                             \
  do {                                                             \
    short* ldsb = &Hs[buf][(w << 4) << 6];                         \
    GLDS16(gsrc + (J0), ldsb);                                     \
    GLDS16(gsrc + ((long)8 << 10) + (J0), ldsb + (8 << 6));        \
  } while (0)

  STAGE(0, 0);
  STAGE(1, 64);
  if (t < 256) {
    *(short4v*)&Esh[t << 2] = *(const short4v*)&Eh[(bh << 10) + (t << 2)];
    *(short4v*)&Fsh[t << 2] = *(const short4v*)&Fh[(bh << 10) + (t << 2)];
  }

  const float smax = s2max[bh];
  f16x8 Ai8[4], Bi8[4], dmask[4];
  const f16x2 one2 = {(_Float16)1.f, (_Float16)1.f};
  float dsum[4] = {0.f, 0.f, 0.f, 0.f};
#pragma unroll
  for (int m = 0; m < 4; ++m) {
    const int rblk = (wm << 6) + (m << 4) + lr;   // row within 128-row block
    float s1v = s1[(bh << 10) + i0 + rblk];
    float x = s1v + smax;
    float mi = fmaxf(x, 0.2f * x);  // upper bound of row max (lrelu monotone)
    _Float16 A_ = (_Float16)__expf(x - mi);
    _Float16 B_ = (_Float16)__expf(0.2f * x - mi);
#pragma unroll
    for (int e = 0; e < 8; ++e) { Ai8[m][e] = A_; Bi8[m][e] = B_; }
    const int lqz = ((m << 1) + (lr >> 3)) & 3, ez = lr & 7;
#pragma unroll
    for (int e = 0; e < 8; ++e)
      dmask[m][e] = (lq == lqz && e == ez) ? (_Float16)0.f : (_Float16)1.f;
  }
  const int jtd = (it << 1) + wm;  // wave-uniform diagonal j-tile
  f32x4 acc[4][2] = {};
  __syncthreads();  // prologue: bufs 0,1 + E/F resident (full drain, once)

#define TILE(buf, jt, DIAG)                                                    \
  do {                                                                         \
    _Pragma("unroll") for (int kk = 0; kk < 2; ++kk) {                         \
      const int ebase = ((jt) << 6) + (kk << 5) + (lq << 3);                   \
      f16x8 ev8 = *(const f16x8*)&Esh[ebase];                                  \
      f16x8 fv8 = *(const f16x8*)&Fsh[ebase];                                  \
      f16x8 bf[2];                                                             \
      _Pragma("unroll") for (int n = 0; n < 2; ++n) {                          \
        const int r_ = (wn << 5) + (n << 4) + lr;                              \
        const int slot_ = ((kk << 2) + lq) ^ (r_ & 7);                         \
        bf[n] = *(const f16x8*)(&Hs[buf][(r_ << 6) + (slot_ << 3)]);           \
      }                                                                        \
      f16x8 af[4];                                                             \
      _Pragma("unroll") for (int m = 0; m < 4; ++m) {                          \
        f16x8 pm = __builtin_elementwise_max(Ai8[m] * ev8, Bi8[m] * fv8);      \
        if ((DIAG) && kk == (m >> 1)) pm = pm * dmask[m];                      \
        af[m] = pm;                                                            \
        h8u u_; u_.v = pm;                                                     \
        _Pragma("unroll") for (int p = 0; p < 4; ++p)                          \
            dsum[m] = FDOT2(u_.h[p], one2, dsum[m]);                           \
      }                                                                        \
      _Pragma("unroll") for (int m = 0; m < 4; ++m)                            \
        _Pragma("unroll") for (int n = 0; n < 2; ++n)                          \
            acc[m][n] = __builtin_amdgcn_mfma_f32_16x16x32_f16(                \
                af[m], bf[n], acc[m][n], 0, 0, 0);                             \
    }                                                                          \
  } while (0)

  int cur = 0;
#pragma unroll 1
  for (int jt = 0; jt < 16; ++jt) {
    if (jt < 14) {
      STAGE((cur == 0 ? 2 : cur - 1), (jt + 2) << 6);  // (jt+2)%3
      asm volatile("s_waitcnt vmcnt(4)" ::: "memory");  // tile jt's 2 done
    } else if (jt == 14) {
      asm volatile("s_waitcnt vmcnt(2)" ::: "memory");
    } else {
      asm volatile("s_waitcnt vmcnt(0)" ::: "memory");
    }
    __builtin_amdgcn_s_barrier();   // all waves: buf[cur] fully staged
    __builtin_amdgcn_s_setprio(1);
    TILE(cur, jt, jt == jtd);
    __builtin_amdgcn_s_setprio(0);
    __builtin_amdgcn_s_barrier();   // all waves done reading buf[cur]
    cur = (cur == 2) ? 0 : cur + 1;
  }

  const int b = bh >> 2, head = bh & 3;
#pragma unroll
  for (int m = 0; m < 4; ++m) {
    float s = dsum[m];
    s += __shfl_xor(s, 16);
    s += __shfl_xor(s, 32);  // all lq-replica lanes hold the row sum
    float rs = 1.f / s;
    f32x4 d4;
#pragma unroll
    for (int q = 0; q < 4; ++q)
      d4[q] = __shfl(rs, (lane & 48) | ((lq << 2) + q));
    int irow = i0 + (wm << 6) + (m << 4) + (lq << 2);
#pragma unroll
    for (int n = 0; n < 2; ++n) {
      int d = (wn << 5) + (n << 4) + lr;
      long base = ((long)((b << 10) + irow) << 9) + (head << 7) + d;
      attn[base] = f2h(acc[m][n][0] * d4[0]);
      attn[base + 512] = f2h(acc[m][n][1] * d4[1]);
      attn[base + 1024] = f2h(acc[m][n][2] * d4[2]);
      attn[base + 1536] = f2h(acc[m][n][3] * d4[3]);
    }
  }
#undef STAGE
#undef TILE
}

// ---------------- out-proj + bias (+residual) + LN (+relu) ----------------
// 32-row blocks, grid 512 (2 blocks/CU). Wave owns 16 rows x 64 cols; LN via
// cross-wave LDS partial-sum exchange.
template <int HAS_RES, int DO_RELU, int WRITE_OUT>
__global__ __launch_bounds__(256) void k_outproj(const short* __restrict__ attn,
                                                 const short* __restrict__ WoT,
                                                 const float* __restrict__ bo,
                                                 const float* __restrict__ gamma,
                                                 const float* __restrict__ beta,
                                                 float* __restrict__ xf,
                                                 short* __restrict__ xh,
                                                 float* __restrict__ outp) {
  __shared__ __align__(16) short As[32 * LDP];
  __shared__ __align__(16) short Bs[128 * LDP];
  __shared__ float sredS[2][32], sredQ[2][32];
  const int t = threadIdx.x;
  const int bn0 = blockIdx.x << 5;
  const int w = t >> 6, lane = t & 63, lr = lane & 15, lq = lane >> 4;
  const int wm = w & 1, wn = w >> 1;
  f32x4 acc[4] = {};
  const int rowA = t >> 3, chA = (t & 7) << 3;
  const int rowB = t >> 1, chB = (t & 1) << 5;
  for (int k0 = 0; k0 < 512; k0 += 64) {
    {
      const short* sa = attn + ((long)(bn0 + rowA) << 9) + k0 + chA;
      *(short8*)(As + rowA * LDP + chA) = *(const short8*)(sa);
      const short* sb = WoT + (rowB << 9) + k0 + chB;
      short* db = Bs + rowB * LDP + chB;
      *(short8*)(db) = *(const short8*)(sb);
      *(short8*)(db + 8) = *(const short8*)(sb + 8);
      *(short8*)(db + 16) = *(const short8*)(sb + 16);
      *(short8*)(db + 24) = *(const short8*)(sb + 24);
    }
    __syncthreads();
#pragma unroll
    for (int kk = 0; kk < 2; ++kk) {
      f16x8 a = *(const f16x8*)(As + ((wm << 4) + lr) * LDP + (kk << 5) + (lq << 3));
#pragma unroll
      for (int nn = 0; nn < 4; ++nn) {
        f16x8 b = *(const f16x8*)(Bs + ((wn << 6) + (nn << 4) + lr) * LDP + (kk << 5) + (lq << 3));
        acc[nn] = __builtin_amdgcn_mfma_f32_16x16x32_f16(a, b, acc[nn], 0, 0, 0);
      }
    }
    __syncthreads();
  }
  float v[4][4], gam[4], bet[4];
#pragma unroll
  for (int nn = 0; nn < 4; ++nn) {
    int d = (wn << 6) + (nn << 4) + lr;
    float bv = bo[d];
    gam[nn] = gamma[d];
    bet[nn] = beta[d];
#pragma unroll
    for (int r = 0; r < 4; ++r) {
      float x = acc[nn][r] + bv;
      if (HAS_RES) x += xf[((bn0 + (wm << 4) + (lq << 2) + r) << 7) + d];
      v[nn][r] = x;
    }
  }
#pragma unroll
  for (int r = 0; r < 4; ++r) {
    float s = 0.f, q = 0.f;
#pragma unroll
    for (int nn = 0; nn < 4; ++nn) { s += v[nn][r]; q += v[nn][r] * v[nn][r]; }
#pragma unroll
    for (int mk = 1; mk < 16; mk <<= 1) { s += __shfl_xor(s, mk); q += __shfl_xor(q, mk); }
    if (lr == 0) {
      int row = (wm << 4) + (lq << 2) + r;
      sredS[wn][row] = s;
      sredQ[wn][row] = q;
    }
  }
  __syncthreads();
#pragma unroll
  for (int r = 0; r < 4; ++r) {
    int rloc = (wm << 4) + (lq << 2) + r;
    float S = sredS[0][rloc] + sredS[1][rloc];
    float Q = sredQ[0][rloc] + sredQ[1][rloc];
    float mean = S * 0.0078125f;
    float var = Q * 0.0078125f - mean * mean;
    float rstd = rsqrtf(var + 1e-5f);
    int row = bn0 + rloc;
#pragma unroll
    for (int nn = 0; nn < 4; ++nn) {
      int d = (wn << 6) + (nn << 4) + lr;
      float o = (v[nn][r] - mean) * rstd * gam[nn] + bet[nn];
      if (DO_RELU) o = fmaxf(o, 0.f);
      if (WRITE_OUT) {
        outp[(row << 7) + d] = o;
      } else {
        xh[(row << 7) + d] = f2h(o);
        xf[(row << 7) + d] = o;
      }
    }
  }
}

extern "C" void kernel_launch(void* const* d_in, const int* in_sizes, int n_in,
                              void* d_out, int out_size, void* d_ws, size_t ws_size,
                              hipStream_t stream) {
  const float* nf = (const float*)d_in[0];
  const float* Wp = (const float*)d_in[1];
  const float* bp = (const float*)d_in[2];
  const float* W = (const float*)d_in[3];
  const float* a1 = (const float*)d_in[4];
  const float* a2 = (const float*)d_in[5];
  const float* Wo = (const float*)d_in[6];
  const float* bo = (const float*)d_in[7];
  const float* gamma = (const float*)d_in[8];
  const float* beta = (const float*)d_in[9];
  float* outp = (float*)d_out;

  char* ws = (char*)d_ws;
  short* xh = (short*)(ws);                                    // 4 MB
  float* xf = (float*)(ws + (4ll << 20));                      // 8 MB
  short* hT = (short*)(ws + (12ll << 20));                     // 16 MB
  short* attn = (short*)(ws + (28ll << 20));                   // 16 MB
  float* s1 = (float*)(ws + (44ll << 20));                     // 256 KB
  float* s2g = (float*)(ws + (44ll << 20) + (256ll << 10));    // 256 KB
  short* Eh = (short*)(ws + (44ll << 20) + (512ll << 10));     // 128 KB
  short* Fh = (short*)(ws + (44ll << 20) + (640ll << 10));     // 128 KB
  float* s2m = (float*)(ws + (44ll << 20) + (768ll << 10));    // 1 KB
  short* WT = (short*)(ws + (45ll << 20));                     // 384 KB
  short* WoT = (short*)(ws + (45ll << 20) + 393216);           // 384 KB

  k_tw<<<1536, 256, 0, stream>>>(W, Wo, WT, WoT);
  k_inproj<<<8192, 256, 0, stream>>>(nf, Wp, bp, xh);
  for (int l = 0; l < 3; ++l) {
    k_gemm_h<<<dim3(128, 4), 256, 0, stream>>>(xh, WT + l * 65536, hT,
                                               a1 + l * 512, a2 + l * 512, s1, s2g);
    k_ef<<<64, 256, 0, stream>>>(s2g, s2m, Eh, Fh);
    k_attn<<<dim3(64, 8), 512, 0, stream>>>(hT, s1, Eh, Fh, s2m, attn);
    if (l == 0)
      k_outproj<0, 1, 0><<<512, 256, 0, stream>>>(attn, WoT + l * 65536, bo + l * 128,
                                                  gamma + l * 128, beta + l * 128, xf, xh, outp);
    else if (l == 1)
      k_outproj<1, 1, 0><<<512, 256, 0, stream>>>(attn, WoT + l * 65536, bo + l * 128,
                                                  gamma + l * 128, beta + l * 128, xf, xh, outp);
    else
      k_outproj<1, 0, 1><<<512, 256, 0, stream>>>(attn, WoT + l * 65536, bo + l * 128,
                                                  gamma + l * 128, beta + l * 128, xf, xh, outp);
  }
}

// Round 18
// 164.092 us; speedup vs baseline: 1.2424x; 1.2424x over previous
//
#include <hip/hip_runtime.h>
#include <hip/hip_bf16.h>

typedef __attribute__((ext_vector_type(8))) _Float16 f16x8;
typedef __attribute__((ext_vector_type(2))) _Float16 f16x2;
typedef __attribute__((ext_vector_type(8))) short short8;
typedef __attribute__((ext_vector_type(4))) short short4v;
typedef __attribute__((ext_vector_type(4))) float f32x4;

#define LDP 72   // LDS row stride (shorts) for reg-staged GEMM tiles

typedef const __attribute__((address_space(1))) unsigned int* gas_ptr;
typedef __attribute__((address_space(3))) unsigned int* las_ptr;
#define GLDS16(gp, lp) \
  __builtin_amdgcn_global_load_lds((gas_ptr)(gp), (las_ptr)(lp), 16, 0, 0)

#if __has_builtin(__builtin_amdgcn_fdot2)
#define FDOT2(a, b, c) __builtin_amdgcn_fdot2((a), (b), (c), false)
#else
__device__ __forceinline__ float FDOT2(f16x2 a, f16x2 b, float c) {
  return c + (float)a[0] * (float)b[0] + (float)a[1] * (float)b[1];
}
#endif

union h8u {
  f16x8 v;
  f16x2 h[4];
};

__device__ __forceinline__ short f2h(float f) {
  union { _Float16 h; short s; } u; u.h = (_Float16)f; return u.s;
}
__device__ __forceinline__ float h2f(short s) {
  union { short s; _Float16 h; } u; u.s = s; return (float)u.h;
}

// ---------------- weight transpose + f32->f16 ----------------
__global__ __launch_bounds__(256) void k_tw(const float* __restrict__ W,
                                            const float* __restrict__ Wo,
                                            short* __restrict__ WT,
                                            short* __restrict__ WoT) {
  int idx = blockIdx.x * 256 + threadIdx.x;
  if (idx < 3 * 512 * 128) {
    int l = idx >> 16, rem = idx & 65535;
    int c = rem >> 7, k = rem & 127;
    int h = c >> 7, o = c & 127;
    WT[idx] = f2h(W[(((l * 4 + h) * 128 + k) << 7) + o]);
  } else {
    int j = idx - 3 * 512 * 128;
    int l = j >> 16, rem = j & 65535;
    int d = rem >> 9, c = rem & 511;
    WoT[j] = f2h(Wo[((l * 512 + c) << 7) + d]);
  }
}

// ---------------- input projection ----------------
__global__ __launch_bounds__(256) void k_inproj(const float* __restrict__ nf,
                                                const float* __restrict__ Wp,
                                                const float* __restrict__ bp,
                                                short* __restrict__ xh) {
  int idx = blockIdx.x * 256 + threadIdx.x;
  int bn = idx >> 7, d = idx & 127;
  float acc = bp[d];
  const float* nr = nf + bn * 7;
#pragma unroll
  for (int i = 0; i < 7; ++i) acc += nr[i] * Wp[(i << 7) + d];
  xh[idx] = f2h(acc);
}

// ---------------- head projection + fused s1/s2 ----------------
__global__ __launch_bounds__(256) void k_gemm_h(const short* __restrict__ xh,
                                                const short* __restrict__ WT,
                                                short* __restrict__ hT,
                                                const float* __restrict__ a1,
                                                const float* __restrict__ a2,
                                                float* __restrict__ s1g,
                                                float* __restrict__ s2g) {
  __shared__ __align__(16) short As[128 * LDP];
  __shared__ __align__(16) short Bs[128 * LDP];
  __shared__ float sred[2][2][128];
  const int t = threadIdx.x;
  const int bn0 = blockIdx.x << 7;
  const int head = blockIdx.y;
  const int c0 = head << 7;
  const int w = t >> 6, lane = t & 63, lr = lane & 15, lq = lane >> 4;
  const int wr = w >> 1, wc = w & 1;
  f32x4 acc[4][4] = {};
  for (int k0 = 0; k0 < 128; k0 += 64) {
    const int row = t >> 1, half = (t & 1) << 5;
    {
      const short* sa = xh + ((bn0 + row) << 7) + k0 + half;
      short* da = As + row * LDP + half;
      *(short8*)(da) = *(const short8*)(sa);
      *(short8*)(da + 8) = *(const short8*)(sa + 8);
      *(short8*)(da + 16) = *(const short8*)(sa + 16);
      *(short8*)(da + 24) = *(const short8*)(sa + 24);
      const short* sb = WT + ((c0 + row) << 7) + k0 + half;
      short* db = Bs + row * LDP + half;
      *(short8*)(db) = *(const short8*)(sb);
      *(short8*)(db + 8) = *(const short8*)(sb + 8);
      *(short8*)(db + 16) = *(const short8*)(sb + 16);
      *(short8*)(db + 24) = *(const short8*)(sb + 24);
    }
    __syncthreads();
#pragma unroll
    for (int kk = 0; kk < 2; ++kk) {
      f16x8 a[4], b[4];
#pragma unroll
      for (int m = 0; m < 4; ++m)
        a[m] = *(const f16x8*)(As + (wr * 64 + m * 16 + lr) * LDP + (kk << 5) + (lq << 3));
#pragma unroll
      for (int n = 0; n < 4; ++n)
        b[n] = *(const f16x8*)(Bs + (wc * 64 + n * 16 + lr) * LDP + (kk << 5) + (lq << 3));
#pragma unroll
      for (int m = 0; m < 4; ++m)
#pragma unroll
        for (int n = 0; n < 4; ++n)
          acc[m][n] = __builtin_amdgcn_mfma_f32_16x16x32_f16(a[m], b[n], acc[m][n], 0, 0, 0);
    }
    __syncthreads();
  }
  const int b = bn0 >> 10;
  const int nb = bn0 & 1023;
  float a1v[4], a2v[4];
#pragma unroll
  for (int n = 0; n < 4; ++n) {
    int d = wc * 64 + n * 16 + lr;
    a1v[n] = a1[(head << 7) + d];
    a2v[n] = a2[(head << 7) + d];
  }
#pragma unroll
  for (int m = 0; m < 4; ++m)
#pragma unroll
    for (int r = 0; r < 4; ++r) {
      float v1 = 0.f, v2 = 0.f;
#pragma unroll
      for (int n = 0; n < 4; ++n) {
        v1 += acc[m][n][r] * a1v[n];
        v2 += acc[m][n][r] * a2v[n];
      }
#pragma unroll
      for (int off = 1; off < 16; off <<= 1) {
        v1 += __shfl_xor(v1, off);
        v2 += __shfl_xor(v2, off);
      }
      if (lr == 0) {
        int row = wr * 64 + m * 16 + (lq << 2) + r;
        sred[wc][0][row] = v1;
        sred[wc][1][row] = v2;
      }
    }
#pragma unroll
  for (int m = 0; m < 4; ++m) {
    int nrow = nb + wr * 64 + m * 16 + (lq << 2);
#pragma unroll
    for (int n = 0; n < 4; ++n) {
      int d = wc * 64 + n * 16 + lr;
      long base = ((long)((((b << 2) + head) << 7) + d) << 10) + nrow;
      short4v v;
      v[0] = f2h(acc[m][n][0]); v[1] = f2h(acc[m][n][1]);
      v[2] = f2h(acc[m][n][2]); v[3] = f2h(acc[m][n][3]);
      *(short4v*)(hT + base) = v;
    }
  }
  __syncthreads();
  {
    const int bh_ = (b << 2) + head;
    if (t < 128)
      s1g[(bh_ << 10) + nb + t] = sred[0][0][t] + sred[1][0][t];
    else
      s2g[(bh_ << 10) + nb + (t - 128)] = sred[0][1][t - 128] + sred[1][1][t - 128];
  }
}

// ---------------- tiny: s2 -> max, E=exp(s2-max) f16, F=exp(.2(s2-max)) f16 ----
__global__ __launch_bounds__(256) void k_ef(const float* __restrict__ s2g,
                                            float* __restrict__ s2m,
                                            short* __restrict__ Eh,
                                            short* __restrict__ Fh) {
  const int bh = blockIdx.x, t = threadIdx.x;
  __shared__ float red[4];
  f32x4 v = *(const f32x4*)&s2g[(bh << 10) + (t << 2)];
  float mx = fmaxf(fmaxf(v[0], v[1]), fmaxf(v[2], v[3]));
#pragma unroll
  for (int off = 1; off < 64; off <<= 1) mx = fmaxf(mx, __shfl_xor(mx, off));
  if ((t & 63) == 0) red[t >> 6] = mx;
  __syncthreads();
  const float smax = fmaxf(fmaxf(red[0], red[1]), fmaxf(red[2], red[3]));
  if (t == 0) s2m[bh] = smax;
  short4v e, f;
#pragma unroll
  for (int q = 0; q < 4; ++q) {
    e[q] = f2h(__expf(v[q] - smax));
    f[q] = f2h(__expf(0.2f * (v[q] - smax)));
  }
  *(short4v*)&Eh[(bh << 10) + (t << 2)] = e;
  *(short4v*)&Fh[(bh << 10) + (t << 2)] = f;
}

// ---------------- attention ----------------
// grid (64 bh, 8 it). Wave owns 32-row strip (m=2) x full 128 d (n=8).
// 3 LDS buffers, prefetch distance 2, counted s_waitcnt vmcnt(8) (never 0
// in steady state), raw s_barrier. Best-measured configuration (163.8 us).
__global__ __launch_bounds__(256) void k_attn(const short* __restrict__ hT,
                                              const float* __restrict__ s1,
                                              const short* __restrict__ Eh,
                                              const short* __restrict__ Fh,
                                              const float* __restrict__ s2max,
                                              short* __restrict__ attn) {
  __shared__ __align__(16) short Hs[3][128 * 64];
  __shared__ __align__(16) _Float16 Esh[1024];
  __shared__ __align__(16) _Float16 Fsh[1024];
  const int bh = blockIdx.x, it = blockIdx.y;
  const int i0 = it << 7;
  const int t = threadIdx.x;
  const int w = t >> 6, lane = t & 63, lr = lane & 15, lq = lane >> 4;

  const short* hTb = hT + ((long)bh << 17);
  const int grow = (w << 5) + (lane >> 3);
  const int gcol = ((lane & 7) ^ (lane >> 3)) << 3;
  const short* gsrc = hTb + ((long)grow << 10) + gcol;

#define STAGE(buf, J0)                                             \
  do {                                                             \
    short* ldsb = &Hs[buf][(w << 5) << 6];                         \
    _Pragma("unroll") for (int i_ = 0; i_ < 4; ++i_)               \
        GLDS16(gsrc + ((long)(i_ << 3) << 10) + (J0),              \
               ldsb + ((i_ << 3) << 6));                           \
  } while (0)

  STAGE(0, 0);
  STAGE(1, 64);
  *(short4v*)&Esh[t << 2] = *(const short4v*)&Eh[(bh << 10) + (t << 2)];
  *(short4v*)&Fsh[t << 2] = *(const short4v*)&Fh[(bh << 10) + (t << 2)];

  const float smax = s2max[bh];
  f16x8 Ai8[2], Bi8[2];
  const f16x2 one2 = {(_Float16)1.f, (_Float16)1.f};
  f16x8 dmask[2];
  float dsum[2] = {0.f, 0.f};
#pragma unroll
  for (int m = 0; m < 2; ++m) {
    const int rblk = (w << 5) + (m << 4) + lr;
    float s1v = s1[(bh << 10) + i0 + rblk];
    float x = s1v + smax;
    float mi = fmaxf(x, 0.2f * x);  // upper bound of row max (lrelu monotone)
    _Float16 A_ = (_Float16)__expf(x - mi);
    _Float16 B_ = (_Float16)__expf(0.2f * x - mi);
#pragma unroll
    for (int e = 0; e < 8; ++e) { Ai8[m][e] = A_; Bi8[m][e] = B_; }
    const int lqz = ((m << 1) + (lr >> 3)) & 3, ez = lr & 7;
#pragma unroll
    for (int e = 0; e < 8; ++e)
      dmask[m][e] = (lq == lqz && e == ez) ? (_Float16)0.f : (_Float16)1.f;
  }
  const int jtd = (it << 1) + (w >> 1);  // wave-uniform diagonal j-tile
  const int kkd = w & 1;                 // wave-uniform diag k-half
  f32x4 acc[2][8] = {};
  __syncthreads();  // prologue: bufs 0,1 + E/F all resident

#define TILE(buf, jt, DIAG)                                                    \
  do {                                                                         \
    _Pragma("unroll") for (int kk = 0; kk < 2; ++kk) {                         \
      const int ebase = ((jt) << 6) + (kk << 5) + (lq << 3);                   \
      f16x8 ev8 = *(const f16x8*)&Esh[ebase];                                  \
      f16x8 fv8 = *(const f16x8*)&Fsh[ebase];                                  \
      f16x8 bf[8];                                                             \
      _Pragma("unroll") for (int n = 0; n < 8; ++n) {                          \
        const int r_ = (n << 4) + lr;                                          \
        const int slot_ = ((kk << 2) + lq) ^ (r_ & 7);                         \
        bf[n] = *(const f16x8*)(&Hs[buf][(r_ << 6) + (slot_ << 3)]);           \
      }                                                                        \
      f16x8 af[2];                                                             \
      _Pragma("unroll") for (int m = 0; m < 2; ++m) {                          \
        f16x8 pm = __builtin_elementwise_max(Ai8[m] * ev8, Bi8[m] * fv8);      \
        if ((DIAG) && kk == kkd) pm = pm * dmask[m];                           \
        af[m] = pm;                                                            \
        h8u u_; u_.v = pm;                                                     \
        _Pragma("unroll") for (int p = 0; p < 4; ++p)                          \
            dsum[m] = FDOT2(u_.h[p], one2, dsum[m]);                           \
      }                                                                        \
      _Pragma("unroll") for (int m = 0; m < 2; ++m)                            \
        _Pragma("unroll") for (int n = 0; n < 8; ++n)                          \
            acc[m][n] = __builtin_amdgcn_mfma_f32_16x16x32_f16(                \
                af[m], bf[n], acc[m][n], 0, 0, 0);                             \
    }                                                                          \
  } while (0)

  int cur = 0;
#pragma unroll 1
  for (int jt = 0; jt < 16; ++jt) {
    if (jt < 14) {
      STAGE((cur == 0 ? 2 : cur - 1), (jt + 2) << 6);  // (jt+2)%3
      asm volatile("s_waitcnt vmcnt(8)" ::: "memory");  // tile jt's 4 done
    } else if (jt == 14) {
      asm volatile("s_waitcnt vmcnt(4)" ::: "memory");
    } else {
      asm volatile("s_waitcnt vmcnt(0)" ::: "memory");
    }
    __builtin_amdgcn_s_barrier();   // all waves: buf[cur] fully staged
    __builtin_amdgcn_s_setprio(1);
    TILE(cur, jt, jt == jtd);
    __builtin_amdgcn_s_setprio(0);
    __builtin_amdgcn_s_barrier();   // all waves done reading buf[cur]
    cur = (cur == 2) ? 0 : cur + 1;
  }

  const int b = bh >> 2, head = bh & 3;
#pragma unroll
  for (int m = 0; m < 2; ++m) {
    float s = dsum[m];
    s += __shfl_xor(s, 16);
    s += __shfl_xor(s, 32);  // all lq-replica lanes hold the row sum
    float rs = 1.f / s;
    f32x4 d4;
#pragma unroll
    for (int q = 0; q < 4; ++q)
      d4[q] = __shfl(rs, (lane & 48) | ((lq << 2) + q));
    int irow = i0 + (w << 5) + (m << 4) + (lq << 2);
#pragma unroll
    for (int n = 0; n < 8; ++n) {
      int d = (n << 4) + lr;
      long base = ((long)((b << 10) + irow) << 9) + (head << 7) + d;
      attn[base] = f2h(acc[m][n][0] * d4[0]);
      attn[base + 512] = f2h(acc[m][n][1] * d4[1]);
      attn[base + 1024] = f2h(acc[m][n][2] * d4[2]);
      attn[base + 1536] = f2h(acc[m][n][3] * d4[3]);
    }
  }
#undef STAGE
#undef TILE
}

// ---------------- out-proj + bias (+residual) + LN (+relu) ----------------
// 32-row blocks, grid 512 (2 blocks/CU). Wave owns 16 rows x 64 cols; LN via
// cross-wave LDS partial-sum exchange.
template <int HAS_RES, int DO_RELU, int WRITE_OUT>
__global__ __launch_bounds__(256) void k_outproj(const short* __restrict__ attn,
                                                 const short* __restrict__ WoT,
                                                 const float* __restrict__ bo,
                                                 const float* __restrict__ gamma,
                                                 const float* __restrict__ beta,
                                                 float* __restrict__ xf,
                                                 short* __restrict__ xh,
                                                 float* __restrict__ outp) {
  __shared__ __align__(16) short As[32 * LDP];
  __shared__ __align__(16) short Bs[128 * LDP];
  __shared__ float sredS[2][32], sredQ[2][32];
  const int t = threadIdx.x;
  const int bn0 = blockIdx.x << 5;
  const int w = t >> 6, lane = t & 63, lr = lane & 15, lq = lane >> 4;
  const int wm = w & 1, wn = w >> 1;
  f32x4 acc[4] = {};
  const int rowA = t >> 3, chA = (t & 7) << 3;
  const int rowB = t >> 1, chB = (t & 1) << 5;
  for (int k0 = 0; k0 < 512; k0 += 64) {
    {
      const short* sa = attn + ((long)(bn0 + rowA) << 9) + k0 + chA;
      *(short8*)(As + rowA * LDP + chA) = *(const short8*)(sa);
      const short* sb = WoT + (rowB << 9) + k0 + chB;
      short* db = Bs + rowB * LDP + chB;
      *(short8*)(db) = *(const short8*)(sb);
      *(short8*)(db + 8) = *(const short8*)(sb + 8);
      *(short8*)(db + 16) = *(const short8*)(sb + 16);
      *(short8*)(db + 24) = *(const short8*)(sb + 24);
    }
    __syncthreads();
#pragma unroll
    for (int kk = 0; kk < 2; ++kk) {
      f16x8 a = *(const f16x8*)(As + ((wm << 4) + lr) * LDP + (kk << 5) + (lq << 3));
#pragma unroll
      for (int nn = 0; nn < 4; ++nn) {
        f16x8 b = *(const f16x8*)(Bs + ((wn << 6) + (nn << 4) + lr) * LDP + (kk << 5) + (lq << 3));
        acc[nn] = __builtin_amdgcn_mfma_f32_16x16x32_f16(a, b, acc[nn], 0, 0, 0);
      }
    }
    __syncthreads();
  }
  float v[4][4], gam[4], bet[4];
#pragma unroll
  for (int nn = 0; nn < 4; ++nn) {
    int d = (wn << 6) + (nn << 4) + lr;
    float bv = bo[d];
    gam[nn] = gamma[d];
    bet[nn] = beta[d];
#pragma unroll
    for (int r = 0; r < 4; ++r) {
      float x = acc[nn][r] + bv;
      if (HAS_RES) x += xf[((bn0 + (wm << 4) + (lq << 2) + r) << 7) + d];
      v[nn][r] = x;
    }
  }
#pragma unroll
  for (int r = 0; r < 4; ++r) {
    float s = 0.f, q = 0.f;
#pragma unroll
    for (int nn = 0; nn < 4; ++nn) { s += v[nn][r]; q += v[nn][r] * v[nn][r]; }
#pragma unroll
    for (int mk = 1; mk < 16; mk <<= 1) { s += __shfl_xor(s, mk); q += __shfl_xor(q, mk); }
    if (lr == 0) {
      int row = (wm << 4) + (lq << 2) + r;
      sredS[wn][row] = s;
      sredQ[wn][row] = q;
    }
  }
  __syncthreads();
#pragma unroll
  for (int r = 0; r < 4; ++r) {
    int rloc = (wm << 4) + (lq << 2) + r;
    float S = sredS[0][rloc] + sredS[1][rloc];
    float Q = sredQ[0][rloc] + sredQ[1][rloc];
    float mean = S * 0.0078125f;
    float var = Q * 0.0078125f - mean * mean;
    float rstd = rsqrtf(var + 1e-5f);
    int row = bn0 + rloc;
#pragma unroll
    for (int nn = 0; nn < 4; ++nn) {
      int d = (wn << 6) + (nn << 4) + lr;
      float o = (v[nn][r] - mean) * rstd * gam[nn] + bet[nn];
      if (DO_RELU) o = fmaxf(o, 0.f);
      if (WRITE_OUT) {
        outp[(row << 7) + d] = o;
      } else {
        xh[(row << 7) + d] = f2h(o);
        xf[(row << 7) + d] = o;
      }
    }
  }
}

extern "C" void kernel_launch(void* const* d_in, const int* in_sizes, int n_in,
                              void* d_out, int out_size, void* d_ws, size_t ws_size,
                              hipStream_t stream) {
  const float* nf = (const float*)d_in[0];
  const float* Wp = (const float*)d_in[1];
  const float* bp = (const float*)d_in[2];
  const float* W = (const float*)d_in[3];
  const float* a1 = (const float*)d_in[4];
  const float* a2 = (const float*)d_in[5];
  const float* Wo = (const float*)d_in[6];
  const float* bo = (const float*)d_in[7];
  const float* gamma = (const float*)d_in[8];
  const float* beta = (const float*)d_in[9];
  float* outp = (float*)d_out;

  char* ws = (char*)d_ws;
  short* xh = (short*)(ws);                                    // 4 MB
  float* xf = (float*)(ws + (4ll << 20));                      // 8 MB
  short* hT = (short*)(ws + (12ll << 20));                     // 16 MB
  short* attn = (short*)(ws + (28ll << 20));                   // 16 MB
  float* s1 = (float*)(ws + (44ll << 20));                     // 256 KB
  float* s2g = (float*)(ws + (44ll << 20) + (256ll << 10));    // 256 KB
  short* Eh = (short*)(ws + (44ll << 20) + (512ll << 10));     // 128 KB
  short* Fh = (short*)(ws + (44ll << 20) + (640ll << 10));     // 128 KB
  float* s2m = (float*)(ws + (44ll << 20) + (768ll << 10));    // 1 KB
  short* WT = (short*)(ws + (45ll << 20));                     // 384 KB
  short* WoT = (short*)(ws + (45ll << 20) + 393216);           // 384 KB

  k_tw<<<1536, 256, 0, stream>>>(W, Wo, WT, WoT);
  k_inproj<<<8192, 256, 0, stream>>>(nf, Wp, bp, xh);
  for (int l = 0; l < 3; ++l) {
    k_gemm_h<<<dim3(128, 4), 256, 0, stream>>>(xh, WT + l * 65536, hT,
                                               a1 + l * 512, a2 + l * 512, s1, s2g);
    k_ef<<<64, 256, 0, stream>>>(s2g, s2m, Eh, Fh);
    k_attn<<<dim3(64, 8), 256, 0, stream>>>(hT, s1, Eh, Fh, s2m, attn);
    if (l == 0)
      k_outproj<0, 1, 0><<<512, 256, 0, stream>>>(attn, WoT + l * 65536, bo + l * 128,
                                                  gamma + l * 128, beta + l * 128, xf, xh, outp);
    else if (l == 1)
      k_outproj<1, 1, 0><<<512, 256, 0, stream>>>(attn, WoT + l * 65536, bo + l * 128,
                                                  gamma + l * 128, beta + l * 128, xf, xh, outp);
    else
      k_outproj<1, 0, 1><<<512, 256, 0, stream>>>(attn, WoT + l * 65536, bo + l * 128,
                                                  gamma + l * 128, beta + l * 128, xf, xh, outp);
  }
}

// Round 19
// 163.726 us; speedup vs baseline: 1.2452x; 1.0022x over previous
//
#include <hip/hip_runtime.h>
#include <hip/hip_bf16.h>

typedef __attribute__((ext_vector_type(8))) _Float16 f16x8;
typedef __attribute__((ext_vector_type(2))) _Float16 f16x2;
typedef __attribute__((ext_vector_type(8))) short short8;
typedef __attribute__((ext_vector_type(4))) short short4v;
typedef __attribute__((ext_vector_type(4))) float f32x4;

#define LDP 72   // LDS row stride (shorts) for reg-staged GEMM tiles

typedef const __attribute__((address_space(1))) unsigned int* gas_ptr;
typedef __attribute__((address_space(3))) unsigned int* las_ptr;
#define GLDS16(gp, lp) \
  __builtin_amdgcn_global_load_lds((gas_ptr)(gp), (las_ptr)(lp), 16, 0, 0)

#if __has_builtin(__builtin_amdgcn_fdot2)
#define FDOT2(a, b, c) __builtin_amdgcn_fdot2((a), (b), (c), false)
#else
__device__ __forceinline__ float FDOT2(f16x2 a, f16x2 b, float c) {
  return c + (float)a[0] * (float)b[0] + (float)a[1] * (float)b[1];
}
#endif

union h8u {
  f16x8 v;
  f16x2 h[4];
};

__device__ __forceinline__ short f2h(float f) {
  union { _Float16 h; short s; } u; u.h = (_Float16)f; return u.s;
}
__device__ __forceinline__ float h2f(short s) {
  union { short s; _Float16 h; } u; u.s = s; return (float)u.h;
}

// ---------------- weight transpose + f32->f16 ----------------
__global__ __launch_bounds__(256) void k_tw(const float* __restrict__ W,
                                            const float* __restrict__ Wo,
                                            short* __restrict__ WT,
                                            short* __restrict__ WoT) {
  int idx = blockIdx.x * 256 + threadIdx.x;
  if (idx < 3 * 512 * 128) {
    int l = idx >> 16, rem = idx & 65535;
    int c = rem >> 7, k = rem & 127;
    int h = c >> 7, o = c & 127;
    WT[idx] = f2h(W[(((l * 4 + h) * 128 + k) << 7) + o]);
  } else {
    int j = idx - 3 * 512 * 128;
    int l = j >> 16, rem = j & 65535;
    int d = rem >> 9, c = rem & 511;
    WoT[j] = f2h(Wo[((l * 512 + c) << 7) + d]);
  }
}

// ---------------- input projection ----------------
__global__ __launch_bounds__(256) void k_inproj(const float* __restrict__ nf,
                                                const float* __restrict__ Wp,
                                                const float* __restrict__ bp,
                                                short* __restrict__ xh) {
  int idx = blockIdx.x * 256 + threadIdx.x;
  int bn = idx >> 7, d = idx & 127;
  float acc = bp[d];
  const float* nr = nf + bn * 7;
#pragma unroll
  for (int i = 0; i < 7; ++i) acc += nr[i] * Wp[(i << 7) + d];
  xh[idx] = f2h(acc);
}

// ---------------- head projection + fused s1/s2 ----------------
__global__ __launch_bounds__(256) void k_gemm_h(const short* __restrict__ xh,
                                                const short* __restrict__ WT,
                                                short* __restrict__ hT,
                                                const float* __restrict__ a1,
                                                const float* __restrict__ a2,
                                                float* __restrict__ s1g,
                                                float* __restrict__ s2g) {
  __shared__ __align__(16) short As[128 * LDP];
  __shared__ __align__(16) short Bs[128 * LDP];
  __shared__ float sred[2][2][128];
  const int t = threadIdx.x;
  const int bn0 = blockIdx.x << 7;
  const int head = blockIdx.y;
  const int c0 = head << 7;
  const int w = t >> 6, lane = t & 63, lr = lane & 15, lq = lane >> 4;
  const int wr = w >> 1, wc = w & 1;
  f32x4 acc[4][4] = {};
  for (int k0 = 0; k0 < 128; k0 += 64) {
    const int row = t >> 1, half = (t & 1) << 5;
    {
      const short* sa = xh + ((bn0 + row) << 7) + k0 + half;
      short* da = As + row * LDP + half;
      *(short8*)(da) = *(const short8*)(sa);
      *(short8*)(da + 8) = *(const short8*)(sa + 8);
      *(short8*)(da + 16) = *(const short8*)(sa + 16);
      *(short8*)(da + 24) = *(const short8*)(sa + 24);
      const short* sb = WT + ((c0 + row) << 7) + k0 + half;
      short* db = Bs + row * LDP + half;
      *(short8*)(db) = *(const short8*)(sb);
      *(short8*)(db + 8) = *(const short8*)(sb + 8);
      *(short8*)(db + 16) = *(const short8*)(sb + 16);
      *(short8*)(db + 24) = *(const short8*)(sb + 24);
    }
    __syncthreads();
#pragma unroll
    for (int kk = 0; kk < 2; ++kk) {
      f16x8 a[4], b[4];
#pragma unroll
      for (int m = 0; m < 4; ++m)
        a[m] = *(const f16x8*)(As + (wr * 64 + m * 16 + lr) * LDP + (kk << 5) + (lq << 3));
#pragma unroll
      for (int n = 0; n < 4; ++n)
        b[n] = *(const f16x8*)(Bs + (wc * 64 + n * 16 + lr) * LDP + (kk << 5) + (lq << 3));
#pragma unroll
      for (int m = 0; m < 4; ++m)
#pragma unroll
        for (int n = 0; n < 4; ++n)
          acc[m][n] = __builtin_amdgcn_mfma_f32_16x16x32_f16(a[m], b[n], acc[m][n], 0, 0, 0);
    }
    __syncthreads();
  }
  const int b = bn0 >> 10;
  const int nb = bn0 & 1023;
  float a1v[4], a2v[4];
#pragma unroll
  for (int n = 0; n < 4; ++n) {
    int d = wc * 64 + n * 16 + lr;
    a1v[n] = a1[(head << 7) + d];
    a2v[n] = a2[(head << 7) + d];
  }
#pragma unroll
  for (int m = 0; m < 4; ++m)
#pragma unroll
    for (int r = 0; r < 4; ++r) {
      float v1 = 0.f, v2 = 0.f;
#pragma unroll
      for (int n = 0; n < 4; ++n) {
        v1 += acc[m][n][r] * a1v[n];
        v2 += acc[m][n][r] * a2v[n];
      }
#pragma unroll
      for (int off = 1; off < 16; off <<= 1) {
        v1 += __shfl_xor(v1, off);
        v2 += __shfl_xor(v2, off);
      }
      if (lr == 0) {
        int row = wr * 64 + m * 16 + (lq << 2) + r;
        sred[wc][0][row] = v1;
        sred[wc][1][row] = v2;
      }
    }
#pragma unroll
  for (int m = 0; m < 4; ++m) {
    int nrow = nb + wr * 64 + m * 16 + (lq << 2);
#pragma unroll
    for (int n = 0; n < 4; ++n) {
      int d = wc * 64 + n * 16 + lr;
      long base = ((long)((((b << 2) + head) << 7) + d) << 10) + nrow;
      short4v v;
      v[0] = f2h(acc[m][n][0]); v[1] = f2h(acc[m][n][1]);
      v[2] = f2h(acc[m][n][2]); v[3] = f2h(acc[m][n][3]);
      *(short4v*)(hT + base) = v;
    }
  }
  __syncthreads();
  {
    const int bh_ = (b << 2) + head;
    if (t < 128)
      s1g[(bh_ << 10) + nb + t] = sred[0][0][t] + sred[1][0][t];
    else
      s2g[(bh_ << 10) + nb + (t - 128)] = sred[0][1][t - 128] + sred[1][1][t - 128];
  }
}

// ---------------- tiny: s2 -> max, E=exp(s2-max) f16, F=exp(.2(s2-max)) f16 ----
__global__ __launch_bounds__(256) void k_ef(const float* __restrict__ s2g,
                                            float* __restrict__ s2m,
                                            short* __restrict__ Eh,
                                            short* __restrict__ Fh) {
  const int bh = blockIdx.x, t = threadIdx.x;
  __shared__ float red[4];
  f32x4 v = *(const f32x4*)&s2g[(bh << 10) + (t << 2)];
  float mx = fmaxf(fmaxf(v[0], v[1]), fmaxf(v[2], v[3]));
#pragma unroll
  for (int off = 1; off < 64; off <<= 1) mx = fmaxf(mx, __shfl_xor(mx, off));
  if ((t & 63) == 0) red[t >> 6] = mx;
  __syncthreads();
  const float smax = fmaxf(fmaxf(red[0], red[1]), fmaxf(red[2], red[3]));
  if (t == 0) s2m[bh] = smax;
  short4v e, f;
#pragma unroll
  for (int q = 0; q < 4; ++q) {
    e[q] = f2h(__expf(v[q] - smax));
    f[q] = f2h(__expf(0.2f * (v[q] - smax)));
  }
  *(short4v*)&Eh[(bh << 10) + (t << 2)] = e;
  *(short4v*)&Fh[(bh << 10) + (t << 2)] = f;
}

// ---------------- attention ----------------
// grid (64 bh, 8 it). Wave owns 32-row strip (m=2) x full 128 d (n=8).
// 3 LDS buffers, prefetch distance 2, counted s_waitcnt vmcnt(4), and a
// SINGLE barrier per iteration: {vmcnt -> barrier -> STAGE(jt+2) -> TILE(jt)}.
// Safety: per-wave vmcnt + barrier => all waves' tile-jt stages resident;
// STAGE(jt+2) issued after the barrier that certifies all waves finished
// TILE(jt-1) (the last reader of buf[(jt+2)%3]).
__global__ __launch_bounds__(256) void k_attn(const short* __restrict__ hT,
                                              const float* __restrict__ s1,
                                              const short* __restrict__ Eh,
                                              const short* __restrict__ Fh,
                                              const float* __restrict__ s2max,
                                              short* __restrict__ attn) {
  __shared__ __align__(16) short Hs[3][128 * 64];
  __shared__ __align__(16) _Float16 Esh[1024];
  __shared__ __align__(16) _Float16 Fsh[1024];
  const int bh = blockIdx.x, it = blockIdx.y;
  const int i0 = it << 7;
  const int t = threadIdx.x;
  const int w = t >> 6, lane = t & 63, lr = lane & 15, lq = lane >> 4;

  const short* hTb = hT + ((long)bh << 17);
  const int grow = (w << 5) + (lane >> 3);
  const int gcol = ((lane & 7) ^ (lane >> 3)) << 3;
  const short* gsrc = hTb + ((long)grow << 10) + gcol;

#define STAGE(buf, J0)                                             \
  do {                                                             \
    short* ldsb = &Hs[buf][(w << 5) << 6];                         \
    _Pragma("unroll") for (int i_ = 0; i_ < 4; ++i_)               \
        GLDS16(gsrc + ((long)(i_ << 3) << 10) + (J0),              \
               ldsb + ((i_ << 3) << 6));                           \
  } while (0)

  STAGE(0, 0);
  STAGE(1, 64);
  *(short4v*)&Esh[t << 2] = *(const short4v*)&Eh[(bh << 10) + (t << 2)];
  *(short4v*)&Fsh[t << 2] = *(const short4v*)&Fh[(bh << 10) + (t << 2)];

  const float smax = s2max[bh];
  f16x8 Ai8[2], Bi8[2];
  const f16x2 one2 = {(_Float16)1.f, (_Float16)1.f};
  f16x8 dmask[2];
  float dsum[2] = {0.f, 0.f};
#pragma unroll
  for (int m = 0; m < 2; ++m) {
    const int rblk = (w << 5) + (m << 4) + lr;
    float s1v = s1[(bh << 10) + i0 + rblk];
    float x = s1v + smax;
    float mi = fmaxf(x, 0.2f * x);  // upper bound of row max (lrelu monotone)
    _Float16 A_ = (_Float16)__expf(x - mi);
    _Float16 B_ = (_Float16)__expf(0.2f * x - mi);
#pragma unroll
    for (int e = 0; e < 8; ++e) { Ai8[m][e] = A_; Bi8[m][e] = B_; }
    const int lqz = ((m << 1) + (lr >> 3)) & 3, ez = lr & 7;
#pragma unroll
    for (int e = 0; e < 8; ++e)
      dmask[m][e] = (lq == lqz && e == ez) ? (_Float16)0.f : (_Float16)1.f;
  }
  const int jtd = (it << 1) + (w >> 1);  // wave-uniform diagonal j-tile
  const int kkd = w & 1;                 // wave-uniform diag k-half
  f32x4 acc[2][8] = {};
  __syncthreads();  // prologue: bufs 0,1 + E/F all resident

#define TILE(buf, jt, DIAG)                                                    \
  do {                                                                         \
    _Pragma("unroll") for (int kk = 0; kk < 2; ++kk) {                         \
      const int ebase = ((jt) << 6) + (kk << 5) + (lq << 3);                   \
      f16x8 ev8 = *(const f16x8*)&Esh[ebase];                                  \
      f16x8 fv8 = *(const f16x8*)&Fsh[ebase];                                  \
      f16x8 bf[8];                                                             \
      _Pragma("unroll") for (int n = 0; n < 8; ++n) {                          \
        const int r_ = (n << 4) + lr;                                          \
        const int slot_ = ((kk << 2) + lq) ^ (r_ & 7);                         \
        bf[n] = *(const f16x8*)(&Hs[buf][(r_ << 6) + (slot_ << 3)]);           \
      }                                                                        \
      f16x8 af[2];                                                             \
      _Pragma("unroll") for (int m = 0; m < 2; ++m) {                          \
        f16x8 pm = __builtin_elementwise_max(Ai8[m] * ev8, Bi8[m] * fv8);      \
        if ((DIAG) && kk == kkd) pm = pm * dmask[m];                           \
        af[m] = pm;                                                            \
        h8u u_; u_.v = pm;                                                     \
        _Pragma("unroll") for (int p = 0; p < 4; ++p)                          \
            dsum[m] = FDOT2(u_.h[p], one2, dsum[m]);                           \
      }                                                                        \
      _Pragma("unroll") for (int m = 0; m < 2; ++m)                            \
        _Pragma("unroll") for (int n = 0; n < 8; ++n)                          \
            acc[m][n] = __builtin_amdgcn_mfma_f32_16x16x32_f16(                \
                af[m], bf[n], acc[m][n], 0, 0, 0);                             \
    }                                                                          \
  } while (0)

  int cur = 0;
#pragma unroll 1
  for (int jt = 0; jt < 16; ++jt) {
    if (jt < 15) {
      asm volatile("s_waitcnt vmcnt(4)" ::: "memory");  // own tile-jt loads in
    } else {
      asm volatile("s_waitcnt vmcnt(0)" ::: "memory");
    }
    __builtin_amdgcn_s_barrier();   // all waves: buf[cur] fully staged AND
                                    // all waves done reading buf[(jt+2)%3]
    if (jt < 14) STAGE((cur == 0 ? 2 : cur - 1), (jt + 2) << 6);
    __builtin_amdgcn_s_setprio(1);
    TILE(cur, jt, jt == jtd);
    __builtin_amdgcn_s_setprio(0);
    cur = (cur == 2) ? 0 : cur + 1;
  }

  const int b = bh >> 2, head = bh & 3;
#pragma unroll
  for (int m = 0; m < 2; ++m) {
    float s = dsum[m];
    s += __shfl_xor(s, 16);
    s += __shfl_xor(s, 32);  // all lq-replica lanes hold the row sum
    float rs = 1.f / s;
    f32x4 d4;
#pragma unroll
    for (int q = 0; q < 4; ++q)
      d4[q] = __shfl(rs, (lane & 48) | ((lq << 2) + q));
    int irow = i0 + (w << 5) + (m << 4) + (lq << 2);
#pragma unroll
    for (int n = 0; n < 8; ++n) {
      int d = (n << 4) + lr;
      long base = ((long)((b << 10) + irow) << 9) + (head << 7) + d;
      attn[base] = f2h(acc[m][n][0] * d4[0]);
      attn[base + 512] = f2h(acc[m][n][1] * d4[1]);
      attn[base + 1024] = f2h(acc[m][n][2] * d4[2]);
      attn[base + 1536] = f2h(acc[m][n][3] * d4[3]);
    }
  }
#undef STAGE
#undef TILE
}

// ---------------- out-proj + bias (+residual) + LN (+relu) ----------------
// 32-row blocks, grid 512 (2 blocks/CU). Wave owns 16 rows x 64 cols; LN via
// cross-wave LDS partial-sum exchange.
template <int HAS_RES, int DO_RELU, int WRITE_OUT>
__global__ __launch_bounds__(256) void k_outproj(const short* __restrict__ attn,
                                                 const short* __restrict__ WoT,
                                                 const float* __restrict__ bo,
                                                 const float* __restrict__ gamma,
                                                 const float* __restrict__ beta,
                                                 float* __restrict__ xf,
                                                 short* __restrict__ xh,
                                                 float* __restrict__ outp) {
  __shared__ __align__(16) short As[32 * LDP];
  __shared__ __align__(16) short Bs[128 * LDP];
  __shared__ float sredS[2][32], sredQ[2][32];
  const int t = threadIdx.x;
  const int bn0 = blockIdx.x << 5;
  const int w = t >> 6, lane = t & 63, lr = lane & 15, lq = lane >> 4;
  const int wm = w & 1, wn = w >> 1;
  f32x4 acc[4] = {};
  const int rowA = t >> 3, chA = (t & 7) << 3;
  const int rowB = t >> 1, chB = (t & 1) << 5;
  for (int k0 = 0; k0 < 512; k0 += 64) {
    {
      const short* sa = attn + ((long)(bn0 + rowA) << 9) + k0 + chA;
      *(short8*)(As + rowA * LDP + chA) = *(const short8*)(sa);
      const short* sb = WoT + (rowB << 9) + k0 + chB;
      short* db = Bs + rowB * LDP + chB;
      *(short8*)(db) = *(const short8*)(sb);
      *(short8*)(db + 8) = *(const short8*)(sb + 8);
      *(short8*)(db + 16) = *(const short8*)(sb + 16);
      *(short8*)(db + 24) = *(const short8*)(sb + 24);
    }
    __syncthreads();
#pragma unroll
    for (int kk = 0; kk < 2; ++kk) {
      f16x8 a = *(const f16x8*)(As + ((wm << 4) + lr) * LDP + (kk << 5) + (lq << 3));
#pragma unroll
      for (int nn = 0; nn < 4; ++nn) {
        f16x8 b = *(const f16x8*)(Bs + ((wn << 6) + (nn << 4) + lr) * LDP + (kk << 5) + (lq << 3));
        acc[nn] = __builtin_amdgcn_mfma_f32_16x16x32_f16(a, b, acc[nn], 0, 0, 0);
      }
    }
    __syncthreads();
  }
  float v[4][4], gam[4], bet[4];
#pragma unroll
  for (int nn = 0; nn < 4; ++nn) {
    int d = (wn << 6) + (nn << 4) + lr;
    float bv = bo[d];
    gam[nn] = gamma[d];
    bet[nn] = beta[d];
#pragma unroll
    for (int r = 0; r < 4; ++r) {
      float x = acc[nn][r] + bv;
      if (HAS_RES) x += xf[((bn0 + (wm << 4) + (lq << 2) + r) << 7) + d];
      v[nn][r] = x;
    }
  }
#pragma unroll
  for (int r = 0; r < 4; ++r) {
    float s = 0.f, q = 0.f;
#pragma unroll
    for (int nn = 0; nn < 4; ++nn) { s += v[nn][r]; q += v[nn][r] * v[nn][r]; }
#pragma unroll
    for (int mk = 1; mk < 16; mk <<= 1) { s += __shfl_xor(s, mk); q += __shfl_xor(q, mk); }
    if (lr == 0) {
      int row = (wm << 4) + (lq << 2) + r;
      sredS[wn][row] = s;
      sredQ[wn][row] = q;
    }
  }
  __syncthreads();
#pragma unroll
  for (int r = 0; r < 4; ++r) {
    int rloc = (wm << 4) + (lq << 2) + r;
    float S = sredS[0][rloc] + sredS[1][rloc];
    float Q = sredQ[0][rloc] + sredQ[1][rloc];
    float mean = S * 0.0078125f;
    float var = Q * 0.0078125f - mean * mean;
    float rstd = rsqrtf(var + 1e-5f);
    int row = bn0 + rloc;
#pragma unroll
    for (int nn = 0; nn < 4; ++nn) {
      int d = (wn << 6) + (nn << 4) + lr;
      float o = (v[nn][r] - mean) * rstd * gam[nn] + bet[nn];
      if (DO_RELU) o = fmaxf(o, 0.f);
      if (WRITE_OUT) {
        outp[(row << 7) + d] = o;
      } else {
        xh[(row << 7) + d] = f2h(o);
        xf[(row << 7) + d] = o;
      }
    }
  }
}

extern "C" void kernel_launch(void* const* d_in, const int* in_sizes, int n_in,
                              void* d_out, int out_size, void* d_ws, size_t ws_size,
                              hipStream_t stream) {
  const float* nf = (const float*)d_in[0];
  const float* Wp = (const float*)d_in[1];
  const float* bp = (const float*)d_in[2];
  const float* W = (const float*)d_in[3];
  const float* a1 = (const float*)d_in[4];
  const float* a2 = (const float*)d_in[5];
  const float* Wo = (const float*)d_in[6];
  const float* bo = (const float*)d_in[7];
  const float* gamma = (const float*)d_in[8];
  const float* beta = (const float*)d_in[9];
  float* outp = (float*)d_out;

  char* ws = (char*)d_ws;
  short* xh = (short*)(ws);                                    // 4 MB
  float* xf = (float*)(ws + (4ll << 20));                      // 8 MB
  short* hT = (short*)(ws + (12ll << 20));                     // 16 MB
  short* attn = (short*)(ws + (28ll << 20));                   // 16 MB
  float* s1 = (float*)(ws + (44ll << 20));                     // 256 KB
  float* s2g = (float*)(ws + (44ll << 20) + (256ll << 10));    // 256 KB
  short* Eh = (short*)(ws + (44ll << 20) + (512ll << 10));     // 128 KB
  short* Fh = (short*)(ws + (44ll << 20) + (640ll << 10));     // 128 KB
  float* s2m = (float*)(ws + (44ll << 20) + (768ll << 10));    // 1 KB
  short* WT = (short*)(ws + (45ll << 20));                     // 384 KB
  short* WoT = (short*)(ws + (45ll << 20) + 393216);           // 384 KB

  k_tw<<<1536, 256, 0, stream>>>(W, Wo, WT, WoT);
  k_inproj<<<8192, 256, 0, stream>>>(nf, Wp, bp, xh);
  for (int l = 0; l < 3; ++l) {
    k_gemm_h<<<dim3(128, 4), 256, 0, stream>>>(xh, WT + l * 65536, hT,
                                               a1 + l * 512, a2 + l * 512, s1, s2g);
    k_ef<<<64, 256, 0, stream>>>(s2g, s2m, Eh, Fh);
    k_attn<<<dim3(64, 8), 256, 0, stream>>>(hT, s1, Eh, Fh, s2m, attn);
    if (l == 0)
      k_outproj<0, 1, 0><<<512, 256, 0, stream>>>(attn, WoT + l * 65536, bo + l * 128,
                                                  gamma + l * 128, beta + l * 128, xf, xh, outp);
    else if (l == 1)
      k_outproj<1, 1, 0><<<512, 256, 0, stream>>>(attn, WoT + l * 65536, bo + l * 128,
                                                  gamma + l * 128, beta + l * 128, xf, xh, outp);
    else
      k_outproj<1, 0, 1><<<512, 256, 0, stream>>>(attn, WoT + l * 65536, bo + l * 128,
                                                  gamma + l * 128, beta + l * 128, xf, xh, outp);
  }
}

// Round 20
// 159.164 us; speedup vs baseline: 1.2809x; 1.0287x over previous
//
#include <hip/hip_runtime.h>
#include <hip/hip_bf16.h>

typedef __attribute__((ext_vector_type(8))) _Float16 f16x8;
typedef __attribute__((ext_vector_type(2))) _Float16 f16x2;
typedef __attribute__((ext_vector_type(8))) short short8;
typedef __attribute__((ext_vector_type(4))) short short4v;
typedef __attribute__((ext_vector_type(4))) float f32x4;

#define LDP 72   // LDS row stride (shorts) for reg-staged GEMM tiles

typedef const __attribute__((address_space(1))) unsigned int* gas_ptr;
typedef __attribute__((address_space(3))) unsigned int* las_ptr;
#define GLDS16(gp, lp) \
  __builtin_amdgcn_global_load_lds((gas_ptr)(gp), (las_ptr)(lp), 16, 0, 0)

#if __has_builtin(__builtin_amdgcn_fdot2)
#define FDOT2(a, b, c) __builtin_amdgcn_fdot2((a), (b), (c), false)
#else
__device__ __forceinline__ float FDOT2(f16x2 a, f16x2 b, float c) {
  return c + (float)a[0] * (float)b[0] + (float)a[1] * (float)b[1];
}
#endif

union h8u {
  f16x8 v;
  f16x2 h[4];
};

__device__ __forceinline__ short f2h(float f) {
  union { _Float16 h; short s; } u; u.h = (_Float16)f; return u.s;
}
__device__ __forceinline__ float h2f(short s) {
  union { short s; _Float16 h; } u; u.s = s; return (float)u.h;
}

// ---------------- weight transpose + f32->f16 ----------------
__global__ __launch_bounds__(256) void k_tw(const float* __restrict__ W,
                                            const float* __restrict__ Wo,
                                            short* __restrict__ WT,
                                            short* __restrict__ WoT) {
  int idx = blockIdx.x * 256 + threadIdx.x;
  if (idx < 3 * 512 * 128) {
    int l = idx >> 16, rem = idx & 65535;
    int c = rem >> 7, k = rem & 127;
    int h = c >> 7, o = c & 127;
    WT[idx] = f2h(W[(((l * 4 + h) * 128 + k) << 7) + o]);
  } else {
    int j = idx - 3 * 512 * 128;
    int l = j >> 16, rem = j & 65535;
    int d = rem >> 9, c = rem & 511;
    WoT[j] = f2h(Wo[((l * 512 + c) << 7) + d]);
  }
}

// ---------------- input projection ----------------
__global__ __launch_bounds__(256) void k_inproj(const float* __restrict__ nf,
                                                const float* __restrict__ Wp,
                                                const float* __restrict__ bp,
                                                short* __restrict__ xh) {
  int idx = blockIdx.x * 256 + threadIdx.x;
  int bn = idx >> 7, d = idx & 127;
  float acc = bp[d];
  const float* nr = nf + bn * 7;
#pragma unroll
  for (int i = 0; i < 7; ++i) acc += nr[i] * Wp[(i << 7) + d];
  xh[idx] = f2h(acc);
}

// ---------------- head projection + fused s1/s2 ----------------
__global__ __launch_bounds__(256) void k_gemm_h(const short* __restrict__ xh,
                                                const short* __restrict__ WT,
                                                short* __restrict__ hT,
                                                const float* __restrict__ a1,
                                                const float* __restrict__ a2,
                                                float* __restrict__ s1g,
                                                float* __restrict__ s2g) {
  __shared__ __align__(16) short As[128 * LDP];
  __shared__ __align__(16) short Bs[128 * LDP];
  __shared__ float sred[2][2][128];
  const int t = threadIdx.x;
  const int bn0 = blockIdx.x << 7;
  const int head = blockIdx.y;
  const int c0 = head << 7;
  const int w = t >> 6, lane = t & 63, lr = lane & 15, lq = lane >> 4;
  const int wr = w >> 1, wc = w & 1;
  f32x4 acc[4][4] = {};
  for (int k0 = 0; k0 < 128; k0 += 64) {
    const int row = t >> 1, half = (t & 1) << 5;
    {
      const short* sa = xh + ((bn0 + row) << 7) + k0 + half;
      short* da = As + row * LDP + half;
      *(short8*)(da) = *(const short8*)(sa);
      *(short8*)(da + 8) = *(const short8*)(sa + 8);
      *(short8*)(da + 16) = *(const short8*)(sa + 16);
      *(short8*)(da + 24) = *(const short8*)(sa + 24);
      const short* sb = WT + ((c0 + row) << 7) + k0 + half;
      short* db = Bs + row * LDP + half;
      *(short8*)(db) = *(const short8*)(sb);
      *(short8*)(db + 8) = *(const short8*)(sb + 8);
      *(short8*)(db + 16) = *(const short8*)(sb + 16);
      *(short8*)(db + 24) = *(const short8*)(sb + 24);
    }
    __syncthreads();
#pragma unroll
    for (int kk = 0; kk < 2; ++kk) {
      f16x8 a[4], b[4];
#pragma unroll
      for (int m = 0; m < 4; ++m)
        a[m] = *(const f16x8*)(As + (wr * 64 + m * 16 + lr) * LDP + (kk << 5) + (lq << 3));
#pragma unroll
      for (int n = 0; n < 4; ++n)
        b[n] = *(const f16x8*)(Bs + (wc * 64 + n * 16 + lr) * LDP + (kk << 5) + (lq << 3));
#pragma unroll
      for (int m = 0; m < 4; ++m)
#pragma unroll
        for (int n = 0; n < 4; ++n)
          acc[m][n] = __builtin_amdgcn_mfma_f32_16x16x32_f16(a[m], b[n], acc[m][n], 0, 0, 0);
    }
    __syncthreads();
  }
  const int b = bn0 >> 10;
  const int nb = bn0 & 1023;
  float a1v[4], a2v[4];
#pragma unroll
  for (int n = 0; n < 4; ++n) {
    int d = wc * 64 + n * 16 + lr;
    a1v[n] = a1[(head << 7) + d];
    a2v[n] = a2[(head << 7) + d];
  }
#pragma unroll
  for (int m = 0; m < 4; ++m)
#pragma unroll
    for (int r = 0; r < 4; ++r) {
      float v1 = 0.f, v2 = 0.f;
#pragma unroll
      for (int n = 0; n < 4; ++n) {
        v1 += acc[m][n][r] * a1v[n];
        v2 += acc[m][n][r] * a2v[n];
      }
#pragma unroll
      for (int off = 1; off < 16; off <<= 1) {
        v1 += __shfl_xor(v1, off);
        v2 += __shfl_xor(v2, off);
      }
      if (lr == 0) {
        int row = wr * 64 + m * 16 + (lq << 2) + r;
        sred[wc][0][row] = v1;
        sred[wc][1][row] = v2;
      }
    }
#pragma unroll
  for (int m = 0; m < 4; ++m) {
    int nrow = nb + wr * 64 + m * 16 + (lq << 2);
#pragma unroll
    for (int n = 0; n < 4; ++n) {
      int d = wc * 64 + n * 16 + lr;
      long base = ((long)((((b << 2) + head) << 7) + d) << 10) + nrow;
      short4v v;
      v[0] = f2h(acc[m][n][0]); v[1] = f2h(acc[m][n][1]);
      v[2] = f2h(acc[m][n][2]); v[3] = f2h(acc[m][n][3]);
      *(short4v*)(hT + base) = v;
    }
  }
  __syncthreads();
  {
    const int bh_ = (b << 2) + head;
    if (t < 128)
      s1g[(bh_ << 10) + nb + t] = sred[0][0][t] + sred[1][0][t];
    else
      s2g[(bh_ << 10) + nb + (t - 128)] = sred[0][1][t - 128] + sred[1][1][t - 128];
  }
}

// ---------------- attention (k_ef fused into prologue) ----------------
// grid (64 bh, 8 it). Wave owns 32-row strip (m=2) x full 128 d (n=8).
// Prologue: load s2 slice, block-reduce max, compute E/F f16 into LDS
// (overlapped with the in-flight glds of bufs 0/1). Main loop: 3 LDS
// buffers, prefetch distance 2, counted vmcnt(4), single barrier/iter.
__global__ __launch_bounds__(256) void k_attn(const short* __restrict__ hT,
                                              const float* __restrict__ s1,
                                              const float* __restrict__ s2g,
                                              short* __restrict__ attn) {
  __shared__ __align__(16) short Hs[3][128 * 64];
  __shared__ __align__(16) _Float16 Esh[1024];
  __shared__ __align__(16) _Float16 Fsh[1024];
  __shared__ float red[4];
  const int bh = blockIdx.x, it = blockIdx.y;
  const int i0 = it << 7;
  const int t = threadIdx.x;
  const int w = t >> 6, lane = t & 63, lr = lane & 15, lq = lane >> 4;

  const short* hTb = hT + ((long)bh << 17);
  const int grow = (w << 5) + (lane >> 3);
  const int gcol = ((lane & 7) ^ (lane >> 3)) << 3;
  const short* gsrc = hTb + ((long)grow << 10) + gcol;

#define STAGE(buf, J0)                                             \
  do {                                                             \
    short* ldsb = &Hs[buf][(w << 5) << 6];                         \
    _Pragma("unroll") for (int i_ = 0; i_ < 4; ++i_)               \
        GLDS16(gsrc + ((long)(i_ << 3) << 10) + (J0),              \
               ldsb + ((i_ << 3) << 6));                           \
  } while (0)

  STAGE(0, 0);
  STAGE(1, 64);

  // fused k_ef: max(s2) then E=exp(s2-max), F=exp(.2(s2-max)) into LDS
  f32x4 v2 = *(const f32x4*)&s2g[(bh << 10) + (t << 2)];
  {
    float mx = fmaxf(fmaxf(v2[0], v2[1]), fmaxf(v2[2], v2[3]));
#pragma unroll
    for (int off = 1; off < 64; off <<= 1) mx = fmaxf(mx, __shfl_xor(mx, off));
    if ((t & 63) == 0) red[t >> 6] = mx;
  }
  __syncthreads();
  const float smax = fmaxf(fmaxf(red[0], red[1]), fmaxf(red[2], red[3]));
  {
    short4v e, f;
#pragma unroll
    for (int q = 0; q < 4; ++q) {
      e[q] = f2h(__expf(v2[q] - smax));
      f[q] = f2h(__expf(0.2f * (v2[q] - smax)));
    }
    *(short4v*)&Esh[t << 2] = e;
    *(short4v*)&Fsh[t << 2] = f;
  }

  f16x8 Ai8[2], Bi8[2];
  const f16x2 one2 = {(_Float16)1.f, (_Float16)1.f};
  f16x8 dmask[2];
  float dsum[2] = {0.f, 0.f};
#pragma unroll
  for (int m = 0; m < 2; ++m) {
    const int rblk = (w << 5) + (m << 4) + lr;
    float s1v = s1[(bh << 10) + i0 + rblk];
    float x = s1v + smax;
    float mi = fmaxf(x, 0.2f * x);  // upper bound of row max (lrelu monotone)
    _Float16 A_ = (_Float16)__expf(x - mi);
    _Float16 B_ = (_Float16)__expf(0.2f * x - mi);
#pragma unroll
    for (int e = 0; e < 8; ++e) { Ai8[m][e] = A_; Bi8[m][e] = B_; }
    const int lqz = ((m << 1) + (lr >> 3)) & 3, ez = lr & 7;
#pragma unroll
    for (int e = 0; e < 8; ++e)
      dmask[m][e] = (lq == lqz && e == ez) ? (_Float16)0.f : (_Float16)1.f;
  }
  const int jtd = (it << 1) + (w >> 1);  // wave-uniform diagonal j-tile
  const int kkd = w & 1;                 // wave-uniform diag k-half
  f32x4 acc[2][8] = {};
  __syncthreads();  // prologue: bufs 0,1 + E/F all resident

#define TILE(buf, jt, DIAG)                                                    \
  do {                                                                         \
    _Pragma("unroll") for (int kk = 0; kk < 2; ++kk) {                         \
      const int ebase = ((jt) << 6) + (kk << 5) + (lq << 3);                   \
      f16x8 ev8 = *(const f16x8*)&Esh[ebase];                                  \
      f16x8 fv8 = *(const f16x8*)&Fsh[ebase];                                  \
      f16x8 bf[8];                                                             \
      _Pragma("unroll") for (int n = 0; n < 8; ++n) {                          \
        const int r_ = (n << 4) + lr;                                          \
        const int slot_ = ((kk << 2) + lq) ^ (r_ & 7);                         \
        bf[n] = *(const f16x8*)(&Hs[buf][(r_ << 6) + (slot_ << 3)]);           \
      }                                                                        \
      f16x8 af[2];                                                             \
      _Pragma("unroll") for (int m = 0; m < 2; ++m) {                          \
        f16x8 pm = __builtin_elementwise_max(Ai8[m] * ev8, Bi8[m] * fv8);      \
        if ((DIAG) && kk == kkd) pm = pm * dmask[m];                           \
        af[m] = pm;                                                            \
        h8u u_; u_.v = pm;                                                     \
        _Pragma("unroll") for (int p = 0; p < 4; ++p)                          \
            dsum[m] = FDOT2(u_.h[p], one2, dsum[m]);                           \
      }                                                                        \
      _Pragma("unroll") for (int m = 0; m < 2; ++m)                            \
        _Pragma("unroll") for (int n = 0; n < 8; ++n)                          \
            acc[m][n] = __builtin_amdgcn_mfma_f32_16x16x32_f16(                \
                af[m], bf[n], acc[m][n], 0, 0, 0);                             \
    }                                                                          \
  } while (0)

  int cur = 0;
#pragma unroll 1
  for (int jt = 0; jt < 16; ++jt) {
    if (jt < 15) {
      asm volatile("s_waitcnt vmcnt(4)" ::: "memory");  // own tile-jt loads in
    } else {
      asm volatile("s_waitcnt vmcnt(0)" ::: "memory");
    }
    __builtin_amdgcn_s_barrier();   // all waves: buf[cur] fully staged AND
                                    // all waves done reading buf[(jt+2)%3]
    if (jt < 14) STAGE((cur == 0 ? 2 : cur - 1), (jt + 2) << 6);
    __builtin_amdgcn_s_setprio(1);
    TILE(cur, jt, jt == jtd);
    __builtin_amdgcn_s_setprio(0);
    cur = (cur == 2) ? 0 : cur + 1;
  }

  const int b = bh >> 2, head = bh & 3;
#pragma unroll
  for (int m = 0; m < 2; ++m) {
    float s = dsum[m];
    s += __shfl_xor(s, 16);
    s += __shfl_xor(s, 32);  // all lq-replica lanes hold the row sum
    float rs = 1.f / s;
    f32x4 d4;
#pragma unroll
    for (int q = 0; q < 4; ++q)
      d4[q] = __shfl(rs, (lane & 48) | ((lq << 2) + q));
    int irow = i0 + (w << 5) + (m << 4) + (lq << 2);
#pragma unroll
    for (int n = 0; n < 8; ++n) {
      int d = (n << 4) + lr;
      long base = ((long)((b << 10) + irow) << 9) + (head << 7) + d;
      attn[base] = f2h(acc[m][n][0] * d4[0]);
      attn[base + 512] = f2h(acc[m][n][1] * d4[1]);
      attn[base + 1024] = f2h(acc[m][n][2] * d4[2]);
      attn[base + 1536] = f2h(acc[m][n][3] * d4[3]);
    }
  }
#undef STAGE
#undef TILE
}

// ---------------- out-proj + bias (+residual) + LN (+relu) ----------------
// 32-row blocks, grid 512 (2 blocks/CU). Wave owns 16 rows x 64 cols; LN via
// cross-wave LDS partial-sum exchange.
template <int HAS_RES, int DO_RELU, int WRITE_OUT>
__global__ __launch_bounds__(256) void k_outproj(const short* __restrict__ attn,
                                                 const short* __restrict__ WoT,
                                                 const float* __restrict__ bo,
                                                 const float* __restrict__ gamma,
                                                 const float* __restrict__ beta,
                                                 float* __restrict__ xf,
                                                 short* __restrict__ xh,
                                                 float* __restrict__ outp) {
  __shared__ __align__(16) short As[32 * LDP];
  __shared__ __align__(16) short Bs[128 * LDP];
  __shared__ float sredS[2][32], sredQ[2][32];
  const int t = threadIdx.x;
  const int bn0 = blockIdx.x << 5;
  const int w = t >> 6, lane = t & 63, lr = lane & 15, lq = lane >> 4;
  const int wm = w & 1, wn = w >> 1;
  f32x4 acc[4] = {};
  const int rowA = t >> 3, chA = (t & 7) << 3;
  const int rowB = t >> 1, chB = (t & 1) << 5;
  for (int k0 = 0; k0 < 512; k0 += 64) {
    {
      const short* sa = attn + ((long)(bn0 + rowA) << 9) + k0 + chA;
      *(short8*)(As + rowA * LDP + chA) = *(const short8*)(sa);
      const short* sb = WoT + (rowB << 9) + k0 + chB;
      short* db = Bs + rowB * LDP + chB;
      *(short8*)(db) = *(const short8*)(sb);
      *(short8*)(db + 8) = *(const short8*)(sb + 8);
      *(short8*)(db + 16) = *(const short8*)(sb + 16);
      *(short8*)(db + 24) = *(const short8*)(sb + 24);
    }
    __syncthreads();
#pragma unroll
    for (int kk = 0; kk < 2; ++kk) {
      f16x8 a = *(const f16x8*)(As + ((wm << 4) + lr) * LDP + (kk << 5) + (lq << 3));
#pragma unroll
      for (int nn = 0; nn < 4; ++nn) {
        f16x8 b = *(const f16x8*)(Bs + ((wn << 6) + (nn << 4) + lr) * LDP + (kk << 5) + (lq << 3));
        acc[nn] = __builtin_amdgcn_mfma_f32_16x16x32_f16(a, b, acc[nn], 0, 0, 0);
      }
    }
    __syncthreads();
  }
  float v[4][4], gam[4], bet[4];
#pragma unroll
  for (int nn = 0; nn < 4; ++nn) {
    int d = (wn << 6) + (nn << 4) + lr;
    float bv = bo[d];
    gam[nn] = gamma[d];
    bet[nn] = beta[d];
#pragma unroll
    for (int r = 0; r < 4; ++r) {
      float x = acc[nn][r] + bv;
      if (HAS_RES) x += xf[((bn0 + (wm << 4) + (lq << 2) + r) << 7) + d];
      v[nn][r] = x;
    }
  }
#pragma unroll
  for (int r = 0; r < 4; ++r) {
    float s = 0.f, q = 0.f;
#pragma unroll
    for (int nn = 0; nn < 4; ++nn) { s += v[nn][r]; q += v[nn][r] * v[nn][r]; }
#pragma unroll
    for (int mk = 1; mk < 16; mk <<= 1) { s += __shfl_xor(s, mk); q += __shfl_xor(q, mk); }
    if (lr == 0) {
      int row = (wm << 4) + (lq << 2) + r;
      sredS[wn][row] = s;
      sredQ[wn][row] = q;
    }
  }
  __syncthreads();
#pragma unroll
  for (int r = 0; r < 4; ++r) {
    int rloc = (wm << 4) + (lq << 2) + r;
    float S = sredS[0][rloc] + sredS[1][rloc];
    float Q = sredQ[0][rloc] + sredQ[1][rloc];
    float mean = S * 0.0078125f;
    float var = Q * 0.0078125f - mean * mean;
    float rstd = rsqrtf(var + 1e-5f);
    int row = bn0 + rloc;
#pragma unroll
    for (int nn = 0; nn < 4; ++nn) {
      int d = (wn << 6) + (nn << 4) + lr;
      float o = (v[nn][r] - mean) * rstd * gam[nn] + bet[nn];
      if (DO_RELU) o = fmaxf(o, 0.f);
      if (WRITE_OUT) {
        outp[(row << 7) + d] = o;
      } else {
        xh[(row << 7) + d] = f2h(o);
        xf[(row << 7) + d] = o;
      }
    }
  }
}

extern "C" void kernel_launch(void* const* d_in, const int* in_sizes, int n_in,
                              void* d_out, int out_size, void* d_ws, size_t ws_size,
                              hipStream_t stream) {
  const float* nf = (const float*)d_in[0];
  const float* Wp = (const float*)d_in[1];
  const float* bp = (const float*)d_in[2];
  const float* W = (const float*)d_in[3];
  const float* a1 = (const float*)d_in[4];
  const float* a2 = (const float*)d_in[5];
  const float* Wo = (const float*)d_in[6];
  const float* bo = (const float*)d_in[7];
  const float* gamma = (const float*)d_in[8];
  const float* beta = (const float*)d_in[9];
  float* outp = (float*)d_out;

  char* ws = (char*)d_ws;
  short* xh = (short*)(ws);                                    // 4 MB
  float* xf = (float*)(ws + (4ll << 20));                      // 8 MB
  short* hT = (short*)(ws + (12ll << 20));                     // 16 MB
  short* attn = (short*)(ws + (28ll << 20));                   // 16 MB
  float* s1 = (float*)(ws + (44ll << 20));                     // 256 KB
  float* s2g = (float*)(ws + (44ll << 20) + (256ll << 10));    // 256 KB
  short* WT = (short*)(ws + (45ll << 20));                     // 384 KB
  short* WoT = (short*)(ws + (45ll << 20) + 393216);           // 384 KB

  k_tw<<<1536, 256, 0, stream>>>(W, Wo, WT, WoT);
  k_inproj<<<8192, 256, 0, stream>>>(nf, Wp, bp, xh);
  for (int l = 0; l < 3; ++l) {
    k_gemm_h<<<dim3(128, 4), 256, 0, stream>>>(xh, WT + l * 65536, hT,
                                               a1 + l * 512, a2 + l * 512, s1, s2g);
    k_attn<<<dim3(64, 8), 256, 0, stream>>>(hT, s1, s2g, attn);
    if (l == 0)
      k_outproj<0, 1, 0><<<512, 256, 0, stream>>>(attn, WoT + l * 65536, bo + l * 128,
                                                  gamma + l * 128, beta + l * 128, xf, xh, outp);
    else if (l == 1)
      k_outproj<1, 1, 0><<<512, 256, 0, stream>>>(attn, WoT + l * 65536, bo + l * 128,
                                                  gamma + l * 128, beta + l * 128, xf, xh, outp);
    else
      k_outproj<1, 0, 1><<<512, 256, 0, stream>>>(attn, WoT + l * 65536, bo + l * 128,
                                                  gamma + l * 128, beta + l * 128, xf, xh, outp);
  }
}

// Round 21
// 156.132 us; speedup vs baseline: 1.3057x; 1.0194x over previous
//
#include <hip/hip_runtime.h>
#include <hip/hip_bf16.h>

typedef __attribute__((ext_vector_type(8))) _Float16 f16x8;
typedef __attribute__((ext_vector_type(2))) _Float16 f16x2;
typedef __attribute__((ext_vector_type(8))) short short8;
typedef __attribute__((ext_vector_type(4))) short short4v;
typedef __attribute__((ext_vector_type(4))) float f32x4;

#define LDP 72   // LDS row stride (shorts) for reg-staged GEMM tiles

typedef const __attribute__((address_space(1))) unsigned int* gas_ptr;
typedef __attribute__((address_space(3))) unsigned int* las_ptr;
#define GLDS16(gp, lp) \
  __builtin_amdgcn_global_load_lds((gas_ptr)(gp), (las_ptr)(lp), 16, 0, 0)

#if __has_builtin(__builtin_amdgcn_fdot2)
#define FDOT2(a, b, c) __builtin_amdgcn_fdot2((a), (b), (c), false)
#else
__device__ __forceinline__ float FDOT2(f16x2 a, f16x2 b, float c) {
  return c + (float)a[0] * (float)b[0] + (float)a[1] * (float)b[1];
}
#endif

union h8u {
  f16x8 v;
  f16x2 h[4];
};

__device__ __forceinline__ short f2h(float f) {
  union { _Float16 h; short s; } u; u.h = (_Float16)f; return u.s;
}
__device__ __forceinline__ float h2f(short s) {
  union { short s; _Float16 h; } u; u.s = s; return (float)u.h;
}

// ------- init: weight transpose/cvt (blocks 0..1535) + input proj (rest) ----
__global__ __launch_bounds__(256) void k_init(const float* __restrict__ W,
                                              const float* __restrict__ Wo,
                                              const float* __restrict__ nf,
                                              const float* __restrict__ Wp,
                                              const float* __restrict__ bp,
                                              short* __restrict__ WT,
                                              short* __restrict__ WoT,
                                              short* __restrict__ xh) {
  if (blockIdx.x < 1536) {
    int idx = blockIdx.x * 256 + threadIdx.x;
    if (idx < 3 * 512 * 128) {
      int l = idx >> 16, rem = idx & 65535;
      int c = rem >> 7, k = rem & 127;
      int h = c >> 7, o = c & 127;
      WT[idx] = f2h(W[(((l * 4 + h) * 128 + k) << 7) + o]);
    } else {
      int j = idx - 3 * 512 * 128;
      int l = j >> 16, rem = j & 65535;
      int d = rem >> 9, c = rem & 511;
      WoT[j] = f2h(Wo[((l * 512 + c) << 7) + d]);
    }
  } else {
    int idx = (blockIdx.x - 1536) * 256 + threadIdx.x;
    int bn = idx >> 7, d = idx & 127;
    float acc = bp[d];
    const float* nr = nf + bn * 7;
#pragma unroll
    for (int i = 0; i < 7; ++i) acc += nr[i] * Wp[(i << 7) + d];
    xh[idx] = f2h(acc);
  }
}

// ---------------- head projection + fused s1/s2 ----------------
__global__ __launch_bounds__(256) void k_gemm_h(const short* __restrict__ xh,
                                                const short* __restrict__ WT,
                                                short* __restrict__ hT,
                                                const float* __restrict__ a1,
                                                const float* __restrict__ a2,
                                                float* __restrict__ s1g,
                                                float* __restrict__ s2g) {
  __shared__ __align__(16) short As[128 * LDP];
  __shared__ __align__(16) short Bs[128 * LDP];
  __shared__ float sred[2][2][128];
  const int t = threadIdx.x;
  const int bn0 = blockIdx.x << 7;
  const int head = blockIdx.y;
  const int c0 = head << 7;
  const int w = t >> 6, lane = t & 63, lr = lane & 15, lq = lane >> 4;
  const int wr = w >> 1, wc = w & 1;
  f32x4 acc[4][4] = {};
  for (int k0 = 0; k0 < 128; k0 += 64) {
    const int row = t >> 1, half = (t & 1) << 5;
    {
      const short* sa = xh + ((bn0 + row) << 7) + k0 + half;
      short* da = As + row * LDP + half;
      *(short8*)(da) = *(const short8*)(sa);
      *(short8*)(da + 8) = *(const short8*)(sa + 8);
      *(short8*)(da + 16) = *(const short8*)(sa + 16);
      *(short8*)(da + 24) = *(const short8*)(sa + 24);
      const short* sb = WT + ((c0 + row) << 7) + k0 + half;
      short* db = Bs + row * LDP + half;
      *(short8*)(db) = *(const short8*)(sb);
      *(short8*)(db + 8) = *(const short8*)(sb + 8);
      *(short8*)(db + 16) = *(const short8*)(sb + 16);
      *(short8*)(db + 24) = *(const short8*)(sb + 24);
    }
    __syncthreads();
#pragma unroll
    for (int kk = 0; kk < 2; ++kk) {
      f16x8 a[4], b[4];
#pragma unroll
      for (int m = 0; m < 4; ++m)
        a[m] = *(const f16x8*)(As + (wr * 64 + m * 16 + lr) * LDP + (kk << 5) + (lq << 3));
#pragma unroll
      for (int n = 0; n < 4; ++n)
        b[n] = *(const f16x8*)(Bs + (wc * 64 + n * 16 + lr) * LDP + (kk << 5) + (lq << 3));
#pragma unroll
      for (int m = 0; m < 4; ++m)
#pragma unroll
        for (int n = 0; n < 4; ++n)
          acc[m][n] = __builtin_amdgcn_mfma_f32_16x16x32_f16(a[m], b[n], acc[m][n], 0, 0, 0);
    }
    __syncthreads();
  }
  const int b = bn0 >> 10;
  const int nb = bn0 & 1023;
  float a1v[4], a2v[4];
#pragma unroll
  for (int n = 0; n < 4; ++n) {
    int d = wc * 64 + n * 16 + lr;
    a1v[n] = a1[(head << 7) + d];
    a2v[n] = a2[(head << 7) + d];
  }
#pragma unroll
  for (int m = 0; m < 4; ++m)
#pragma unroll
    for (int r = 0; r < 4; ++r) {
      float v1 = 0.f, v2 = 0.f;
#pragma unroll
      for (int n = 0; n < 4; ++n) {
        v1 += acc[m][n][r] * a1v[n];
        v2 += acc[m][n][r] * a2v[n];
      }
#pragma unroll
      for (int off = 1; off < 16; off <<= 1) {
        v1 += __shfl_xor(v1, off);
        v2 += __shfl_xor(v2, off);
      }
      if (lr == 0) {
        int row = wr * 64 + m * 16 + (lq << 2) + r;
        sred[wc][0][row] = v1;
        sred[wc][1][row] = v2;
      }
    }
#pragma unroll
  for (int m = 0; m < 4; ++m) {
    int nrow = nb + wr * 64 + m * 16 + (lq << 2);
#pragma unroll
    for (int n = 0; n < 4; ++n) {
      int d = wc * 64 + n * 16 + lr;
      long base = ((long)((((b << 2) + head) << 7) + d) << 10) + nrow;
      short4v v;
      v[0] = f2h(acc[m][n][0]); v[1] = f2h(acc[m][n][1]);
      v[2] = f2h(acc[m][n][2]); v[3] = f2h(acc[m][n][3]);
      *(short4v*)(hT + base) = v;
    }
  }
  __syncthreads();
  {
    const int bh_ = (b << 2) + head;
    if (t < 128)
      s1g[(bh_ << 10) + nb + t] = sred[0][0][t] + sred[1][0][t];
    else
      s2g[(bh_ << 10) + nb + (t - 128)] = sred[0][1][t - 128] + sred[1][1][t - 128];
  }
}

// ---------------- attention (k_ef fused into prologue) ----------------
// grid (64 bh, 8 it). Wave owns 32-row strip (m=2) x full 128 d (n=8).
// Prologue: load s2 slice, block-reduce max, compute E/F f16 into LDS
// (overlapped with the in-flight glds of bufs 0/1). Main loop: 3 LDS
// buffers, prefetch distance 2, counted vmcnt(4), single barrier/iter.
__global__ __launch_bounds__(256) void k_attn(const short* __restrict__ hT,
                                              const float* __restrict__ s1,
                                              const float* __restrict__ s2g,
                                              short* __restrict__ attn) {
  __shared__ __align__(16) short Hs[3][128 * 64];
  __shared__ __align__(16) _Float16 Esh[1024];
  __shared__ __align__(16) _Float16 Fsh[1024];
  __shared__ float red[4];
  const int bh = blockIdx.x, it = blockIdx.y;
  const int i0 = it << 7;
  const int t = threadIdx.x;
  const int w = t >> 6, lane = t & 63, lr = lane & 15, lq = lane >> 4;

  const short* hTb = hT + ((long)bh << 17);
  const int grow = (w << 5) + (lane >> 3);
  const int gcol = ((lane & 7) ^ (lane >> 3)) << 3;
  const short* gsrc = hTb + ((long)grow << 10) + gcol;

#define STAGE(buf, J0)                                             \
  do {                                                             \
    short* ldsb = &Hs[buf][(w << 5) << 6];                         \
    _Pragma("unroll") for (int i_ = 0; i_ < 4; ++i_)               \
        GLDS16(gsrc + ((long)(i_ << 3) << 10) + (J0),              \
               ldsb + ((i_ << 3) << 6));                           \
  } while (0)

  STAGE(0, 0);
  STAGE(1, 64);

  // fused k_ef: max(s2) then E=exp(s2-max), F=exp(.2(s2-max)) into LDS
  f32x4 v2 = *(const f32x4*)&s2g[(bh << 10) + (t << 2)];
  {
    float mx = fmaxf(fmaxf(v2[0], v2[1]), fmaxf(v2[2], v2[3]));
#pragma unroll
    for (int off = 1; off < 64; off <<= 1) mx = fmaxf(mx, __shfl_xor(mx, off));
    if ((t & 63) == 0) red[t >> 6] = mx;
  }
  __syncthreads();
  const float smax = fmaxf(fmaxf(red[0], red[1]), fmaxf(red[2], red[3]));
  {
    short4v e, f;
#pragma unroll
    for (int q = 0; q < 4; ++q) {
      e[q] = f2h(__expf(v2[q] - smax));
      f[q] = f2h(__expf(0.2f * (v2[q] - smax)));
    }
    *(short4v*)&Esh[t << 2] = e;
    *(short4v*)&Fsh[t << 2] = f;
  }

  f16x8 Ai8[2], Bi8[2];
  const f16x2 one2 = {(_Float16)1.f, (_Float16)1.f};
  f16x8 dmask[2];
  float dsum[2] = {0.f, 0.f};
#pragma unroll
  for (int m = 0; m < 2; ++m) {
    const int rblk = (w << 5) + (m << 4) + lr;
    float s1v = s1[(bh << 10) + i0 + rblk];
    float x = s1v + smax;
    float mi = fmaxf(x, 0.2f * x);  // upper bound of row max (lrelu monotone)
    _Float16 A_ = (_Float16)__expf(x - mi);
    _Float16 B_ = (_Float16)__expf(0.2f * x - mi);
#pragma unroll
    for (int e = 0; e < 8; ++e) { Ai8[m][e] = A_; Bi8[m][e] = B_; }
    const int lqz = ((m << 1) + (lr >> 3)) & 3, ez = lr & 7;
#pragma unroll
    for (int e = 0; e < 8; ++e)
      dmask[m][e] = (lq == lqz && e == ez) ? (_Float16)0.f : (_Float16)1.f;
  }
  const int jtd = (it << 1) + (w >> 1);  // wave-uniform diagonal j-tile
  const int kkd = w & 1;                 // wave-uniform diag k-half
  f32x4 acc[2][8] = {};
  __syncthreads();  // prologue: bufs 0,1 + E/F all resident

#define TILE(buf, jt, DIAG)                                                    \
  do {                                                                         \
    _Pragma("unroll") for (int kk = 0; kk < 2; ++kk) {                         \
      const int ebase = ((jt) << 6) + (kk << 5) + (lq << 3);                   \
      f16x8 ev8 = *(const f16x8*)&Esh[ebase];                                  \
      f16x8 fv8 = *(const f16x8*)&Fsh[ebase];                                  \
      f16x8 bf[8];                                                             \
      _Pragma("unroll") for (int n = 0; n < 8; ++n) {                          \
        const int r_ = (n << 4) + lr;                                          \
        const int slot_ = ((kk << 2) + lq) ^ (r_ & 7);                         \
        bf[n] = *(const f16x8*)(&Hs[buf][(r_ << 6) + (slot_ << 3)]);           \
      }                                                                        \
      f16x8 af[2];                                                             \
      _Pragma("unroll") for (int m = 0; m < 2; ++m) {                          \
        f16x8 pm = __builtin_elementwise_max(Ai8[m] * ev8, Bi8[m] * fv8);      \
        if ((DIAG) && kk == kkd) pm = pm * dmask[m];                           \
        af[m] = pm;                                                            \
        h8u u_; u_.v = pm;                                                     \
        _Pragma("unroll") for (int p = 0; p < 4; ++p)                          \
            dsum[m] = FDOT2(u_.h[p], one2, dsum[m]);                           \
      }                                                                        \
      _Pragma("unroll") for (int m = 0; m < 2; ++m)                            \
        _Pragma("unroll") for (int n = 0; n < 8; ++n)                          \
            acc[m][n] = __builtin_amdgcn_mfma_f32_16x16x32_f16(                \
                af[m], bf[n], acc[m][n], 0, 0, 0);                             \
    }                                                                          \
  } while (0)

  int cur = 0;
#pragma unroll 1
  for (int jt = 0; jt < 16; ++jt) {
    if (jt < 15) {
      asm volatile("s_waitcnt vmcnt(4)" ::: "memory");  // own tile-jt loads in
    } else {
      asm volatile("s_waitcnt vmcnt(0)" ::: "memory");
    }
    __builtin_amdgcn_s_barrier();   // all waves: buf[cur] fully staged AND
                                    // all waves done reading buf[(jt+2)%3]
    if (jt < 14) STAGE((cur == 0 ? 2 : cur - 1), (jt + 2) << 6);
    __builtin_amdgcn_s_setprio(1);
    TILE(cur, jt, jt == jtd);
    __builtin_amdgcn_s_setprio(0);
    cur = (cur == 2) ? 0 : cur + 1;
  }

  const int b = bh >> 2, head = bh & 3;
#pragma unroll
  for (int m = 0; m < 2; ++m) {
    float s = dsum[m];
    s += __shfl_xor(s, 16);
    s += __shfl_xor(s, 32);  // all lq-replica lanes hold the row sum
    float rs = 1.f / s;
    f32x4 d4;
#pragma unroll
    for (int q = 0; q < 4; ++q)
      d4[q] = __shfl(rs, (lane & 48) | ((lq << 2) + q));
    int irow = i0 + (w << 5) + (m << 4) + (lq << 2);
#pragma unroll
    for (int n = 0; n < 8; ++n) {
      int d = (n << 4) + lr;
      long base = ((long)((b << 10) + irow) << 9) + (head << 7) + d;
      attn[base] = f2h(acc[m][n][0] * d4[0]);
      attn[base + 512] = f2h(acc[m][n][1] * d4[1]);
      attn[base + 1024] = f2h(acc[m][n][2] * d4[2]);
      attn[base + 1536] = f2h(acc[m][n][3] * d4[3]);
    }
  }
#undef STAGE
#undef TILE
}

// ---------------- out-proj + bias (+residual) + LN (+relu) ----------------
// 32-row blocks, grid 512 (2 blocks/CU). Wave owns 16 rows x 64 cols; LN via
// cross-wave LDS partial-sum exchange.
template <int HAS_RES, int DO_RELU, int WRITE_OUT>
__global__ __launch_bounds__(256) void k_outproj(const short* __restrict__ attn,
                                                 const short* __restrict__ WoT,
                                                 const float* __restrict__ bo,
                                                 const float* __restrict__ gamma,
                                                 const float* __restrict__ beta,
                                                 float* __restrict__ xf,
                                                 short* __restrict__ xh,
                                                 float* __restrict__ outp) {
  __shared__ __align__(16) short As[32 * LDP];
  __shared__ __align__(16) short Bs[128 * LDP];
  __shared__ float sredS[2][32], sredQ[2][32];
  const int t = threadIdx.x;
  const int bn0 = blockIdx.x << 5;
  const int w = t >> 6, lane = t & 63, lr = lane & 15, lq = lane >> 4;
  const int wm = w & 1, wn = w >> 1;
  f32x4 acc[4] = {};
  const int rowA = t >> 3, chA = (t & 7) << 3;
  const int rowB = t >> 1, chB = (t & 1) << 5;
  for (int k0 = 0; k0 < 512; k0 += 64) {
    {
      const short* sa = attn + ((long)(bn0 + rowA) << 9) + k0 + chA;
      *(short8*)(As + rowA * LDP + chA) = *(const short8*)(sa);
      const short* sb = WoT + (rowB << 9) + k0 + chB;
      short* db = Bs + rowB * LDP + chB;
      *(short8*)(db) = *(const short8*)(sb);
      *(short8*)(db + 8) = *(const short8*)(sb + 8);
      *(short8*)(db + 16) = *(const short8*)(sb + 16);
      *(short8*)(db + 24) = *(const short8*)(sb + 24);
    }
    __syncthreads();
#pragma unroll
    for (int kk = 0; kk < 2; ++kk) {
      f16x8 a = *(const f16x8*)(As + ((wm << 4) + lr) * LDP + (kk << 5) + (lq << 3));
#pragma unroll
      for (int nn = 0; nn < 4; ++nn) {
        f16x8 b = *(const f16x8*)(Bs + ((wn << 6) + (nn << 4) + lr) * LDP + (kk << 5) + (lq << 3));
        acc[nn] = __builtin_amdgcn_mfma_f32_16x16x32_f16(a, b, acc[nn], 0, 0, 0);
      }
    }
    __syncthreads();
  }
  float v[4][4], gam[4], bet[4];
#pragma unroll
  for (int nn = 0; nn < 4; ++nn) {
    int d = (wn << 6) + (nn << 4) + lr;
    float bv = bo[d];
    gam[nn] = gamma[d];
    bet[nn] = beta[d];
#pragma unroll
    for (int r = 0; r < 4; ++r) {
      float x = acc[nn][r] + bv;
      if (HAS_RES) x += xf[((bn0 + (wm << 4) + (lq << 2) + r) << 7) + d];
      v[nn][r] = x;
    }
  }
#pragma unroll
  for (int r = 0; r < 4; ++r) {
    float s = 0.f, q = 0.f;
#pragma unroll
    for (int nn = 0; nn < 4; ++nn) { s += v[nn][r]; q += v[nn][r] * v[nn][r]; }
#pragma unroll
    for (int mk = 1; mk < 16; mk <<= 1) { s += __shfl_xor(s, mk); q += __shfl_xor(q, mk); }
    if (lr == 0) {
      int row = (wm << 4) + (lq << 2) + r;
      sredS[wn][row] = s;
      sredQ[wn][row] = q;
    }
  }
  __syncthreads();
#pragma unroll
  for (int r = 0; r < 4; ++r) {
    int rloc = (wm << 4) + (lq << 2) + r;
    float S = sredS[0][rloc] + sredS[1][rloc];
    float Q = sredQ[0][rloc] + sredQ[1][rloc];
    float mean = S * 0.0078125f;
    float var = Q * 0.0078125f - mean * mean;
    float rstd = rsqrtf(var + 1e-5f);
    int row = bn0 + rloc;
#pragma unroll
    for (int nn = 0; nn < 4; ++nn) {
      int d = (wn << 6) + (nn << 4) + lr;
      float o = (v[nn][r] - mean) * rstd * gam[nn] + bet[nn];
      if (DO_RELU) o = fmaxf(o, 0.f);
      if (WRITE_OUT) {
        outp[(row << 7) + d] = o;
      } else {
        xh[(row << 7) + d] = f2h(o);
        xf[(row << 7) + d] = o;
      }
    }
  }
}

extern "C" void kernel_launch(void* const* d_in, const int* in_sizes, int n_in,
                              void* d_out, int out_size, void* d_ws, size_t ws_size,
                              hipStream_t stream) {
  const float* nf = (const float*)d_in[0];
  const float* Wp = (const float*)d_in[1];
  const float* bp = (const float*)d_in[2];
  const float* W = (const float*)d_in[3];
  const float* a1 = (const float*)d_in[4];
  const float* a2 = (const float*)d_in[5];
  const float* Wo = (const float*)d_in[6];
  const float* bo = (const float*)d_in[7];
  const float* gamma = (const float*)d_in[8];
  const float* beta = (const float*)d_in[9];
  float* outp = (float*)d_out;

  char* ws = (char*)d_ws;
  short* xh = (short*)(ws);                                    // 4 MB
  float* xf = (float*)(ws + (4ll << 20));                      // 8 MB
  short* hT = (short*)(ws + (12ll << 20));                     // 16 MB
  short* attn = (short*)(ws + (28ll << 20));                   // 16 MB
  float* s1 = (float*)(ws + (44ll << 20));                     // 256 KB
  float* s2g = (float*)(ws + (44ll << 20) + (256ll << 10));    // 256 KB
  short* WT = (short*)(ws + (45ll << 20));                     // 384 KB
  short* WoT = (short*)(ws + (45ll << 20) + 393216);           // 384 KB

  k_init<<<9728, 256, 0, stream>>>(W, Wo, nf, Wp, bp, WT, WoT, xh);
  for (int l = 0; l < 3; ++l) {
    k_gemm_h<<<dim3(128, 4), 256, 0, stream>>>(xh, WT + l * 65536, hT,
                                               a1 + l * 512, a2 + l * 512, s1, s2g);
    k_attn<<<dim3(64, 8), 256, 0, stream>>>(hT, s1, s2g, attn);
    if (l == 0)
      k_outproj<0, 1, 0><<<512, 256, 0, stream>>>(attn, WoT + l * 65536, bo + l * 128,
                                                  gamma + l * 128, beta + l * 128, xf, xh, outp);
    else if (l == 1)
      k_outproj<1, 1, 0><<<512, 256, 0, stream>>>(attn, WoT + l * 65536, bo + l * 128,
                                                  gamma + l * 128, beta + l * 128, xf, xh, outp);
    else
      k_outproj<1, 0, 1><<<512, 256, 0, stream>>>(attn, WoT + l * 65536, bo + l * 128,
                                                  gamma + l * 128, beta + l * 128, xf, xh, outp);
  }
}

// Round 22
// 155.406 us; speedup vs baseline: 1.3118x; 1.0047x over previous
//
#include <hip/hip_runtime.h>
#include <hip/hip_bf16.h>

typedef __attribute__((ext_vector_type(8))) _Float16 f16x8;
typedef __attribute__((ext_vector_type(2))) _Float16 f16x2;
typedef __attribute__((ext_vector_type(8))) short short8;
typedef __attribute__((ext_vector_type(4))) short short4v;
typedef __attribute__((ext_vector_type(4))) float f32x4;

#define LDP 72   // LDS row stride (shorts) for reg-staged GEMM tiles

typedef const __attribute__((address_space(1))) unsigned int* gas_ptr;
typedef __attribute__((address_space(3))) unsigned int* las_ptr;
#define GLDS16(gp, lp) \
  __builtin_amdgcn_global_load_lds((gas_ptr)(gp), (las_ptr)(lp), 16, 0, 0)

#if __has_builtin(__builtin_amdgcn_fdot2)
#define FDOT2(a, b, c) __builtin_amdgcn_fdot2((a), (b), (c), false)
#else
__device__ __forceinline__ float FDOT2(f16x2 a, f16x2 b, float c) {
  return c + (float)a[0] * (float)b[0] + (float)a[1] * (float)b[1];
}
#endif

union h8u {
  f16x8 v;
  f16x2 h[4];
};

__device__ __forceinline__ short f2h(float f) {
  union { _Float16 h; short s; } u; u.h = (_Float16)f; return u.s;
}
__device__ __forceinline__ float h2f(short s) {
  union { short s; _Float16 h; } u; u.s = s; return (float)u.h;
}

// ------- init: weight transpose/cvt (blocks 0..1535) + input proj (rest) ----
__global__ __launch_bounds__(256) void k_init(const float* __restrict__ W,
                                              const float* __restrict__ Wo,
                                              const float* __restrict__ nf,
                                              const float* __restrict__ Wp,
                                              const float* __restrict__ bp,
                                              short* __restrict__ WT,
                                              short* __restrict__ WoT,
                                              short* __restrict__ xh) {
  if (blockIdx.x < 1536) {
    int idx = blockIdx.x * 256 + threadIdx.x;
    if (idx < 3 * 512 * 128) {
      int l = idx >> 16, rem = idx & 65535;
      int c = rem >> 7, k = rem & 127;
      int h = c >> 7, o = c & 127;
      WT[idx] = f2h(W[(((l * 4 + h) * 128 + k) << 7) + o]);
    } else {
      int j = idx - 3 * 512 * 128;
      int l = j >> 16, rem = j & 65535;
      int d = rem >> 9, c = rem & 511;
      WoT[j] = f2h(Wo[((l * 512 + c) << 7) + d]);
    }
  } else {
    int idx = (blockIdx.x - 1536) * 256 + threadIdx.x;
    int bn = idx >> 7, d = idx & 127;
    float acc = bp[d];
    const float* nr = nf + bn * 7;
#pragma unroll
    for (int i = 0; i < 7; ++i) acc += nr[i] * Wp[(i << 7) + d];
    xh[idx] = f2h(acc);
  }
}

// ---------------- head projection + fused s1/s2 ----------------
__global__ __launch_bounds__(256) void k_gemm_h(const short* __restrict__ xh,
                                                const short* __restrict__ WT,
                                                short* __restrict__ hT,
                                                const float* __restrict__ a1,
                                                const float* __restrict__ a2,
                                                float* __restrict__ s1g,
                                                float* __restrict__ s2g) {
  __shared__ __align__(16) short As[128 * LDP];
  __shared__ __align__(16) short Bs[128 * LDP];
  __shared__ float sred[2][2][128];
  const int t = threadIdx.x;
  const int bn0 = blockIdx.x << 7;
  const int head = blockIdx.y;
  const int c0 = head << 7;
  const int w = t >> 6, lane = t & 63, lr = lane & 15, lq = lane >> 4;
  const int wr = w >> 1, wc = w & 1;
  f32x4 acc[4][4] = {};
  for (int k0 = 0; k0 < 128; k0 += 64) {
    const int row = t >> 1, half = (t & 1) << 5;
    {
      const short* sa = xh + ((bn0 + row) << 7) + k0 + half;
      short* da = As + row * LDP + half;
      *(short8*)(da) = *(const short8*)(sa);
      *(short8*)(da + 8) = *(const short8*)(sa + 8);
      *(short8*)(da + 16) = *(const short8*)(sa + 16);
      *(short8*)(da + 24) = *(const short8*)(sa + 24);
      const short* sb = WT + ((c0 + row) << 7) + k0 + half;
      short* db = Bs + row * LDP + half;
      *(short8*)(db) = *(const short8*)(sb);
      *(short8*)(db + 8) = *(const short8*)(sb + 8);
      *(short8*)(db + 16) = *(const short8*)(sb + 16);
      *(short8*)(db + 24) = *(const short8*)(sb + 24);
    }
    __syncthreads();
#pragma unroll
    for (int kk = 0; kk < 2; ++kk) {
      f16x8 a[4], b[4];
#pragma unroll
      for (int m = 0; m < 4; ++m)
        a[m] = *(const f16x8*)(As + (wr * 64 + m * 16 + lr) * LDP + (kk << 5) + (lq << 3));
#pragma unroll
      for (int n = 0; n < 4; ++n)
        b[n] = *(const f16x8*)(Bs + (wc * 64 + n * 16 + lr) * LDP + (kk << 5) + (lq << 3));
#pragma unroll
      for (int m = 0; m < 4; ++m)
#pragma unroll
        for (int n = 0; n < 4; ++n)
          acc[m][n] = __builtin_amdgcn_mfma_f32_16x16x32_f16(a[m], b[n], acc[m][n], 0, 0, 0);
    }
    __syncthreads();
  }
  const int b = bn0 >> 10;
  const int nb = bn0 & 1023;
  float a1v[4], a2v[4];
#pragma unroll
  for (int n = 0; n < 4; ++n) {
    int d = wc * 64 + n * 16 + lr;
    a1v[n] = a1[(head << 7) + d];
    a2v[n] = a2[(head << 7) + d];
  }
#pragma unroll
  for (int m = 0; m < 4; ++m)
#pragma unroll
    for (int r = 0; r < 4; ++r) {
      float v1 = 0.f, v2 = 0.f;
#pragma unroll
      for (int n = 0; n < 4; ++n) {
        v1 += acc[m][n][r] * a1v[n];
        v2 += acc[m][n][r] * a2v[n];
      }
#pragma unroll
      for (int off = 1; off < 16; off <<= 1) {
        v1 += __shfl_xor(v1, off);
        v2 += __shfl_xor(v2, off);
      }
      if (lr == 0) {
        int row = wr * 64 + m * 16 + (lq << 2) + r;
        sred[wc][0][row] = v1;
        sred[wc][1][row] = v2;
      }
    }
#pragma unroll
  for (int m = 0; m < 4; ++m) {
    int nrow = nb + wr * 64 + m * 16 + (lq << 2);
#pragma unroll
    for (int n = 0; n < 4; ++n) {
      int d = wc * 64 + n * 16 + lr;
      long base = ((long)((((b << 2) + head) << 7) + d) << 10) + nrow;
      short4v v;
      v[0] = f2h(acc[m][n][0]); v[1] = f2h(acc[m][n][1]);
      v[2] = f2h(acc[m][n][2]); v[3] = f2h(acc[m][n][3]);
      *(short4v*)(hT + base) = v;
    }
  }
  __syncthreads();
  {
    const int bh_ = (b << 2) + head;
    if (t < 128)
      s1g[(bh_ << 10) + nb + t] = sred[0][0][t] + sred[1][0][t];
    else
      s2g[(bh_ << 10) + nb + (t - 128)] = sred[0][1][t - 128] + sred[1][1][t - 128];
  }
}

// ---------------- attention (k_ef fused into prologue) ----------------
// grid (64 bh, 8 it). Wave owns 32-row strip (m=2) x full 128 d (n=8).
// Prologue: load s2 slice, block-reduce max, compute E/F f16 into LDS
// (overlapped with the in-flight glds of bufs 0/1). Main loop: 3 LDS
// buffers, prefetch distance 2, counted vmcnt(4), single barrier/iter.
__global__ __launch_bounds__(256) void k_attn(const short* __restrict__ hT,
                                              const float* __restrict__ s1,
                                              const float* __restrict__ s2g,
                                              short* __restrict__ attn) {
  __shared__ __align__(16) short Hs[3][128 * 64];
  __shared__ __align__(16) _Float16 Esh[1024];
  __shared__ __align__(16) _Float16 Fsh[1024];
  __shared__ float red[4];
  const int bh = blockIdx.x, it = blockIdx.y;
  const int i0 = it << 7;
  const int t = threadIdx.x;
  const int w = t >> 6, lane = t & 63, lr = lane & 15, lq = lane >> 4;

  const short* hTb = hT + ((long)bh << 17);
  const int grow = (w << 5) + (lane >> 3);
  const int gcol = ((lane & 7) ^ (lane >> 3)) << 3;
  const short* gsrc = hTb + ((long)grow << 10) + gcol;

#define STAGE(buf, J0)                                             \
  do {                                                             \
    short* ldsb = &Hs[buf][(w << 5) << 6];                         \
    _Pragma("unroll") for (int i_ = 0; i_ < 4; ++i_)               \
        GLDS16(gsrc + ((long)(i_ << 3) << 10) + (J0),              \
               ldsb + ((i_ << 3) << 6));                           \
  } while (0)

  STAGE(0, 0);
  STAGE(1, 64);

  // fused k_ef: max(s2) then E=exp(s2-max), F=exp(.2(s2-max)) into LDS
  f32x4 v2 = *(const f32x4*)&s2g[(bh << 10) + (t << 2)];
  {
    float mx = fmaxf(fmaxf(v2[0], v2[1]), fmaxf(v2[2], v2[3]));
#pragma unroll
    for (int off = 1; off < 64; off <<= 1) mx = fmaxf(mx, __shfl_xor(mx, off));
    if ((t & 63) == 0) red[t >> 6] = mx;
  }
  __syncthreads();
  const float smax = fmaxf(fmaxf(red[0], red[1]), fmaxf(red[2], red[3]));
  {
    short4v e, f;
#pragma unroll
    for (int q = 0; q < 4; ++q) {
      e[q] = f2h(__expf(v2[q] - smax));
      f[q] = f2h(__expf(0.2f * (v2[q] - smax)));
    }
    *(short4v*)&Esh[t << 2] = e;
    *(short4v*)&Fsh[t << 2] = f;
  }

  f16x8 Ai8[2], Bi8[2];
  const f16x2 one2 = {(_Float16)1.f, (_Float16)1.f};
  f16x8 dmask[2];
  float dsum[2] = {0.f, 0.f};
#pragma unroll
  for (int m = 0; m < 2; ++m) {
    const int rblk = (w << 5) + (m << 4) + lr;
    float s1v = s1[(bh << 10) + i0 + rblk];
    float x = s1v + smax;
    float mi = fmaxf(x, 0.2f * x);  // upper bound of row max (lrelu monotone)
    _Float16 A_ = (_Float16)__expf(x - mi);
    _Float16 B_ = (_Float16)__expf(0.2f * x - mi);
#pragma unroll
    for (int e = 0; e < 8; ++e) { Ai8[m][e] = A_; Bi8[m][e] = B_; }
    const int lqz = ((m << 1) + (lr >> 3)) & 3, ez = lr & 7;
#pragma unroll
    for (int e = 0; e < 8; ++e)
      dmask[m][e] = (lq == lqz && e == ez) ? (_Float16)0.f : (_Float16)1.f;
  }
  const int jtd = (it << 1) + (w >> 1);  // wave-uniform diagonal j-tile
  const int kkd = w & 1;                 // wave-uniform diag k-half
  f32x4 acc[2][8] = {};
  __syncthreads();  // prologue: bufs 0,1 + E/F all resident

#define TILE(buf, jt, DIAG)                                                    \
  do {                                                                         \
    _Pragma("unroll") for (int kk = 0; kk < 2; ++kk) {                         \
      const int ebase = ((jt) << 6) + (kk << 5) + (lq << 3);                   \
      f16x8 ev8 = *(const f16x8*)&Esh[ebase];                                  \
      f16x8 fv8 = *(const f16x8*)&Fsh[ebase];                                  \
      f16x8 bf[8];                                                             \
      _Pragma("unroll") for (int n = 0; n < 8; ++n) {                          \
        const int r_ = (n << 4) + lr;                                          \
        const int slot_ = ((kk << 2) + lq) ^ (r_ & 7);                         \
        bf[n] = *(const f16x8*)(&Hs[buf][(r_ << 6) + (slot_ << 3)]);           \
      }                                                                        \
      f16x8 af[2];                                                             \
      _Pragma("unroll") for (int m = 0; m < 2; ++m) {                          \
        f16x8 pm = __builtin_elementwise_max(Ai8[m] * ev8, Bi8[m] * fv8);      \
        if ((DIAG) && kk == kkd) pm = pm * dmask[m];                           \
        af[m] = pm;                                                            \
        h8u u_; u_.v = pm;                                                     \
        _Pragma("unroll") for (int p = 0; p < 4; ++p)                          \
            dsum[m] = FDOT2(u_.h[p], one2, dsum[m]);                           \
      }                                                                        \
      _Pragma("unroll") for (int m = 0; m < 2; ++m)                            \
        _Pragma("unroll") for (int n = 0; n < 8; ++n)                          \
            acc[m][n] = __builtin_amdgcn_mfma_f32_16x16x32_f16(                \
                af[m], bf[n], acc[m][n], 0, 0, 0);                             \
    }                                                                          \
  } while (0)

  int cur = 0;
#pragma unroll 1
  for (int jt = 0; jt < 16; ++jt) {
    if (jt < 15) {
      asm volatile("s_waitcnt vmcnt(4)" ::: "memory");  // own tile-jt loads in
    } else {
      asm volatile("s_waitcnt vmcnt(0)" ::: "memory");
    }
    __builtin_amdgcn_s_barrier();   // all waves: buf[cur] fully staged AND
                                    // all waves done reading buf[(jt+2)%3]
    if (jt < 14) STAGE((cur == 0 ? 2 : cur - 1), (jt + 2) << 6);
    __builtin_amdgcn_s_setprio(1);
    TILE(cur, jt, jt == jtd);
    __builtin_amdgcn_s_setprio(0);
    cur = (cur == 2) ? 0 : cur + 1;
  }

  const int b = bh >> 2, head = bh & 3;
#pragma unroll
  for (int m = 0; m < 2; ++m) {
    float s = dsum[m];
    s += __shfl_xor(s, 16);
    s += __shfl_xor(s, 32);  // all lq-replica lanes hold the row sum
    float rs = 1.f / s;
    f32x4 d4;
#pragma unroll
    for (int q = 0; q < 4; ++q)
      d4[q] = __shfl(rs, (lane & 48) | ((lq << 2) + q));
    int irow = i0 + (w << 5) + (m << 4) + (lq << 2);
#pragma unroll
    for (int n = 0; n < 8; ++n) {
      int d = (n << 4) + lr;
      long base = ((long)((b << 10) + irow) << 9) + (head << 7) + d;
      attn[base] = f2h(acc[m][n][0] * d4[0]);
      attn[base + 512] = f2h(acc[m][n][1] * d4[1]);
      attn[base + 1024] = f2h(acc[m][n][2] * d4[2]);
      attn[base + 1536] = f2h(acc[m][n][3] * d4[3]);
    }
  }
#undef STAGE
#undef TILE
}

// ---------------- out-proj + bias (+residual from f16 xh) + LN (+relu) -----
// 32-row blocks, grid 512 (2 blocks/CU). Wave owns 16 rows x 64 cols; LN via
// cross-wave LDS partial-sum exchange. Residual read from xh (f16) — proven
// absmax-neutral in rounds 9-11; removes the f32 xf mirror (16 MB/layer).
template <int HAS_RES, int DO_RELU, int WRITE_OUT>
__global__ __launch_bounds__(256) void k_outproj(const short* __restrict__ attn,
                                                 const short* __restrict__ WoT,
                                                 const float* __restrict__ bo,
                                                 const float* __restrict__ gamma,
                                                 const float* __restrict__ beta,
                                                 short* __restrict__ xh,
                                                 float* __restrict__ outp) {
  __shared__ __align__(16) short As[32 * LDP];
  __shared__ __align__(16) short Bs[128 * LDP];
  __shared__ float sredS[2][32], sredQ[2][32];
  const int t = threadIdx.x;
  const int bn0 = blockIdx.x << 5;
  const int w = t >> 6, lane = t & 63, lr = lane & 15, lq = lane >> 4;
  const int wm = w & 1, wn = w >> 1;
  f32x4 acc[4] = {};
  const int rowA = t >> 3, chA = (t & 7) << 3;
  const int rowB = t >> 1, chB = (t & 1) << 5;
  for (int k0 = 0; k0 < 512; k0 += 64) {
    {
      const short* sa = attn + ((long)(bn0 + rowA) << 9) + k0 + chA;
      *(short8*)(As + rowA * LDP + chA) = *(const short8*)(sa);
      const short* sb = WoT + (rowB << 9) + k0 + chB;
      short* db = Bs + rowB * LDP + chB;
      *(short8*)(db) = *(const short8*)(sb);
      *(short8*)(db + 8) = *(const short8*)(sb + 8);
      *(short8*)(db + 16) = *(const short8*)(sb + 16);
      *(short8*)(db + 24) = *(const short8*)(sb + 24);
    }
    __syncthreads();
#pragma unroll
    for (int kk = 0; kk < 2; ++kk) {
      f16x8 a = *(const f16x8*)(As + ((wm << 4) + lr) * LDP + (kk << 5) + (lq << 3));
#pragma unroll
      for (int nn = 0; nn < 4; ++nn) {
        f16x8 b = *(const f16x8*)(Bs + ((wn << 6) + (nn << 4) + lr) * LDP + (kk << 5) + (lq << 3));
        acc[nn] = __builtin_amdgcn_mfma_f32_16x16x32_f16(a, b, acc[nn], 0, 0, 0);
      }
    }
    __syncthreads();
  }
  float v[4][4], gam[4], bet[4];
#pragma unroll
  for (int nn = 0; nn < 4; ++nn) {
    int d = (wn << 6) + (nn << 4) + lr;
    float bv = bo[d];
    gam[nn] = gamma[d];
    bet[nn] = beta[d];
#pragma unroll
    for (int r = 0; r < 4; ++r) {
      float x = acc[nn][r] + bv;
      if (HAS_RES) x += h2f(xh[((bn0 + (wm << 4) + (lq << 2) + r) << 7) + d]);
      v[nn][r] = x;
    }
  }
#pragma unroll
  for (int r = 0; r < 4; ++r) {
    float s = 0.f, q = 0.f;
#pragma unroll
    for (int nn = 0; nn < 4; ++nn) { s += v[nn][r]; q += v[nn][r] * v[nn][r]; }
#pragma unroll
    for (int mk = 1; mk < 16; mk <<= 1) { s += __shfl_xor(s, mk); q += __shfl_xor(q, mk); }
    if (lr == 0) {
      int row = (wm << 4) + (lq << 2) + r;
      sredS[wn][row] = s;
      sredQ[wn][row] = q;
    }
  }
  __syncthreads();
#pragma unroll
  for (int r = 0; r < 4; ++r) {
    int rloc = (wm << 4) + (lq << 2) + r;
    float S = sredS[0][rloc] + sredS[1][rloc];
    float Q = sredQ[0][rloc] + sredQ[1][rloc];
    float mean = S * 0.0078125f;
    float var = Q * 0.0078125f - mean * mean;
    float rstd = rsqrtf(var + 1e-5f);
    int row = bn0 + rloc;
#pragma unroll
    for (int nn = 0; nn < 4; ++nn) {
      int d = (wn << 6) + (nn << 4) + lr;
      float o = (v[nn][r] - mean) * rstd * gam[nn] + bet[nn];
      if (DO_RELU) o = fmaxf(o, 0.f);
      if (WRITE_OUT) outp[(row << 7) + d] = o;
      else xh[(row << 7) + d] = f2h(o);
    }
  }
}

extern "C" void kernel_launch(void* const* d_in, const int* in_sizes, int n_in,
                              void* d_out, int out_size, void* d_ws, size_t ws_size,
                              hipStream_t stream) {
  const float* nf = (const float*)d_in[0];
  const float* Wp = (const float*)d_in[1];
  const float* bp = (const float*)d_in[2];
  const float* W = (const float*)d_in[3];
  const float* a1 = (const float*)d_in[4];
  const float* a2 = (const float*)d_in[5];
  const float* Wo = (const float*)d_in[6];
  const float* bo = (const float*)d_in[7];
  const float* gamma = (const float*)d_in[8];
  const float* beta = (const float*)d_in[9];
  float* outp = (float*)d_out;

  char* ws = (char*)d_ws;
  short* xh = (short*)(ws);                                    // 4 MB
  short* hT = (short*)(ws + (4ll << 20));                      // 16 MB
  short* attn = (short*)(ws + (20ll << 20));                   // 16 MB
  float* s1 = (float*)(ws + (36ll << 20));                     // 256 KB
  float* s2g = (float*)(ws + (36ll << 20) + (256ll << 10));    // 256 KB
  short* WT = (short*)(ws + (37ll << 20));                     // 384 KB
  short* WoT = (short*)(ws + (37ll << 20) + 393216);           // 384 KB

  k_init<<<9728, 256, 0, stream>>>(W, Wo, nf, Wp, bp, WT, WoT, xh);
  for (int l = 0; l < 3; ++l) {
    k_gemm_h<<<dim3(128, 4), 256, 0, stream>>>(xh, WT + l * 65536, hT,
                                               a1 + l * 512, a2 + l * 512, s1, s2g);
    k_attn<<<dim3(64, 8), 256, 0, stream>>>(hT, s1, s2g, attn);
    if (l == 0)
      k_outproj<0, 1, 0><<<512, 256, 0, stream>>>(attn, WoT + l * 65536, bo + l * 128,
                                                  gamma + l * 128, beta + l * 128, xh, outp);
    else if (l == 1)
      k_outproj<1, 1, 0><<<512, 256, 0, stream>>>(attn, WoT + l * 65536, bo + l * 128,
                                                  gamma + l * 128, beta + l * 128, xh, outp);
    else
      k_outproj<1, 0, 1><<<512, 256, 0, stream>>>(attn, WoT + l * 65536, bo + l * 128,
                                                  gamma + l * 128, beta + l * 128, xh, outp);
  }
}

// Round 23
// 152.778 us; speedup vs baseline: 1.3344x; 1.0172x over previous
//
#include <hip/hip_runtime.h>
#include <hip/hip_bf16.h>

typedef __attribute__((ext_vector_type(8))) _Float16 f16x8;
typedef __attribute__((ext_vector_type(2))) _Float16 f16x2;
typedef __attribute__((ext_vector_type(8))) short short8;
typedef __attribute__((ext_vector_type(4))) short short4v;
typedef __attribute__((ext_vector_type(4))) float f32x4;

#define LDP 72   // LDS row stride (shorts) for reg-staged GEMM tiles

typedef const __attribute__((address_space(1))) unsigned int* gas_ptr;
typedef __attribute__((address_space(3))) unsigned int* las_ptr;
#define GLDS16(gp, lp) \
  __builtin_amdgcn_global_load_lds((gas_ptr)(gp), (las_ptr)(lp), 16, 0, 0)

#if __has_builtin(__builtin_amdgcn_fdot2)
#define FDOT2(a, b, c) __builtin_amdgcn_fdot2((a), (b), (c), false)
#else
__device__ __forceinline__ float FDOT2(f16x2 a, f16x2 b, float c) {
  return c + (float)a[0] * (float)b[0] + (float)a[1] * (float)b[1];
}
#endif

union h8u {
  f16x8 v;
  f16x2 h[4];
};

__device__ __forceinline__ short f2h(float f) {
  union { _Float16 h; short s; } u; u.h = (_Float16)f; return u.s;
}
__device__ __forceinline__ float h2f(short s) {
  union { short s; _Float16 h; } u; u.s = s; return (float)u.h;
}

// ------- init: weight transpose/cvt (blocks 0..1535) + input proj (rest) ----
__global__ __launch_bounds__(256) void k_init(const float* __restrict__ W,
                                              const float* __restrict__ Wo,
                                              const float* __restrict__ nf,
                                              const float* __restrict__ Wp,
                                              const float* __restrict__ bp,
                                              short* __restrict__ WT,
                                              short* __restrict__ WoT,
                                              short* __restrict__ xh) {
  if (blockIdx.x < 1536) {
    int idx = blockIdx.x * 256 + threadIdx.x;
    if (idx < 3 * 512 * 128) {
      int l = idx >> 16, rem = idx & 65535;
      int c = rem >> 7, k = rem & 127;
      int h = c >> 7, o = c & 127;
      WT[idx] = f2h(W[(((l * 4 + h) * 128 + k) << 7) + o]);
    } else {
      int j = idx - 3 * 512 * 128;
      int l = j >> 16, rem = j & 65535;
      int d = rem >> 9, c = rem & 511;
      WoT[j] = f2h(Wo[((l * 512 + c) << 7) + d]);
    }
  } else {
    int idx = (blockIdx.x - 1536) * 256 + threadIdx.x;
    int bn = idx >> 7, d = idx & 127;
    float acc = bp[d];
    const float* nr = nf + bn * 7;
#pragma unroll
    for (int i = 0; i < 7; ++i) acc += nr[i] * Wp[(i << 7) + d];
    xh[idx] = f2h(acc);
  }
}

// ---------------- head projection + fused s1/s2 ----------------
__global__ __launch_bounds__(256) void k_gemm_h(const short* __restrict__ xh,
                                                const short* __restrict__ WT,
                                                short* __restrict__ hT,
                                                const float* __restrict__ a1,
                                                const float* __restrict__ a2,
                                                float* __restrict__ s1g,
                                                float* __restrict__ s2g) {
  __shared__ __align__(16) short As[128 * LDP];
  __shared__ __align__(16) short Bs[128 * LDP];
  __shared__ float sred[2][2][128];
  const int t = threadIdx.x;
  const int bn0 = blockIdx.x << 7;
  const int head = blockIdx.y;
  const int c0 = head << 7;
  const int w = t >> 6, lane = t & 63, lr = lane & 15, lq = lane >> 4;
  const int wr = w >> 1, wc = w & 1;
  f32x4 acc[4][4] = {};
  for (int k0 = 0; k0 < 128; k0 += 64) {
    const int row = t >> 1, half = (t & 1) << 5;
    {
      const short* sa = xh + ((bn0 + row) << 7) + k0 + half;
      short* da = As + row * LDP + half;
      *(short8*)(da) = *(const short8*)(sa);
      *(short8*)(da + 8) = *(const short8*)(sa + 8);
      *(short8*)(da + 16) = *(const short8*)(sa + 16);
      *(short8*)(da + 24) = *(const short8*)(sa + 24);
      const short* sb = WT + ((c0 + row) << 7) + k0 + half;
      short* db = Bs + row * LDP + half;
      *(short8*)(db) = *(const short8*)(sb);
      *(short8*)(db + 8) = *(const short8*)(sb + 8);
      *(short8*)(db + 16) = *(const short8*)(sb + 16);
      *(short8*)(db + 24) = *(const short8*)(sb + 24);
    }
    __syncthreads();
#pragma unroll
    for (int kk = 0; kk < 2; ++kk) {
      f16x8 a[4], b[4];
#pragma unroll
      for (int m = 0; m < 4; ++m)
        a[m] = *(const f16x8*)(As + (wr * 64 + m * 16 + lr) * LDP + (kk << 5) + (lq << 3));
#pragma unroll
      for (int n = 0; n < 4; ++n)
        b[n] = *(const f16x8*)(Bs + (wc * 64 + n * 16 + lr) * LDP + (kk << 5) + (lq << 3));
#pragma unroll
      for (int m = 0; m < 4; ++m)
#pragma unroll
        for (int n = 0; n < 4; ++n)
          acc[m][n] = __builtin_amdgcn_mfma_f32_16x16x32_f16(a[m], b[n], acc[m][n], 0, 0, 0);
    }
    __syncthreads();
  }
  const int b = bn0 >> 10;
  const int nb = bn0 & 1023;
  float a1v[4], a2v[4];
#pragma unroll
  for (int n = 0; n < 4; ++n) {
    int d = wc * 64 + n * 16 + lr;
    a1v[n] = a1[(head << 7) + d];
    a2v[n] = a2[(head << 7) + d];
  }
#pragma unroll
  for (int m = 0; m < 4; ++m)
#pragma unroll
    for (int r = 0; r < 4; ++r) {
      float v1 = 0.f, v2 = 0.f;
#pragma unroll
      for (int n = 0; n < 4; ++n) {
        v1 += acc[m][n][r] * a1v[n];
        v2 += acc[m][n][r] * a2v[n];
      }
#pragma unroll
      for (int off = 1; off < 16; off <<= 1) {
        v1 += __shfl_xor(v1, off);
        v2 += __shfl_xor(v2, off);
      }
      if (lr == 0) {
        int row = wr * 64 + m * 16 + (lq << 2) + r;
        sred[wc][0][row] = v1;
        sred[wc][1][row] = v2;
      }
    }
#pragma unroll
  for (int m = 0; m < 4; ++m) {
    int nrow = nb + wr * 64 + m * 16 + (lq << 2);
#pragma unroll
    for (int n = 0; n < 4; ++n) {
      int d = wc * 64 + n * 16 + lr;
      long base = ((long)((((b << 2) + head) << 7) + d) << 10) + nrow;
      short4v v;
      v[0] = f2h(acc[m][n][0]); v[1] = f2h(acc[m][n][1]);
      v[2] = f2h(acc[m][n][2]); v[3] = f2h(acc[m][n][3]);
      *(short4v*)(hT + base) = v;
    }
  }
  __syncthreads();
  {
    const int bh_ = (b << 2) + head;
    if (t < 128)
      s1g[(bh_ << 10) + nb + t] = sred[0][0][t] + sred[1][0][t];
    else
      s2g[(bh_ << 10) + nb + (t - 128)] = sred[0][1][t - 128] + sred[1][1][t - 128];
  }
}

// ---------------- attention (k_ef fused into prologue) ----------------
// grid (64 bh, 8 it). Wave owns 32-row strip (m=2) x full 128 d (n=8).
// Prologue: load s2 slice, block-reduce max, compute E/F f16 into LDS.
// Main loop: 3 LDS buffers, prefetch distance 2, counted vmcnt(4), single
// barrier/iter. NO setprio: lockstep barrier loop (m190: setprio hurts here).
__global__ __launch_bounds__(256) void k_attn(const short* __restrict__ hT,
                                              const float* __restrict__ s1,
                                              const float* __restrict__ s2g,
                                              short* __restrict__ attn) {
  __shared__ __align__(16) short Hs[3][128 * 64];
  __shared__ __align__(16) _Float16 Esh[1024];
  __shared__ __align__(16) _Float16 Fsh[1024];
  __shared__ float red[4];
  const int bh = blockIdx.x, it = blockIdx.y;
  const int i0 = it << 7;
  const int t = threadIdx.x;
  const int w = t >> 6, lane = t & 63, lr = lane & 15, lq = lane >> 4;

  const short* hTb = hT + ((long)bh << 17);
  const int grow = (w << 5) + (lane >> 3);
  const int gcol = ((lane & 7) ^ (lane >> 3)) << 3;
  const short* gsrc = hTb + ((long)grow << 10) + gcol;

#define STAGE(buf, J0)                                             \
  do {                                                             \
    short* ldsb = &Hs[buf][(w << 5) << 6];                         \
    _Pragma("unroll") for (int i_ = 0; i_ < 4; ++i_)               \
        GLDS16(gsrc + ((long)(i_ << 3) << 10) + (J0),              \
               ldsb + ((i_ << 3) << 6));                           \
  } while (0)

  STAGE(0, 0);
  STAGE(1, 64);

  // fused k_ef: max(s2) then E=exp(s2-max), F=exp(.2(s2-max)) into LDS
  f32x4 v2 = *(const f32x4*)&s2g[(bh << 10) + (t << 2)];
  {
    float mx = fmaxf(fmaxf(v2[0], v2[1]), fmaxf(v2[2], v2[3]));
#pragma unroll
    for (int off = 1; off < 64; off <<= 1) mx = fmaxf(mx, __shfl_xor(mx, off));
    if ((t & 63) == 0) red[t >> 6] = mx;
  }
  __syncthreads();
  const float smax = fmaxf(fmaxf(red[0], red[1]), fmaxf(red[2], red[3]));
  {
    short4v e, f;
#pragma unroll
    for (int q = 0; q < 4; ++q) {
      e[q] = f2h(__expf(v2[q] - smax));
      f[q] = f2h(__expf(0.2f * (v2[q] - smax)));
    }
    *(short4v*)&Esh[t << 2] = e;
    *(short4v*)&Fsh[t << 2] = f;
  }

  f16x8 Ai8[2], Bi8[2];
  const f16x2 one2 = {(_Float16)1.f, (_Float16)1.f};
  f16x8 dmask[2];
  float dsum[2] = {0.f, 0.f};
#pragma unroll
  for (int m = 0; m < 2; ++m) {
    const int rblk = (w << 5) + (m << 4) + lr;
    float s1v = s1[(bh << 10) + i0 + rblk];
    float x = s1v + smax;
    float mi = fmaxf(x, 0.2f * x);  // upper bound of row max (lrelu monotone)
    _Float16 A_ = (_Float16)__expf(x - mi);
    _Float16 B_ = (_Float16)__expf(0.2f * x - mi);
#pragma unroll
    for (int e = 0; e < 8; ++e) { Ai8[m][e] = A_; Bi8[m][e] = B_; }
    const int lqz = ((m << 1) + (lr >> 3)) & 3, ez = lr & 7;
#pragma unroll
    for (int e = 0; e < 8; ++e)
      dmask[m][e] = (lq == lqz && e == ez) ? (_Float16)0.f : (_Float16)1.f;
  }
  const int jtd = (it << 1) + (w >> 1);  // wave-uniform diagonal j-tile
  const int kkd = w & 1;                 // wave-uniform diag k-half
  f32x4 acc[2][8] = {};
  __syncthreads();  // prologue: bufs 0,1 + E/F all resident

#define TILE(buf, jt, DIAG)                                                    \
  do {                                                                         \
    _Pragma("unroll") for (int kk = 0; kk < 2; ++kk) {                         \
      const int ebase = ((jt) << 6) + (kk << 5) + (lq << 3);                   \
      f16x8 ev8 = *(const f16x8*)&Esh[ebase];                                  \
      f16x8 fv8 = *(const f16x8*)&Fsh[ebase];                                  \
      f16x8 bf[8];                                                             \
      _Pragma("unroll") for (int n = 0; n < 8; ++n) {                          \
        const int r_ = (n << 4) + lr;                                          \
        const int slot_ = ((kk << 2) + lq) ^ (r_ & 7);                         \
        bf[n] = *(const f16x8*)(&Hs[buf][(r_ << 6) + (slot_ << 3)]);           \
      }                                                                        \
      f16x8 af[2];                                                             \
      _Pragma("unroll") for (int m = 0; m < 2; ++m) {                          \
        f16x8 pm = __builtin_elementwise_max(Ai8[m] * ev8, Bi8[m] * fv8);      \
        if ((DIAG) && kk == kkd) pm = pm * dmask[m];                           \
        af[m] = pm;                                                            \
        h8u u_; u_.v = pm;                                                     \
        _Pragma("unroll") for (int p = 0; p < 4; ++p)                          \
            dsum[m] = FDOT2(u_.h[p], one2, dsum[m]);                           \
      }                                                                        \
      _Pragma("unroll") for (int m = 0; m < 2; ++m)                            \
        _Pragma("unroll") for (int n = 0; n < 8; ++n)                          \
            acc[m][n] = __builtin_amdgcn_mfma_f32_16x16x32_f16(                \
                af[m], bf[n], acc[m][n], 0, 0, 0);                             \
    }                                                                          \
  } while (0)

  int cur = 0;
#pragma unroll 1
  for (int jt = 0; jt < 16; ++jt) {
    if (jt < 15) {
      asm volatile("s_waitcnt vmcnt(4)" ::: "memory");  // own tile-jt loads in
    } else {
      asm volatile("s_waitcnt vmcnt(0)" ::: "memory");
    }
    __builtin_amdgcn_s_barrier();   // all waves: buf[cur] fully staged AND
                                    // all waves done reading buf[(jt+2)%3]
    if (jt < 14) STAGE((cur == 0 ? 2 : cur - 1), (jt + 2) << 6);
    TILE(cur, jt, jt == jtd);
    cur = (cur == 2) ? 0 : cur + 1;
  }

  const int b = bh >> 2, head = bh & 3;
#pragma unroll
  for (int m = 0; m < 2; ++m) {
    float s = dsum[m];
    s += __shfl_xor(s, 16);
    s += __shfl_xor(s, 32);  // all lq-replica lanes hold the row sum
    float rs = 1.f / s;
    f32x4 d4;
#pragma unroll
    for (int q = 0; q < 4; ++q)
      d4[q] = __shfl(rs, (lane & 48) | ((lq << 2) + q));
    int irow = i0 + (w << 5) + (m << 4) + (lq << 2);
#pragma unroll
    for (int n = 0; n < 8; ++n) {
      int d = (n << 4) + lr;
      long base = ((long)((b << 10) + irow) << 9) + (head << 7) + d;
      attn[base] = f2h(acc[m][n][0] * d4[0]);
      attn[base + 512] = f2h(acc[m][n][1] * d4[1]);
      attn[base + 1024] = f2h(acc[m][n][2] * d4[2]);
      attn[base + 1536] = f2h(acc[m][n][3] * d4[3]);
    }
  }
#undef STAGE
#undef TILE
}

// ---------------- out-proj + bias (+residual from f16 xh) + LN (+relu) -----
template <int HAS_RES, int DO_RELU, int WRITE_OUT>
__global__ __launch_bounds__(256) void k_outproj(const short* __restrict__ attn,
                                                 const short* __restrict__ WoT,
                                                 const float* __restrict__ bo,
                                                 const float* __restrict__ gamma,
                                                 const float* __restrict__ beta,
                                                 short* __restrict__ xh,
                                                 float* __restrict__ outp) {
  __shared__ __align__(16) short As[32 * LDP];
  __shared__ __align__(16) short Bs[128 * LDP];
  __shared__ float sredS[2][32], sredQ[2][32];
  const int t = threadIdx.x;
  const int bn0 = blockIdx.x << 5;
  const int w = t >> 6, lane = t & 63, lr = lane & 15, lq = lane >> 4;
  const int wm = w & 1, wn = w >> 1;
  f32x4 acc[4] = {};
  const int rowA = t >> 3, chA = (t & 7) << 3;
  const int rowB = t >> 1, chB = (t & 1) << 5;
  for (int k0 = 0; k0 < 512; k0 += 64) {
    {
      const short* sa = attn + ((long)(bn0 + rowA) << 9) + k0 + chA;
      *(short8*)(As + rowA * LDP + chA) = *(const short8*)(sa);
      const short* sb = WoT + (rowB << 9) + k0 + chB;
      short* db = Bs + rowB * LDP + chB;
      *(short8*)(db) = *(const short8*)(sb);
      *(short8*)(db + 8) = *(const short8*)(sb + 8);
      *(short8*)(db + 16) = *(const short8*)(sb + 16);
      *(short8*)(db + 24) = *(const short8*)(sb + 24);
    }
    __syncthreads();
#pragma unroll
    for (int kk = 0; kk < 2; ++kk) {
      f16x8 a = *(const f16x8*)(As + ((wm << 4) + lr) * LDP + (kk << 5) + (lq << 3));
#pragma unroll
      for (int nn = 0; nn < 4; ++nn) {
        f16x8 b = *(const f16x8*)(Bs + ((wn << 6) + (nn << 4) + lr) * LDP + (kk << 5) + (lq << 3));
        acc[nn] = __builtin_amdgcn_mfma_f32_16x16x32_f16(a, b, acc[nn], 0, 0, 0);
      }
    }
    __syncthreads();
  }
  float v[4][4], gam[4], bet[4];
#pragma unroll
  for (int nn = 0; nn < 4; ++nn) {
    int d = (wn << 6) + (nn << 4) + lr;
    float bv = bo[d];
    gam[nn] = gamma[d];
    bet[nn] = beta[d];
#pragma unroll
    for (int r = 0; r < 4; ++r) {
      float x = acc[nn][r] + bv;
      if (HAS_RES) x += h2f(xh[((bn0 + (wm << 4) + (lq << 2) + r) << 7) + d]);
      v[nn][r] = x;
    }
  }
#pragma unroll
  for (int r = 0; r < 4; ++r) {
    float s = 0.f, q = 0.f;
#pragma unroll
    for (int nn = 0; nn < 4; ++nn) { s += v[nn][r]; q += v[nn][r] * v[nn][r]; }
#pragma unroll
    for (int mk = 1; mk < 16; mk <<= 1) { s += __shfl_xor(s, mk); q += __shfl_xor(q, mk); }
    if (lr == 0) {
      int row = (wm << 4) + (lq << 2) + r;
      sredS[wn][row] = s;
      sredQ[wn][row] = q;
    }
  }
  __syncthreads();
#pragma unroll
  for (int r = 0; r < 4; ++r) {
    int rloc = (wm << 4) + (lq << 2) + r;
    float S = sredS[0][rloc] + sredS[1][rloc];
    float Q = sredQ[0][rloc] + sredQ[1][rloc];
    float mean = S * 0.0078125f;
    float var = Q * 0.0078125f - mean * mean;
    float rstd = rsqrtf(var + 1e-5f);
    int row = bn0 + rloc;
#pragma unroll
    for (int nn = 0; nn < 4; ++nn) {
      int d = (wn << 6) + (nn << 4) + lr;
      float o = (v[nn][r] - mean) * rstd * gam[nn] + bet[nn];
      if (DO_RELU) o = fmaxf(o, 0.f);
      if (WRITE_OUT) outp[(row << 7) + d] = o;
      else xh[(row << 7) + d] = f2h(o);
    }
  }
}

extern "C" void kernel_launch(void* const* d_in, const int* in_sizes, int n_in,
                              void* d_out, int out_size, void* d_ws, size_t ws_size,
                              hipStream_t stream) {
  const float* nf = (const float*)d_in[0];
  const float* Wp = (const float*)d_in[1];
  const float* bp = (const float*)d_in[2];
  const float* W = (const float*)d_in[3];
  const float* a1 = (const float*)d_in[4];
  const float* a2 = (const float*)d_in[5];
  const float* Wo = (const float*)d_in[6];
  const float* bo = (const float*)d_in[7];
  const float* gamma = (const float*)d_in[8];
  const float* beta = (const float*)d_in[9];
  float* outp = (float*)d_out;

  char* ws = (char*)d_ws;
  short* xh = (short*)(ws);                                    // 4 MB
  short* hT = (short*)(ws + (4ll << 20));                      // 16 MB
  short* attn = (short*)(ws + (20ll << 20));                   // 16 MB
  float* s1 = (float*)(ws + (36ll << 20));                     // 256 KB
  float* s2g = (float*)(ws + (36ll << 20) + (256ll << 10));    // 256 KB
  short* WT = (short*)(ws + (37ll << 20));                     // 384 KB
  short* WoT = (short*)(ws + (37ll << 20) + 393216);           // 384 KB

  k_init<<<9728, 256, 0, stream>>>(W, Wo, nf, Wp, bp, WT, WoT, xh);
  for (int l = 0; l < 3; ++l) {
    k_gemm_h<<<dim3(128, 4), 256, 0, stream>>>(xh, WT + l * 65536, hT,
                                               a1 + l * 512, a2 + l * 512, s1, s2g);
    k_attn<<<dim3(64, 8), 256, 0, stream>>>(hT, s1, s2g, attn);
    if (l == 0)
      k_outproj<0, 1, 0><<<512, 256, 0, stream>>>(attn, WoT + l * 65536, bo + l * 128,
                                                  gamma + l * 128, beta + l * 128, xh, outp);
    else if (l == 1)
      k_outproj<1, 1, 0><<<512, 256, 0, stream>>>(attn, WoT + l * 65536, bo + l * 128,
                                                  gamma + l * 128, beta + l * 128, xh, outp);
    else
      k_outproj<1, 0, 1><<<512, 256, 0, stream>>>(attn, WoT + l * 65536, bo + l * 128,
                                                  gamma + l * 128, beta + l * 128, xh, outp);
  }
}

// Round 24
// 146.038 us; speedup vs baseline: 1.3960x; 1.0462x over previous
//
#include <hip/hip_runtime.h>
#include <hip/hip_bf16.h>

typedef __attribute__((ext_vector_type(8))) _Float16 f16x8;
typedef __attribute__((ext_vector_type(2))) _Float16 f16x2;
typedef __attribute__((ext_vector_type(8))) short short8;
typedef __attribute__((ext_vector_type(4))) short short4v;
typedef __attribute__((ext_vector_type(4))) float f32x4;

#define LDP 72   // LDS row stride (shorts) for reg-staged A tiles

typedef const __attribute__((address_space(1))) unsigned int* gas_ptr;
typedef __attribute__((address_space(3))) unsigned int* las_ptr;
#define GLDS16(gp, lp) \
  __builtin_amdgcn_global_load_lds((gas_ptr)(gp), (las_ptr)(lp), 16, 0, 0)

#if __has_builtin(__builtin_amdgcn_fdot2)
#define FDOT2(a, b, c) __builtin_amdgcn_fdot2((a), (b), (c), false)
#else
__device__ __forceinline__ float FDOT2(f16x2 a, f16x2 b, float c) {
  return c + (float)a[0] * (float)b[0] + (float)a[1] * (float)b[1];
}
#endif

union h8u {
  f16x8 v;
  f16x2 h[4];
};

__device__ __forceinline__ short f2h(float f) {
  union { _Float16 h; short s; } u; u.h = (_Float16)f; return u.s;
}
__device__ __forceinline__ float h2f(short s) {
  union { short s; _Float16 h; } u; u.s = s; return (float)u.h;
}

// ------- init: weight transpose/cvt (blocks 0..1535) + input proj (rest) ----
__global__ __launch_bounds__(256) void k_init(const float* __restrict__ W,
                                              const float* __restrict__ Wo,
                                              const float* __restrict__ nf,
                                              const float* __restrict__ Wp,
                                              const float* __restrict__ bp,
                                              short* __restrict__ WT,
                                              short* __restrict__ WoT,
                                              short* __restrict__ xh) {
  if (blockIdx.x < 1536) {
    int idx = blockIdx.x * 256 + threadIdx.x;
    if (idx < 3 * 512 * 128) {
      int l = idx >> 16, rem = idx & 65535;
      int c = rem >> 7, k = rem & 127;
      int h = c >> 7, o = c & 127;
      WT[idx] = f2h(W[(((l * 4 + h) * 128 + k) << 7) + o]);
    } else {
      int j = idx - 3 * 512 * 128;
      int l = j >> 16, rem = j & 65535;
      int d = rem >> 9, c = rem & 511;
      WoT[j] = f2h(Wo[((l * 512 + c) << 7) + d]);
    }
  } else {
    int idx = (blockIdx.x - 1536) * 256 + threadIdx.x;
    int bn = idx >> 7, d = idx & 127;
    float acc = bp[d];
    const float* nr = nf + bn * 7;
#pragma unroll
    for (int i = 0; i < 7; ++i) acc += nr[i] * Wp[(i << 7) + d];
    xh[idx] = f2h(acc);
  }
}

// ---------------- head projection + fused s1/s2 ----------------
// B (weights) staged via global_load_lds: linear [128][64] LDS, pre-swizzled
// source chunk (lane&7)^(lane>>3), XOR slot on read (k_attn's proven pattern).
__global__ __launch_bounds__(256) void k_gemm_h(const short* __restrict__ xh,
                                                const short* __restrict__ WT,
                                                short* __restrict__ hT,
                                                const float* __restrict__ a1,
                                                const float* __restrict__ a2,
                                                float* __restrict__ s1g,
                                                float* __restrict__ s2g) {
  __shared__ __align__(16) short As[128 * LDP];
  __shared__ __align__(16) short Bs[128 * 64];
  __shared__ float sred[2][2][128];
  const int t = threadIdx.x;
  const int bn0 = blockIdx.x << 7;
  const int head = blockIdx.y;
  const int c0 = head << 7;
  const int w = t >> 6, lane = t & 63, lr = lane & 15, lq = lane >> 4;
  const int wr = w >> 1, wc = w & 1;
  // glds source for B: wave w covers rows [w*32, w*32+32) of the 128-row tile
  const int growB = (w << 5) + (lane >> 3);
  const int gcolB = ((lane & 7) ^ (lane >> 3)) << 3;
  const short* gsrcB = WT + ((c0 + growB) << 7) + gcolB;
  f32x4 acc[4][4] = {};
  for (int k0 = 0; k0 < 128; k0 += 64) {
    {
      short* ldsbB = &Bs[(w << 5) << 6];
#pragma unroll
      for (int i_ = 0; i_ < 4; ++i_)
        GLDS16(gsrcB + ((i_ << 3) << 7) + k0, ldsbB + ((i_ << 3) << 6));
      const int row = t >> 1, half = (t & 1) << 5;
      const short* sa = xh + ((bn0 + row) << 7) + k0 + half;
      short* da = As + row * LDP + half;
      *(short8*)(da) = *(const short8*)(sa);
      *(short8*)(da + 8) = *(const short8*)(sa + 8);
      *(short8*)(da + 16) = *(const short8*)(sa + 16);
      *(short8*)(da + 24) = *(const short8*)(sa + 24);
    }
    __syncthreads();   // drains vmcnt+lgkm: As and Bs fully resident
#pragma unroll
    for (int kk = 0; kk < 2; ++kk) {
      f16x8 a[4], b[4];
#pragma unroll
      for (int m = 0; m < 4; ++m)
        a[m] = *(const f16x8*)(As + (wr * 64 + m * 16 + lr) * LDP + (kk << 5) + (lq << 3));
#pragma unroll
      for (int n = 0; n < 4; ++n) {
        const int r_ = wc * 64 + n * 16 + lr;
        const int slot_ = ((kk << 2) + lq) ^ (r_ & 7);
        b[n] = *(const f16x8*)(&Bs[(r_ << 6) + (slot_ << 3)]);
      }
#pragma unroll
      for (int m = 0; m < 4; ++m)
#pragma unroll
        for (int n = 0; n < 4; ++n)
          acc[m][n] = __builtin_amdgcn_mfma_f32_16x16x32_f16(a[m], b[n], acc[m][n], 0, 0, 0);
    }
    __syncthreads();
  }
  const int b = bn0 >> 10;
  const int nb = bn0 & 1023;
  float a1v[4], a2v[4];
#pragma unroll
  for (int n = 0; n < 4; ++n) {
    int d = wc * 64 + n * 16 + lr;
    a1v[n] = a1[(head << 7) + d];
    a2v[n] = a2[(head << 7) + d];
  }
#pragma unroll
  for (int m = 0; m < 4; ++m)
#pragma unroll
    for (int r = 0; r < 4; ++r) {
      float v1 = 0.f, v2 = 0.f;
#pragma unroll
      for (int n = 0; n < 4; ++n) {
        v1 += acc[m][n][r] * a1v[n];
        v2 += acc[m][n][r] * a2v[n];
      }
#pragma unroll
      for (int off = 1; off < 16; off <<= 1) {
        v1 += __shfl_xor(v1, off);
        v2 += __shfl_xor(v2, off);
      }
      if (lr == 0) {
        int row = wr * 64 + m * 16 + (lq << 2) + r;
        sred[wc][0][row] = v1;
        sred[wc][1][row] = v2;
      }
    }
#pragma unroll
  for (int m = 0; m < 4; ++m) {
    int nrow = nb + wr * 64 + m * 16 + (lq << 2);
#pragma unroll
    for (int n = 0; n < 4; ++n) {
      int d = wc * 64 + n * 16 + lr;
      long base = ((long)((((b << 2) + head) << 7) + d) << 10) + nrow;
      short4v v;
      v[0] = f2h(acc[m][n][0]); v[1] = f2h(acc[m][n][1]);
      v[2] = f2h(acc[m][n][2]); v[3] = f2h(acc[m][n][3]);
      *(short4v*)(hT + base) = v;
    }
  }
  __syncthreads();
  {
    const int bh_ = (b << 2) + head;
    if (t < 128)
      s1g[(bh_ << 10) + nb + t] = sred[0][0][t] + sred[1][0][t];
    else
      s2g[(bh_ << 10) + nb + (t - 128)] = sred[0][1][t - 128] + sred[1][1][t - 128];
  }
}

// ---------------- attention (k_ef fused into prologue) ----------------
// grid (64 bh, 8 it). Wave owns 32-row strip (m=2) x full 128 d (n=8).
// 3 LDS buffers, prefetch distance 2, counted vmcnt(4), single barrier/iter.
__global__ __launch_bounds__(256) void k_attn(const short* __restrict__ hT,
                                              const float* __restrict__ s1,
                                              const float* __restrict__ s2g,
                                              short* __restrict__ attn) {
  __shared__ __align__(16) short Hs[3][128 * 64];
  __shared__ __align__(16) _Float16 Esh[1024];
  __shared__ __align__(16) _Float16 Fsh[1024];
  __shared__ float red[4];
  const int bh = blockIdx.x, it = blockIdx.y;
  const int i0 = it << 7;
  const int t = threadIdx.x;
  const int w = t >> 6, lane = t & 63, lr = lane & 15, lq = lane >> 4;

  const short* hTb = hT + ((long)bh << 17);
  const int grow = (w << 5) + (lane >> 3);
  const int gcol = ((lane & 7) ^ (lane >> 3)) << 3;
  const short* gsrc = hTb + ((long)grow << 10) + gcol;

#define STAGE(buf, J0)                                             \
  do {                                                             \
    short* ldsb = &Hs[buf][(w << 5) << 6];                         \
    _Pragma("unroll") for (int i_ = 0; i_ < 4; ++i_)               \
        GLDS16(gsrc + ((long)(i_ << 3) << 10) + (J0),              \
               ldsb + ((i_ << 3) << 6));                           \
  } while (0)

  STAGE(0, 0);
  STAGE(1, 64);

  // fused k_ef: max(s2) then E=exp(s2-max), F=exp(.2(s2-max)) into LDS
  f32x4 v2 = *(const f32x4*)&s2g[(bh << 10) + (t << 2)];
  {
    float mx = fmaxf(fmaxf(v2[0], v2[1]), fmaxf(v2[2], v2[3]));
#pragma unroll
    for (int off = 1; off < 64; off <<= 1) mx = fmaxf(mx, __shfl_xor(mx, off));
    if ((t & 63) == 0) red[t >> 6] = mx;
  }
  __syncthreads();
  const float smax = fmaxf(fmaxf(red[0], red[1]), fmaxf(red[2], red[3]));
  {
    short4v e, f;
#pragma unroll
    for (int q = 0; q < 4; ++q) {
      e[q] = f2h(__expf(v2[q] - smax));
      f[q] = f2h(__expf(0.2f * (v2[q] - smax)));
    }
    *(short4v*)&Esh[t << 2] = e;
    *(short4v*)&Fsh[t << 2] = f;
  }

  f16x8 Ai8[2], Bi8[2];
  const f16x2 one2 = {(_Float16)1.f, (_Float16)1.f};
  f16x8 dmask[2];
  float dsum[2] = {0.f, 0.f};
#pragma unroll
  for (int m = 0; m < 2; ++m) {
    const int rblk = (w << 5) + (m << 4) + lr;
    float s1v = s1[(bh << 10) + i0 + rblk];
    float x = s1v + smax;
    float mi = fmaxf(x, 0.2f * x);  // upper bound of row max (lrelu monotone)
    _Float16 A_ = (_Float16)__expf(x - mi);
    _Float16 B_ = (_Float16)__expf(0.2f * x - mi);
#pragma unroll
    for (int e = 0; e < 8; ++e) { Ai8[m][e] = A_; Bi8[m][e] = B_; }
    const int lqz = ((m << 1) + (lr >> 3)) & 3, ez = lr & 7;
#pragma unroll
    for (int e = 0; e < 8; ++e)
      dmask[m][e] = (lq == lqz && e == ez) ? (_Float16)0.f : (_Float16)1.f;
  }
  const int jtd = (it << 1) + (w >> 1);  // wave-uniform diagonal j-tile
  const int kkd = w & 1;                 // wave-uniform diag k-half
  f32x4 acc[2][8] = {};
  __syncthreads();  // prologue: bufs 0,1 + E/F all resident

#define TILE(buf, jt, DIAG)                                                    \
  do {                                                                         \
    _Pragma("unroll") for (int kk = 0; kk < 2; ++kk) {                         \
      const int ebase = ((jt) << 6) + (kk << 5) + (lq << 3);                   \
      f16x8 ev8 = *(const f16x8*)&Esh[ebase];                                  \
      f16x8 fv8 = *(const f16x8*)&Fsh[ebase];                                  \
      f16x8 bf[8];                                                             \
      _Pragma("unroll") for (int n = 0; n < 8; ++n) {                          \
        const int r_ = (n << 4) + lr;                                          \
        const int slot_ = ((kk << 2) + lq) ^ (r_ & 7);                         \
        bf[n] = *(const f16x8*)(&Hs[buf][(r_ << 6) + (slot_ << 3)]);           \
      }                                                                        \
      f16x8 af[2];                                                             \
      _Pragma("unroll") for (int m = 0; m < 2; ++m) {                          \
        f16x8 pm = __builtin_elementwise_max(Ai8[m] * ev8, Bi8[m] * fv8);      \
        if ((DIAG) && kk == kkd) pm = pm * dmask[m];                           \
        af[m] = pm;                                                            \
        h8u u_; u_.v = pm;                                                     \
        _Pragma("unroll") for (int p = 0; p < 4; ++p)                          \
            dsum[m] = FDOT2(u_.h[p], one2, dsum[m]);                           \
      }                                                                        \
      _Pragma("unroll") for (int m = 0; m < 2; ++m)                            \
        _Pragma("unroll") for (int n = 0; n < 8; ++n)                          \
            acc[m][n] = __builtin_amdgcn_mfma_f32_16x16x32_f16(                \
                af[m], bf[n], acc[m][n], 0, 0, 0);                             \
    }                                                                          \
  } while (0)

  int cur = 0;
#pragma unroll 1
  for (int jt = 0; jt < 16; ++jt) {
    if (jt < 15) {
      asm volatile("s_waitcnt vmcnt(4)" ::: "memory");  // own tile-jt loads in
    } else {
      asm volatile("s_waitcnt vmcnt(0)" ::: "memory");
    }
    __builtin_amdgcn_s_barrier();   // all waves: buf[cur] fully staged AND
                                    // all waves done reading buf[(jt+2)%3]
    if (jt < 14) STAGE((cur == 0 ? 2 : cur - 1), (jt + 2) << 6);
    TILE(cur, jt, jt == jtd);
    cur = (cur == 2) ? 0 : cur + 1;
  }

  const int b = bh >> 2, head = bh & 3;
#pragma unroll
  for (int m = 0; m < 2; ++m) {
    float s = dsum[m];
    s += __shfl_xor(s, 16);
    s += __shfl_xor(s, 32);  // all lq-replica lanes hold the row sum
    float rs = 1.f / s;
    f32x4 d4;
#pragma unroll
    for (int q = 0; q < 4; ++q)
      d4[q] = __shfl(rs, (lane & 48) | ((lq << 2) + q));
    int irow = i0 + (w << 5) + (m << 4) + (lq << 2);
#pragma unroll
    for (int n = 0; n < 8; ++n) {
      int d = (n << 4) + lr;
      long base = ((long)((b << 10) + irow) << 9) + (head << 7) + d;
      attn[base] = f2h(acc[m][n][0] * d4[0]);
      attn[base + 512] = f2h(acc[m][n][1] * d4[1]);
      attn[base + 1024] = f2h(acc[m][n][2] * d4[2]);
      attn[base + 1536] = f2h(acc[m][n][3] * d4[3]);
    }
  }
#undef STAGE
#undef TILE
}

// ---------------- out-proj + bias (+residual from f16 xh) + LN (+relu) -----
// B (WoT) staged via global_load_lds (linear [128][64] + XOR-slot reads).
template <int HAS_RES, int DO_RELU, int WRITE_OUT>
__global__ __launch_bounds__(256) void k_outproj(const short* __restrict__ attn,
                                                 const short* __restrict__ WoT,
                                                 const float* __restrict__ bo,
                                                 const float* __restrict__ gamma,
                                                 const float* __restrict__ beta,
                                                 short* __restrict__ xh,
                                                 float* __restrict__ outp) {
  __shared__ __align__(16) short As[32 * LDP];
  __shared__ __align__(16) short Bs[128 * 64];
  __shared__ float sredS[2][32], sredQ[2][32];
  const int t = threadIdx.x;
  const int bn0 = blockIdx.x << 5;
  const int w = t >> 6, lane = t & 63, lr = lane & 15, lq = lane >> 4;
  const int wm = w & 1, wn = w >> 1;
  f32x4 acc[4] = {};
  const int rowA = t >> 3, chA = (t & 7) << 3;
  // glds source for B: wave w covers rows [w*32, w*32+32) of the 128-row tile
  const int growB = (w << 5) + (lane >> 3);
  const int gcolB = ((lane & 7) ^ (lane >> 3)) << 3;
  const short* gsrcB = WoT + (growB << 9) + gcolB;
  for (int k0 = 0; k0 < 512; k0 += 64) {
    {
      short* ldsbB = &Bs[(w << 5) << 6];
#pragma unroll
      for (int i_ = 0; i_ < 4; ++i_)
        GLDS16(gsrcB + ((i_ << 3) << 9) + k0, ldsbB + ((i_ << 3) << 6));
      const short* sa = attn + ((long)(bn0 + rowA) << 9) + k0 + chA;
      *(short8*)(As + rowA * LDP + chA) = *(const short8*)(sa);
    }
    __syncthreads();   // drains vmcnt+lgkm: As and Bs fully resident
#pragma unroll
    for (int kk = 0; kk < 2; ++kk) {
      f16x8 a = *(const f16x8*)(As + ((wm << 4) + lr) * LDP + (kk << 5) + (lq << 3));
#pragma unroll
      for (int nn = 0; nn < 4; ++nn) {
        const int r_ = (wn << 6) + (nn << 4) + lr;
        const int slot_ = ((kk << 2) + lq) ^ (r_ & 7);
        f16x8 b = *(const f16x8*)(&Bs[(r_ << 6) + (slot_ << 3)]);
        acc[nn] = __builtin_amdgcn_mfma_f32_16x16x32_f16(a, b, acc[nn], 0, 0, 0);
      }
    }
    __syncthreads();
  }
  float v[4][4], gam[4], bet[4];
#pragma unroll
  for (int nn = 0; nn < 4; ++nn) {
    int d = (wn << 6) + (nn << 4) + lr;
    float bv = bo[d];
    gam[nn] = gamma[d];
    bet[nn] = beta[d];
#pragma unroll
    for (int r = 0; r < 4; ++r) {
      float x = acc[nn][r] + bv;
      if (HAS_RES) x += h2f(xh[((bn0 + (wm << 4) + (lq << 2) + r) << 7) + d]);
      v[nn][r] = x;
    }
  }
#pragma unroll
  for (int r = 0; r < 4; ++r) {
    float s = 0.f, q = 0.f;
#pragma unroll
    for (int nn = 0; nn < 4; ++nn) { s += v[nn][r]; q += v[nn][r] * v[nn][r]; }
#pragma unroll
    for (int mk = 1; mk < 16; mk <<= 1) { s += __shfl_xor(s, mk); q += __shfl_xor(q, mk); }
    if (lr == 0) {
      int row = (wm << 4) + (lq << 2) + r;
      sredS[wn][row] = s;
      sredQ[wn][row] = q;
    }
  }
  __syncthreads();
#pragma unroll
  for (int r = 0; r < 4; ++r) {
    int rloc = (wm << 4) + (lq << 2) + r;
    float S = sredS[0][rloc] + sredS[1][rloc];
    float Q = sredQ[0][rloc] + sredQ[1][rloc];
    float mean = S * 0.0078125f;
    float var = Q * 0.0078125f - mean * mean;
    float rstd = rsqrtf(var + 1e-5f);
    int row = bn0 + rloc;
#pragma unroll
    for (int nn = 0; nn < 4; ++nn) {
      int d = (wn << 6) + (nn << 4) + lr;
      float o = (v[nn][r] - mean) * rstd * gam[nn] + bet[nn];
      if (DO_RELU) o = fmaxf(o, 0.f);
      if (WRITE_OUT) outp[(row << 7) + d] = o;
      else xh[(row << 7) + d] = f2h(o);
    }
  }
}

extern "C" void kernel_launch(void* const* d_in, const int* in_sizes, int n_in,
                              void* d_out, int out_size, void* d_ws, size_t ws_size,
                              hipStream_t stream) {
  const float* nf = (const float*)d_in[0];
  const float* Wp = (const float*)d_in[1];
  const float* bp = (const float*)d_in[2];
  const float* W = (const float*)d_in[3];
  const float* a1 = (const float*)d_in[4];
  const float* a2 = (const float*)d_in[5];
  const float* Wo = (const float*)d_in[6];
  const float* bo = (const float*)d_in[7];
  const float* gamma = (const float*)d_in[8];
  const float* beta = (const float*)d_in[9];
  float* outp = (float*)d_out;

  char* ws = (char*)d_ws;
  short* xh = (short*)(ws);                                    // 4 MB
  short* hT = (short*)(ws + (4ll << 20));                      // 16 MB
  short* attn = (short*)(ws + (20ll << 20));                   // 16 MB
  float* s1 = (float*)(ws + (36ll << 20));                     // 256 KB
  float* s2g = (float*)(ws + (36ll << 20) + (256ll << 10));    // 256 KB
  short* WT = (short*)(ws + (37ll << 20));                     // 384 KB
  short* WoT = (short*)(ws + (37ll << 20) + 393216);           // 384 KB

  k_init<<<9728, 256, 0, stream>>>(W, Wo, nf, Wp, bp, WT, WoT, xh);
  for (int l = 0; l < 3; ++l) {
    k_gemm_h<<<dim3(128, 4), 256, 0, stream>>>(xh, WT + l * 65536, hT,
                                               a1 + l * 512, a2 + l * 512, s1, s2g);
    k_attn<<<dim3(64, 8), 256, 0, stream>>>(hT, s1, s2g, attn);
    if (l == 0)
      k_outproj<0, 1, 0><<<512, 256, 0, stream>>>(attn, WoT + l * 65536, bo + l * 128,
                                                  gamma + l * 128, beta + l * 128, xh, outp);
    else if (l == 1)
      k_outproj<1, 1, 0><<<512, 256, 0, stream>>>(attn, WoT + l * 65536, bo + l * 128,
                                                  gamma + l * 128, beta + l * 128, xh, outp);
    else
      k_outproj<1, 0, 1><<<512, 256, 0, stream>>>(attn, WoT + l * 65536, bo + l * 128,
                                                  gamma + l * 128, beta + l * 128, xh, outp);
  }
}

// Round 25
// 143.489 us; speedup vs baseline: 1.4208x; 1.0178x over previous
//
#include <hip/hip_runtime.h>
#include <hip/hip_bf16.h>

typedef __attribute__((ext_vector_type(8))) _Float16 f16x8;
typedef __attribute__((ext_vector_type(2))) _Float16 f16x2;
typedef __attribute__((ext_vector_type(8))) short short8;
typedef __attribute__((ext_vector_type(4))) short short4v;
typedef __attribute__((ext_vector_type(4))) float f32x4;

typedef const __attribute__((address_space(1))) unsigned int* gas_ptr;
typedef __attribute__((address_space(3))) unsigned int* las_ptr;
#define GLDS16(gp, lp) \
  __builtin_amdgcn_global_load_lds((gas_ptr)(gp), (las_ptr)(lp), 16, 0, 0)

#if __has_builtin(__builtin_amdgcn_fdot2)
#define FDOT2(a, b, c) __builtin_amdgcn_fdot2((a), (b), (c), false)
#else
__device__ __forceinline__ float FDOT2(f16x2 a, f16x2 b, float c) {
  return c + (float)a[0] * (float)b[0] + (float)a[1] * (float)b[1];
}
#endif

union h8u {
  f16x8 v;
  f16x2 h[4];
};

__device__ __forceinline__ short f2h(float f) {
  union { _Float16 h; short s; } u; u.h = (_Float16)f; return u.s;
}
__device__ __forceinline__ float h2f(short s) {
  union { short s; _Float16 h; } u; u.s = s; return (float)u.h;
}

// ------- init: weight transpose/cvt (blocks 0..1535) + input proj (rest) ----
__global__ __launch_bounds__(256) void k_init(const float* __restrict__ W,
                                              const float* __restrict__ Wo,
                                              const float* __restrict__ nf,
                                              const float* __restrict__ Wp,
                                              const float* __restrict__ bp,
                                              short* __restrict__ WT,
                                              short* __restrict__ WoT,
                                              short* __restrict__ xh) {
  if (blockIdx.x < 1536) {
    int idx = blockIdx.x * 256 + threadIdx.x;
    if (idx < 3 * 512 * 128) {
      int l = idx >> 16, rem = idx & 65535;
      int c = rem >> 7, k = rem & 127;
      int h = c >> 7, o = c & 127;
      WT[idx] = f2h(W[(((l * 4 + h) * 128 + k) << 7) + o]);
    } else {
      int j = idx - 3 * 512 * 128;
      int l = j >> 16, rem = j & 65535;
      int d = rem >> 9, c = rem & 511;
      WoT[j] = f2h(Wo[((l * 512 + c) << 7) + d]);
    }
  } else {
    int idx = (blockIdx.x - 1536) * 256 + threadIdx.x;
    int bn = idx >> 7, d = idx & 127;
    float acc = bp[d];
    const float* nr = nf + bn * 7;
#pragma unroll
    for (int i = 0; i < 7; ++i) acc += nr[i] * Wp[(i << 7) + d];
    xh[idx] = f2h(acc);
  }
}

// ---------------- head projection + fused s1/s2 ----------------
// BOTH tiles staged via global_load_lds: linear [r][64] LDS, pre-swizzled
// source chunk (lane&7)^(lane>>3), XOR slot on read (k_attn's proven pattern).
__global__ __launch_bounds__(256) void k_gemm_h(const short* __restrict__ xh,
                                                const short* __restrict__ WT,
                                                short* __restrict__ hT,
                                                const float* __restrict__ a1,
                                                const float* __restrict__ a2,
                                                float* __restrict__ s1g,
                                                float* __restrict__ s2g) {
  __shared__ __align__(16) short As[128 * 64];
  __shared__ __align__(16) short Bs[128 * 64];
  __shared__ float sred[2][2][128];
  const int t = threadIdx.x;
  const int bn0 = blockIdx.x << 7;
  const int head = blockIdx.y;
  const int c0 = head << 7;
  const int w = t >> 6, lane = t & 63, lr = lane & 15, lq = lane >> 4;
  const int wr = w >> 1, wc = w & 1;
  // glds sources: wave w covers rows [w*32, w*32+32) of each 128-row tile
  const int grow = (w << 5) + (lane >> 3);
  const int gcol = ((lane & 7) ^ (lane >> 3)) << 3;
  const short* gsrcA = xh + ((bn0 + grow) << 7) + gcol;
  const short* gsrcB = WT + ((c0 + grow) << 7) + gcol;
  f32x4 acc[4][4] = {};
  for (int k0 = 0; k0 < 128; k0 += 64) {
    {
      short* ldsbA = &As[(w << 5) << 6];
      short* ldsbB = &Bs[(w << 5) << 6];
#pragma unroll
      for (int i_ = 0; i_ < 4; ++i_) {
        GLDS16(gsrcA + ((i_ << 3) << 7) + k0, ldsbA + ((i_ << 3) << 6));
        GLDS16(gsrcB + ((i_ << 3) << 7) + k0, ldsbB + ((i_ << 3) << 6));
      }
    }
    __syncthreads();   // drains vmcnt: As and Bs fully resident
#pragma unroll
    for (int kk = 0; kk < 2; ++kk) {
      f16x8 a[4], b[4];
#pragma unroll
      for (int m = 0; m < 4; ++m) {
        const int r_ = wr * 64 + m * 16 + lr;
        const int slot_ = ((kk << 2) + lq) ^ (r_ & 7);
        a[m] = *(const f16x8*)(&As[(r_ << 6) + (slot_ << 3)]);
      }
#pragma unroll
      for (int n = 0; n < 4; ++n) {
        const int r_ = wc * 64 + n * 16 + lr;
        const int slot_ = ((kk << 2) + lq) ^ (r_ & 7);
        b[n] = *(const f16x8*)(&Bs[(r_ << 6) + (slot_ << 3)]);
      }
#pragma unroll
      for (int m = 0; m < 4; ++m)
#pragma unroll
        for (int n = 0; n < 4; ++n)
          acc[m][n] = __builtin_amdgcn_mfma_f32_16x16x32_f16(a[m], b[n], acc[m][n], 0, 0, 0);
    }
    __syncthreads();
  }
  const int b = bn0 >> 10;
  const int nb = bn0 & 1023;
  float a1v[4], a2v[4];
#pragma unroll
  for (int n = 0; n < 4; ++n) {
    int d = wc * 64 + n * 16 + lr;
    a1v[n] = a1[(head << 7) + d];
    a2v[n] = a2[(head << 7) + d];
  }
#pragma unroll
  for (int m = 0; m < 4; ++m)
#pragma unroll
    for (int r = 0; r < 4; ++r) {
      float v1 = 0.f, v2 = 0.f;
#pragma unroll
      for (int n = 0; n < 4; ++n) {
        v1 += acc[m][n][r] * a1v[n];
        v2 += acc[m][n][r] * a2v[n];
      }
#pragma unroll
      for (int off = 1; off < 16; off <<= 1) {
        v1 += __shfl_xor(v1, off);
        v2 += __shfl_xor(v2, off);
      }
      if (lr == 0) {
        int row = wr * 64 + m * 16 + (lq << 2) + r;
        sred[wc][0][row] = v1;
        sred[wc][1][row] = v2;
      }
    }
#pragma unroll
  for (int m = 0; m < 4; ++m) {
    int nrow = nb + wr * 64 + m * 16 + (lq << 2);
#pragma unroll
    for (int n = 0; n < 4; ++n) {
      int d = wc * 64 + n * 16 + lr;
      long base = ((long)((((b << 2) + head) << 7) + d) << 10) + nrow;
      short4v v;
      v[0] = f2h(acc[m][n][0]); v[1] = f2h(acc[m][n][1]);
      v[2] = f2h(acc[m][n][2]); v[3] = f2h(acc[m][n][3]);
      *(short4v*)(hT + base) = v;
    }
  }
  __syncthreads();
  {
    const int bh_ = (b << 2) + head;
    if (t < 128)
      s1g[(bh_ << 10) + nb + t] = sred[0][0][t] + sred[1][0][t];
    else
      s2g[(bh_ << 10) + nb + (t - 128)] = sred[0][1][t - 128] + sred[1][1][t - 128];
  }
}

// ---------------- attention (k_ef fused into prologue) ----------------
// grid (64 bh, 8 it). Wave owns 32-row strip (m=2) x full 128 d (n=8).
// 3 LDS buffers, prefetch distance 2, counted vmcnt(4), single barrier/iter.
__global__ __launch_bounds__(256) void k_attn(const short* __restrict__ hT,
                                              const float* __restrict__ s1,
                                              const float* __restrict__ s2g,
                                              short* __restrict__ attn) {
  __shared__ __align__(16) short Hs[3][128 * 64];
  __shared__ __align__(16) _Float16 Esh[1024];
  __shared__ __align__(16) _Float16 Fsh[1024];
  __shared__ float red[4];
  const int bh = blockIdx.x, it = blockIdx.y;
  const int i0 = it << 7;
  const int t = threadIdx.x;
  const int w = t >> 6, lane = t & 63, lr = lane & 15, lq = lane >> 4;

  const short* hTb = hT + ((long)bh << 17);
  const int grow = (w << 5) + (lane >> 3);
  const int gcol = ((lane & 7) ^ (lane >> 3)) << 3;
  const short* gsrc = hTb + ((long)grow << 10) + gcol;

#define STAGE(buf, J0)                                             \
  do {                                                             \
    short* ldsb = &Hs[buf][(w << 5) << 6];                         \
    _Pragma("unroll") for (int i_ = 0; i_ < 4; ++i_)               \
        GLDS16(gsrc + ((long)(i_ << 3) << 10) + (J0),              \
               ldsb + ((i_ << 3) << 6));                           \
  } while (0)

  STAGE(0, 0);
  STAGE(1, 64);

  // fused k_ef: max(s2) then E=exp(s2-max), F=exp(.2(s2-max)) into LDS
  f32x4 v2 = *(const f32x4*)&s2g[(bh << 10) + (t << 2)];
  {
    float mx = fmaxf(fmaxf(v2[0], v2[1]), fmaxf(v2[2], v2[3]));
#pragma unroll
    for (int off = 1; off < 64; off <<= 1) mx = fmaxf(mx, __shfl_xor(mx, off));
    if ((t & 63) == 0) red[t >> 6] = mx;
  }
  __syncthreads();
  const float smax = fmaxf(fmaxf(red[0], red[1]), fmaxf(red[2], red[3]));
  {
    short4v e, f;
#pragma unroll
    for (int q = 0; q < 4; ++q) {
      e[q] = f2h(__expf(v2[q] - smax));
      f[q] = f2h(__expf(0.2f * (v2[q] - smax)));
    }
    *(short4v*)&Esh[t << 2] = e;
    *(short4v*)&Fsh[t << 2] = f;
  }

  f16x8 Ai8[2], Bi8[2];
  const f16x2 one2 = {(_Float16)1.f, (_Float16)1.f};
  f16x8 dmask[2];
  float dsum[2] = {0.f, 0.f};
#pragma unroll
  for (int m = 0; m < 2; ++m) {
    const int rblk = (w << 5) + (m << 4) + lr;
    float s1v = s1[(bh << 10) + i0 + rblk];
    float x = s1v + smax;
    float mi = fmaxf(x, 0.2f * x);  // upper bound of row max (lrelu monotone)
    _Float16 A_ = (_Float16)__expf(x - mi);
    _Float16 B_ = (_Float16)__expf(0.2f * x - mi);
#pragma unroll
    for (int e = 0; e < 8; ++e) { Ai8[m][e] = A_; Bi8[m][e] = B_; }
    const int lqz = ((m << 1) + (lr >> 3)) & 3, ez = lr & 7;
#pragma unroll
    for (int e = 0; e < 8; ++e)
      dmask[m][e] = (lq == lqz && e == ez) ? (_Float16)0.f : (_Float16)1.f;
  }
  const int jtd = (it << 1) + (w >> 1);  // wave-uniform diagonal j-tile
  const int kkd = w & 1;                 // wave-uniform diag k-half
  f32x4 acc[2][8] = {};
  __syncthreads();  // prologue: bufs 0,1 + E/F all resident

#define TILE(buf, jt, DIAG)                                                    \
  do {                                                                         \
    _Pragma("unroll") for (int kk = 0; kk < 2; ++kk) {                         \
      const int ebase = ((jt) << 6) + (kk << 5) + (lq << 3);                   \
      f16x8 ev8 = *(const f16x8*)&Esh[ebase];                                  \
      f16x8 fv8 = *(const f16x8*)&Fsh[ebase];                                  \
      f16x8 bf[8];                                                             \
      _Pragma("unroll") for (int n = 0; n < 8; ++n) {                          \
        const int r_ = (n << 4) + lr;                                          \
        const int slot_ = ((kk << 2) + lq) ^ (r_ & 7);                         \
        bf[n] = *(const f16x8*)(&Hs[buf][(r_ << 6) + (slot_ << 3)]);           \
      }                                                                        \
      f16x8 af[2];                                                             \
      _Pragma("unroll") for (int m = 0; m < 2; ++m) {                          \
        f16x8 pm = __builtin_elementwise_max(Ai8[m] * ev8, Bi8[m] * fv8);      \
        if ((DIAG) && kk == kkd) pm = pm * dmask[m];                           \
        af[m] = pm;                                                            \
        h8u u_; u_.v = pm;                                                     \
        _Pragma("unroll") for (int p = 0; p < 4; ++p)                          \
            dsum[m] = FDOT2(u_.h[p], one2, dsum[m]);                           \
      }                                                                        \
      _Pragma("unroll") for (int m = 0; m < 2; ++m)                            \
        _Pragma("unroll") for (int n = 0; n < 8; ++n)                          \
            acc[m][n] = __builtin_amdgcn_mfma_f32_16x16x32_f16(                \
                af[m], bf[n], acc[m][n], 0, 0, 0);                             \
    }                                                                          \
  } while (0)

  int cur = 0;
#pragma unroll 1
  for (int jt = 0; jt < 16; ++jt) {
    if (jt < 15) {
      asm volatile("s_waitcnt vmcnt(4)" ::: "memory");  // own tile-jt loads in
    } else {
      asm volatile("s_waitcnt vmcnt(0)" ::: "memory");
    }
    __builtin_amdgcn_s_barrier();   // all waves: buf[cur] fully staged AND
                                    // all waves done reading buf[(jt+2)%3]
    if (jt < 14) STAGE((cur == 0 ? 2 : cur - 1), (jt + 2) << 6);
    TILE(cur, jt, jt == jtd);
    cur = (cur == 2) ? 0 : cur + 1;
  }

  const int b = bh >> 2, head = bh & 3;
#pragma unroll
  for (int m = 0; m < 2; ++m) {
    float s = dsum[m];
    s += __shfl_xor(s, 16);
    s += __shfl_xor(s, 32);  // all lq-replica lanes hold the row sum
    float rs = 1.f / s;
    f32x4 d4;
#pragma unroll
    for (int q = 0; q < 4; ++q)
      d4[q] = __shfl(rs, (lane & 48) | ((lq << 2) + q));
    int irow = i0 + (w << 5) + (m << 4) + (lq << 2);
#pragma unroll
    for (int n = 0; n < 8; ++n) {
      int d = (n << 4) + lr;
      long base = ((long)((b << 10) + irow) << 9) + (head << 7) + d;
      attn[base] = f2h(acc[m][n][0] * d4[0]);
      attn[base + 512] = f2h(acc[m][n][1] * d4[1]);
      attn[base + 1024] = f2h(acc[m][n][2] * d4[2]);
      attn[base + 1536] = f2h(acc[m][n][3] * d4[3]);
    }
  }
#undef STAGE
#undef TILE
}

// ---------------- out-proj + bias (+residual from f16 xh) + LN (+relu) -----
// BOTH tiles staged via global_load_lds (linear [r][64] + XOR-slot reads).
template <int HAS_RES, int DO_RELU, int WRITE_OUT>
__global__ __launch_bounds__(256) void k_outproj(const short* __restrict__ attn,
                                                 const short* __restrict__ WoT,
                                                 const float* __restrict__ bo,
                                                 const float* __restrict__ gamma,
                                                 const float* __restrict__ beta,
                                                 short* __restrict__ xh,
                                                 float* __restrict__ outp) {
  __shared__ __align__(16) short As[32 * 64];
  __shared__ __align__(16) short Bs[128 * 64];
  __shared__ float sredS[2][32], sredQ[2][32];
  const int t = threadIdx.x;
  const int bn0 = blockIdx.x << 5;
  const int w = t >> 6, lane = t & 63, lr = lane & 15, lq = lane >> 4;
  const int wm = w & 1, wn = w >> 1;
  f32x4 acc[4] = {};
  const int gcol = ((lane & 7) ^ (lane >> 3)) << 3;
  // A: 32-row tile, wave w covers rows [w*8, w*8+8): 1 GLDS16/lane per k0
  const int growA = (w << 3) + (lane >> 3);
  const short* gsrcA = attn + ((long)(bn0 + growA) << 9) + gcol;
  // B: 128-row tile, wave w covers rows [w*32, w*32+32): 4 GLDS16/lane per k0
  const int growB = (w << 5) + (lane >> 3);
  const short* gsrcB = WoT + (growB << 9) + gcol;
  for (int k0 = 0; k0 < 512; k0 += 64) {
    {
      GLDS16(gsrcA + k0, &As[(w << 3) << 6]);
      short* ldsbB = &Bs[(w << 5) << 6];
#pragma unroll
      for (int i_ = 0; i_ < 4; ++i_)
        GLDS16(gsrcB + ((i_ << 3) << 9) + k0, ldsbB + ((i_ << 3) << 6));
    }
    __syncthreads();   // drains vmcnt: As and Bs fully resident
#pragma unroll
    for (int kk = 0; kk < 2; ++kk) {
      const int rA = (wm << 4) + lr;
      const int slotA = ((kk << 2) + lq) ^ (rA & 7);
      f16x8 a = *(const f16x8*)(&As[(rA << 6) + (slotA << 3)]);
#pragma unroll
      for (int nn = 0; nn < 4; ++nn) {
        const int r_ = (wn << 6) + (nn << 4) + lr;
        const int slot_ = ((kk << 2) + lq) ^ (r_ & 7);
        f16x8 b = *(const f16x8*)(&Bs[(r_ << 6) + (slot_ << 3)]);
        acc[nn] = __builtin_amdgcn_mfma_f32_16x16x32_f16(a, b, acc[nn], 0, 0, 0);
      }
    }
    __syncthreads();
  }
  float v[4][4], gam[4], bet[4];
#pragma unroll
  for (int nn = 0; nn < 4; ++nn) {
    int d = (wn << 6) + (nn << 4) + lr;
    float bv = bo[d];
    gam[nn] = gamma[d];
    bet[nn] = beta[d];
#pragma unroll
    for (int r = 0; r < 4; ++r) {
      float x = acc[nn][r] + bv;
      if (HAS_RES) x += h2f(xh[((bn0 + (wm << 4) + (lq << 2) + r) << 7) + d]);
      v[nn][r] = x;
    }
  }
#pragma unroll
  for (int r = 0; r < 4; ++r) {
    float s = 0.f, q = 0.f;
#pragma unroll
    for (int nn = 0; nn < 4; ++nn) { s += v[nn][r]; q += v[nn][r] * v[nn][r]; }
#pragma unroll
    for (int mk = 1; mk < 16; mk <<= 1) { s += __shfl_xor(s, mk); q += __shfl_xor(q, mk); }
    if (lr == 0) {
      int row = (wm << 4) + (lq << 2) + r;
      sredS[wn][row] = s;
      sredQ[wn][row] = q;
    }
  }
  __syncthreads();
#pragma unroll
  for (int r = 0; r < 4; ++r) {
    int rloc = (wm << 4) + (lq << 2) + r;
    float S = sredS[0][rloc] + sredS[1][rloc];
    float Q = sredQ[0][rloc] + sredQ[1][rloc];
    float mean = S * 0.0078125f;
    float var = Q * 0.0078125f - mean * mean;
    float rstd = rsqrtf(var + 1e-5f);
    int row = bn0 + rloc;
#pragma unroll
    for (int nn = 0; nn < 4; ++nn) {
      int d = (wn << 6) + (nn << 4) + lr;
      float o = (v[nn][r] - mean) * rstd * gam[nn] + bet[nn];
      if (DO_RELU) o = fmaxf(o, 0.f);
      if (WRITE_OUT) outp[(row << 7) + d] = o;
      else xh[(row << 7) + d] = f2h(o);
    }
  }
}

extern "C" void kernel_launch(void* const* d_in, const int* in_sizes, int n_in,
                              void* d_out, int out_size, void* d_ws, size_t ws_size,
                              hipStream_t stream) {
  const float* nf = (const float*)d_in[0];
  const float* Wp = (const float*)d_in[1];
  const float* bp = (const float*)d_in[2];
  const float* W = (const float*)d_in[3];
  const float* a1 = (const float*)d_in[4];
  const float* a2 = (const float*)d_in[5];
  const float* Wo = (const float*)d_in[6];
  const float* bo = (const float*)d_in[7];
  const float* gamma = (const float*)d_in[8];
  const float* beta = (const float*)d_in[9];
  float* outp = (float*)d_out;

  char* ws = (char*)d_ws;
  short* xh = (short*)(ws);                                    // 4 MB
  short* hT = (short*)(ws + (4ll << 20));                      // 16 MB
  short* attn = (short*)(ws + (20ll << 20));                   // 16 MB
  float* s1 = (float*)(ws + (36ll << 20));                     // 256 KB
  float* s2g = (float*)(ws + (36ll << 20) + (256ll << 10));    // 256 KB
  short* WT = (short*)(ws + (37ll << 20));                     // 384 KB
  short* WoT = (short*)(ws + (37ll << 20) + 393216);           // 384 KB

  k_init<<<9728, 256, 0, stream>>>(W, Wo, nf, Wp, bp, WT, WoT, xh);
  for (int l = 0; l < 3; ++l) {
    k_gemm_h<<<dim3(128, 4), 256, 0, stream>>>(xh, WT + l * 65536, hT,
                                               a1 + l * 512, a2 + l * 512, s1, s2g);
    k_attn<<<dim3(64, 8), 256, 0, stream>>>(hT, s1, s2g, attn);
    if (l == 0)
      k_outproj<0, 1, 0><<<512, 256, 0, stream>>>(attn, WoT + l * 65536, bo + l * 128,
                                                  gamma + l * 128, beta + l * 128, xh, outp);
    else if (l == 1)
      k_outproj<1, 1, 0><<<512, 256, 0, stream>>>(attn, WoT + l * 65536, bo + l * 128,
                                                  gamma + l * 128, beta + l * 128, xh, outp);
    else
      k_outproj<1, 0, 1><<<512, 256, 0, stream>>>(attn, WoT + l * 65536, bo + l * 128,
                                                  gamma + l * 128, beta + l * 128, xh, outp);
  }
}

// Round 26
// 142.982 us; speedup vs baseline: 1.4258x; 1.0035x over previous
//
#include <hip/hip_runtime.h>
#include <hip/hip_bf16.h>

typedef __attribute__((ext_vector_type(8))) _Float16 f16x8;
typedef __attribute__((ext_vector_type(2))) _Float16 f16x2;
typedef __attribute__((ext_vector_type(8))) short short8;
typedef __attribute__((ext_vector_type(4))) short short4v;
typedef __attribute__((ext_vector_type(4))) float f32x4;

typedef const __attribute__((address_space(1))) unsigned int* gas_ptr;
typedef __attribute__((address_space(3))) unsigned int* las_ptr;
#define GLDS16(gp, lp) \
  __builtin_amdgcn_global_load_lds((gas_ptr)(gp), (las_ptr)(lp), 16, 0, 0)

#if __has_builtin(__builtin_amdgcn_fdot2)
#define FDOT2(a, b, c) __builtin_amdgcn_fdot2((a), (b), (c), false)
#else
__device__ __forceinline__ float FDOT2(f16x2 a, f16x2 b, float c) {
  return c + (float)a[0] * (float)b[0] + (float)a[1] * (float)b[1];
}
#endif

union h8u {
  f16x8 v;
  f16x2 h[4];
};

__device__ __forceinline__ short f2h(float f) {
  union { _Float16 h; short s; } u; u.h = (_Float16)f; return u.s;
}
__device__ __forceinline__ float h2f(short s) {
  union { short s; _Float16 h; } u; u.s = s; return (float)u.h;
}

// ------- init: weight transpose/cvt (blocks 0..1535) + input proj (rest) ----
__global__ __launch_bounds__(256) void k_init(const float* __restrict__ W,
                                              const float* __restrict__ Wo,
                                              const float* __restrict__ nf,
                                              const float* __restrict__ Wp,
                                              const float* __restrict__ bp,
                                              short* __restrict__ WT,
                                              short* __restrict__ WoT,
                                              short* __restrict__ xh) {
  if (blockIdx.x < 1536) {
    int idx = blockIdx.x * 256 + threadIdx.x;
    if (idx < 3 * 512 * 128) {
      int l = idx >> 16, rem = idx & 65535;
      int c = rem >> 7, k = rem & 127;
      int h = c >> 7, o = c & 127;
      WT[idx] = f2h(W[(((l * 4 + h) * 128 + k) << 7) + o]);
    } else {
      int j = idx - 3 * 512 * 128;
      int l = j >> 16, rem = j & 65535;
      int d = rem >> 9, c = rem & 511;
      WoT[j] = f2h(Wo[((l * 512 + c) << 7) + d]);
    }
  } else {
    int idx = (blockIdx.x - 1536) * 256 + threadIdx.x;
    int bn = idx >> 7, d = idx & 127;
    float acc = bp[d];
    const float* nr = nf + bn * 7;
#pragma unroll
    for (int i = 0; i < 7; ++i) acc += nr[i] * Wp[(i << 7) + d];
    xh[idx] = f2h(acc);
  }
}

// ---------------- head projection + fused s1/s2 ----------------
// Both K-tiles glds-staged up front into double buffers; counted vmcnt so
// tile-1 loads fly under tile-0 compute (k_attn's proven pattern).
__global__ __launch_bounds__(256) void k_gemm_h(const short* __restrict__ xh,
                                                const short* __restrict__ WT,
                                                short* __restrict__ hT,
                                                const float* __restrict__ a1,
                                                const float* __restrict__ a2,
                                                float* __restrict__ s1g,
                                                float* __restrict__ s2g) {
  __shared__ __align__(16) short As[2][128 * 64];
  __shared__ __align__(16) short Bs[2][128 * 64];
  __shared__ float sred[2][2][128];
  const int t = threadIdx.x;
  const int bn0 = blockIdx.x << 7;
  const int head = blockIdx.y;
  const int c0 = head << 7;
  const int w = t >> 6, lane = t & 63, lr = lane & 15, lq = lane >> 4;
  const int wr = w >> 1, wc = w & 1;
  const int grow = (w << 5) + (lane >> 3);
  const int gcol = ((lane & 7) ^ (lane >> 3)) << 3;
  const short* gsrcA = xh + ((bn0 + grow) << 7) + gcol;
  const short* gsrcB = WT + ((c0 + grow) << 7) + gcol;
  f32x4 acc[4][4] = {};
  // prologue: stage both K-tiles (8 glds/wave each)
#pragma unroll
  for (int kb = 0; kb < 2; ++kb) {
    short* ldsbA = &As[kb][(w << 5) << 6];
    short* ldsbB = &Bs[kb][(w << 5) << 6];
#pragma unroll
    for (int i_ = 0; i_ < 4; ++i_) {
      GLDS16(gsrcA + ((i_ << 3) << 7) + (kb << 6), ldsbA + ((i_ << 3) << 6));
      GLDS16(gsrcB + ((i_ << 3) << 7) + (kb << 6), ldsbB + ((i_ << 3) << 6));
    }
  }
#pragma unroll 1
  for (int kb = 0; kb < 2; ++kb) {
    if (kb == 0)
      asm volatile("s_waitcnt vmcnt(8)" ::: "memory");  // buf0's 8 done
    else
      asm volatile("s_waitcnt vmcnt(0)" ::: "memory");
    __builtin_amdgcn_s_barrier();   // all waves' loads for buf kb resident
#pragma unroll
    for (int kk = 0; kk < 2; ++kk) {
      f16x8 a[4], b[4];
#pragma unroll
      for (int m = 0; m < 4; ++m) {
        const int r_ = wr * 64 + m * 16 + lr;
        const int slot_ = ((kk << 2) + lq) ^ (r_ & 7);
        a[m] = *(const f16x8*)(&As[kb][(r_ << 6) + (slot_ << 3)]);
      }
#pragma unroll
      for (int n = 0; n < 4; ++n) {
        const int r_ = wc * 64 + n * 16 + lr;
        const int slot_ = ((kk << 2) + lq) ^ (r_ & 7);
        b[n] = *(const f16x8*)(&Bs[kb][(r_ << 6) + (slot_ << 3)]);
      }
#pragma unroll
      for (int m = 0; m < 4; ++m)
#pragma unroll
        for (int n = 0; n < 4; ++n)
          acc[m][n] = __builtin_amdgcn_mfma_f32_16x16x32_f16(a[m], b[n], acc[m][n], 0, 0, 0);
    }
  }
  const int b = bn0 >> 10;
  const int nb = bn0 & 1023;
  float a1v[4], a2v[4];
#pragma unroll
  for (int n = 0; n < 4; ++n) {
    int d = wc * 64 + n * 16 + lr;
    a1v[n] = a1[(head << 7) + d];
    a2v[n] = a2[(head << 7) + d];
  }
#pragma unroll
  for (int m = 0; m < 4; ++m)
#pragma unroll
    for (int r = 0; r < 4; ++r) {
      float v1 = 0.f, v2 = 0.f;
#pragma unroll
      for (int n = 0; n < 4; ++n) {
        v1 += acc[m][n][r] * a1v[n];
        v2 += acc[m][n][r] * a2v[n];
      }
#pragma unroll
      for (int off = 1; off < 16; off <<= 1) {
        v1 += __shfl_xor(v1, off);
        v2 += __shfl_xor(v2, off);
      }
      if (lr == 0) {
        int row = wr * 64 + m * 16 + (lq << 2) + r;
        sred[wc][0][row] = v1;
        sred[wc][1][row] = v2;
      }
    }
#pragma unroll
  for (int m = 0; m < 4; ++m) {
    int nrow = nb + wr * 64 + m * 16 + (lq << 2);
#pragma unroll
    for (int n = 0; n < 4; ++n) {
      int d = wc * 64 + n * 16 + lr;
      long base = ((long)((((b << 2) + head) << 7) + d) << 10) + nrow;
      short4v v;
      v[0] = f2h(acc[m][n][0]); v[1] = f2h(acc[m][n][1]);
      v[2] = f2h(acc[m][n][2]); v[3] = f2h(acc[m][n][3]);
      *(short4v*)(hT + base) = v;
    }
  }
  __syncthreads();
  {
    const int bh_ = (b << 2) + head;
    if (t < 128)
      s1g[(bh_ << 10) + nb + t] = sred[0][0][t] + sred[1][0][t];
    else
      s2g[(bh_ << 10) + nb + (t - 128)] = sred[0][1][t - 128] + sred[1][1][t - 128];
  }
}

// ---------------- attention (k_ef fused into prologue) ----------------
// grid (64 bh, 8 it). Wave owns 32-row strip (m=2) x full 128 d (n=8).
// 3 LDS buffers, prefetch distance 2, counted vmcnt(4), single barrier/iter.
__global__ __launch_bounds__(256) void k_attn(const short* __restrict__ hT,
                                              const float* __restrict__ s1,
                                              const float* __restrict__ s2g,
                                              short* __restrict__ attn) {
  __shared__ __align__(16) short Hs[3][128 * 64];
  __shared__ __align__(16) _Float16 Esh[1024];
  __shared__ __align__(16) _Float16 Fsh[1024];
  __shared__ float red[4];
  const int bh = blockIdx.x, it = blockIdx.y;
  const int i0 = it << 7;
  const int t = threadIdx.x;
  const int w = t >> 6, lane = t & 63, lr = lane & 15, lq = lane >> 4;

  const short* hTb = hT + ((long)bh << 17);
  const int grow = (w << 5) + (lane >> 3);
  const int gcol = ((lane & 7) ^ (lane >> 3)) << 3;
  const short* gsrc = hTb + ((long)grow << 10) + gcol;

#define STAGE(buf, J0)                                             \
  do {                                                             \
    short* ldsb = &Hs[buf][(w << 5) << 6];                         \
    _Pragma("unroll") for (int i_ = 0; i_ < 4; ++i_)               \
        GLDS16(gsrc + ((long)(i_ << 3) << 10) + (J0),              \
               ldsb + ((i_ << 3) << 6));                           \
  } while (0)

  STAGE(0, 0);
  STAGE(1, 64);

  // fused k_ef: max(s2) then E=exp(s2-max), F=exp(.2(s2-max)) into LDS
  f32x4 v2 = *(const f32x4*)&s2g[(bh << 10) + (t << 2)];
  {
    float mx = fmaxf(fmaxf(v2[0], v2[1]), fmaxf(v2[2], v2[3]));
#pragma unroll
    for (int off = 1; off < 64; off <<= 1) mx = fmaxf(mx, __shfl_xor(mx, off));
    if ((t & 63) == 0) red[t >> 6] = mx;
  }
  __syncthreads();
  const float smax = fmaxf(fmaxf(red[0], red[1]), fmaxf(red[2], red[3]));
  {
    short4v e, f;
#pragma unroll
    for (int q = 0; q < 4; ++q) {
      e[q] = f2h(__expf(v2[q] - smax));
      f[q] = f2h(__expf(0.2f * (v2[q] - smax)));
    }
    *(short4v*)&Esh[t << 2] = e;
    *(short4v*)&Fsh[t << 2] = f;
  }

  f16x8 Ai8[2], Bi8[2];
  const f16x2 one2 = {(_Float16)1.f, (_Float16)1.f};
  f16x8 dmask[2];
  float dsum[2] = {0.f, 0.f};
#pragma unroll
  for (int m = 0; m < 2; ++m) {
    const int rblk = (w << 5) + (m << 4) + lr;
    float s1v = s1[(bh << 10) + i0 + rblk];
    float x = s1v + smax;
    float mi = fmaxf(x, 0.2f * x);  // upper bound of row max (lrelu monotone)
    _Float16 A_ = (_Float16)__expf(x - mi);
    _Float16 B_ = (_Float16)__expf(0.2f * x - mi);
#pragma unroll
    for (int e = 0; e < 8; ++e) { Ai8[m][e] = A_; Bi8[m][e] = B_; }
    const int lqz = ((m << 1) + (lr >> 3)) & 3, ez = lr & 7;
#pragma unroll
    for (int e = 0; e < 8; ++e)
      dmask[m][e] = (lq == lqz && e == ez) ? (_Float16)0.f : (_Float16)1.f;
  }
  const int jtd = (it << 1) + (w >> 1);  // wave-uniform diagonal j-tile
  const int kkd = w & 1;                 // wave-uniform diag k-half
  f32x4 acc[2][8] = {};
  __syncthreads();  // prologue: bufs 0,1 + E/F all resident

#define TILE(buf, jt, DIAG)                                                    \
  do {                                                                         \
    _Pragma("unroll") for (int kk = 0; kk < 2; ++kk) {                         \
      const int ebase = ((jt) << 6) + (kk << 5) + (lq << 3);                   \
      f16x8 ev8 = *(const f16x8*)&Esh[ebase];                                  \
      f16x8 fv8 = *(const f16x8*)&Fsh[ebase];                                  \
      f16x8 bf[8];                                                             \
      _Pragma("unroll") for (int n = 0; n < 8; ++n) {                          \
        const int r_ = (n << 4) + lr;                                          \
        const int slot_ = ((kk << 2) + lq) ^ (r_ & 7);                         \
        bf[n] = *(const f16x8*)(&Hs[buf][(r_ << 6) + (slot_ << 3)]);           \
      }                                                                        \
      f16x8 af[2];                                                             \
      _Pragma("unroll") for (int m = 0; m < 2; ++m) {                          \
        f16x8 pm = __builtin_elementwise_max(Ai8[m] * ev8, Bi8[m] * fv8);      \
        if ((DIAG) && kk == kkd) pm = pm * dmask[m];                           \
        af[m] = pm;                                                            \
        h8u u_; u_.v = pm;                                                     \
        _Pragma("unroll") for (int p = 0; p < 4; ++p)                          \
            dsum[m] = FDOT2(u_.h[p], one2, dsum[m]);                           \
      }                                                                        \
      _Pragma("unroll") for (int m = 0; m < 2; ++m)                            \
        _Pragma("unroll") for (int n = 0; n < 8; ++n)                          \
            acc[m][n] = __builtin_amdgcn_mfma_f32_16x16x32_f16(                \
                af[m], bf[n], acc[m][n], 0, 0, 0);                             \
    }                                                                          \
  } while (0)

  int cur = 0;
#pragma unroll 1
  for (int jt = 0; jt < 16; ++jt) {
    if (jt < 15) {
      asm volatile("s_waitcnt vmcnt(4)" ::: "memory");  // own tile-jt loads in
    } else {
      asm volatile("s_waitcnt vmcnt(0)" ::: "memory");
    }
    __builtin_amdgcn_s_barrier();   // all waves: buf[cur] fully staged AND
                                    // all waves done reading buf[(jt+2)%3]
    if (jt < 14) STAGE((cur == 0 ? 2 : cur - 1), (jt + 2) << 6);
    TILE(cur, jt, jt == jtd);
    cur = (cur == 2) ? 0 : cur + 1;
  }

  const int b = bh >> 2, head = bh & 3;
#pragma unroll
  for (int m = 0; m < 2; ++m) {
    float s = dsum[m];
    s += __shfl_xor(s, 16);
    s += __shfl_xor(s, 32);  // all lq-replica lanes hold the row sum
    float rs = 1.f / s;
    f32x4 d4;
#pragma unroll
    for (int q = 0; q < 4; ++q)
      d4[q] = __shfl(rs, (lane & 48) | ((lq << 2) + q));
    int irow = i0 + (w << 5) + (m << 4) + (lq << 2);
#pragma unroll
    for (int n = 0; n < 8; ++n) {
      int d = (n << 4) + lr;
      long base = ((long)((b << 10) + irow) << 9) + (head << 7) + d;
      attn[base] = f2h(acc[m][n][0] * d4[0]);
      attn[base + 512] = f2h(acc[m][n][1] * d4[1]);
      attn[base + 1024] = f2h(acc[m][n][2] * d4[2]);
      attn[base + 1536] = f2h(acc[m][n][3] * d4[3]);
    }
  }
#undef STAGE
#undef TILE
}

// ---------------- out-proj + bias (+residual from f16 xh) + LN (+relu) -----
// 3-buffer glds pipeline, prefetch distance 2, counted vmcnt(5) (1 A + 4 B
// glds per wave per stage), single barrier/iter (k_attn's proven loop).
template <int HAS_RES, int DO_RELU, int WRITE_OUT>
__global__ __launch_bounds__(256) void k_outproj(const short* __restrict__ attn,
                                                 const short* __restrict__ WoT,
                                                 const float* __restrict__ bo,
                                                 const float* __restrict__ gamma,
                                                 const float* __restrict__ beta,
                                                 short* __restrict__ xh,
                                                 float* __restrict__ outp) {
  __shared__ __align__(16) short As3[3][32 * 64];
  __shared__ __align__(16) short Bs3[3][128 * 64];
  __shared__ float sredS[2][32], sredQ[2][32];
  const int t = threadIdx.x;
  const int bn0 = blockIdx.x << 5;
  const int w = t >> 6, lane = t & 63, lr = lane & 15, lq = lane >> 4;
  const int wm = w & 1, wn = w >> 1;
  f32x4 acc[4] = {};
  const int gcol = ((lane & 7) ^ (lane >> 3)) << 3;
  const int growA = (w << 3) + (lane >> 3);
  const short* gsrcA = attn + ((long)(bn0 + growA) << 9) + gcol;
  const int growB = (w << 5) + (lane >> 3);
  const short* gsrcB = WoT + (growB << 9) + gcol;

#define OSTAGE(buf, K0)                                            \
  do {                                                             \
    GLDS16(gsrcA + (K0), &As3[buf][(w << 3) << 6]);                \
    short* ldsbB = &Bs3[buf][(w << 5) << 6];                       \
    _Pragma("unroll") for (int i_ = 0; i_ < 4; ++i_)               \
        GLDS16(gsrcB + ((i_ << 3) << 9) + (K0),                    \
               ldsbB + ((i_ << 3) << 6));                          \
  } while (0)

  OSTAGE(0, 0);
  OSTAGE(1, 64);
  int cur = 0;
#pragma unroll 1
  for (int jt = 0; jt < 8; ++jt) {
    if (jt < 7) {
      asm volatile("s_waitcnt vmcnt(5)" ::: "memory");  // own tile-jt loads in
    } else {
      asm volatile("s_waitcnt vmcnt(0)" ::: "memory");
    }
    __builtin_amdgcn_s_barrier();   // buf[cur] staged; buf[(jt+2)%3] free
    if (jt < 6) OSTAGE((cur == 0 ? 2 : cur - 1), (jt + 2) << 6);
#pragma unroll
    for (int kk = 0; kk < 2; ++kk) {
      const int rA = (wm << 4) + lr;
      const int slotA = ((kk << 2) + lq) ^ (rA & 7);
      f16x8 a = *(const f16x8*)(&As3[cur][(rA << 6) + (slotA << 3)]);
#pragma unroll
      for (int nn = 0; nn < 4; ++nn) {
        const int r_ = (wn << 6) + (nn << 4) + lr;
        const int slot_ = ((kk << 2) + lq) ^ (r_ & 7);
        f16x8 b = *(const f16x8*)(&Bs3[cur][(r_ << 6) + (slot_ << 3)]);
        acc[nn] = __builtin_amdgcn_mfma_f32_16x16x32_f16(a, b, acc[nn], 0, 0, 0);
      }
    }
    cur = (cur == 2) ? 0 : cur + 1;
  }
#undef OSTAGE
  float v[4][4], gam[4], bet[4];
#pragma unroll
  for (int nn = 0; nn < 4; ++nn) {
    int d = (wn << 6) + (nn << 4) + lr;
    float bv = bo[d];
    gam[nn] = gamma[d];
    bet[nn] = beta[d];
#pragma unroll
    for (int r = 0; r < 4; ++r) {
      float x = acc[nn][r] + bv;
      if (HAS_RES) x += h2f(xh[((bn0 + (wm << 4) + (lq << 2) + r) << 7) + d]);
      v[nn][r] = x;
    }
  }
#pragma unroll
  for (int r = 0; r < 4; ++r) {
    float s = 0.f, q = 0.f;
#pragma unroll
    for (int nn = 0; nn < 4; ++nn) { s += v[nn][r]; q += v[nn][r] * v[nn][r]; }
#pragma unroll
    for (int mk = 1; mk < 16; mk <<= 1) { s += __shfl_xor(s, mk); q += __shfl_xor(q, mk); }
    if (lr == 0) {
      int row = (wm << 4) + (lq << 2) + r;
      sredS[wn][row] = s;
      sredQ[wn][row] = q;
    }
  }
  __syncthreads();
#pragma unroll
  for (int r = 0; r < 4; ++r) {
    int rloc = (wm << 4) + (lq << 2) + r;
    float S = sredS[0][rloc] + sredS[1][rloc];
    float Q = sredQ[0][rloc] + sredQ[1][rloc];
    float mean = S * 0.0078125f;
    float var = Q * 0.0078125f - mean * mean;
    float rstd = rsqrtf(var + 1e-5f);
    int row = bn0 + rloc;
#pragma unroll
    for (int nn = 0; nn < 4; ++nn) {
      int d = (wn << 6) + (nn << 4) + lr;
      float o = (v[nn][r] - mean) * rstd * gam[nn] + bet[nn];
      if (DO_RELU) o = fmaxf(o, 0.f);
      if (WRITE_OUT) outp[(row << 7) + d] = o;
      else xh[(row << 7) + d] = f2h(o);
    }
  }
}

extern "C" void kernel_launch(void* const* d_in, const int* in_sizes, int n_in,
                              void* d_out, int out_size, void* d_ws, size_t ws_size,
                              hipStream_t stream) {
  const float* nf = (const float*)d_in[0];
  const float* Wp = (const float*)d_in[1];
  const float* bp = (const float*)d_in[2];
  const float* W = (const float*)d_in[3];
  const float* a1 = (const float*)d_in[4];
  const float* a2 = (const float*)d_in[5];
  const float* Wo = (const float*)d_in[6];
  const float* bo = (const float*)d_in[7];
  const float* gamma = (const float*)d_in[8];
  const float* beta = (const float*)d_in[9];
  float* outp = (float*)d_out;

  char* ws = (char*)d_ws;
  short* xh = (short*)(ws);                                    // 4 MB
  short* hT = (short*)(ws + (4ll << 20));                      // 16 MB
  short* attn = (short*)(ws + (20ll << 20));                   // 16 MB
  float* s1 = (float*)(ws + (36ll << 20));                     // 256 KB
  float* s2g = (float*)(ws + (36ll << 20) + (256ll << 10));    // 256 KB
  short* WT = (short*)(ws + (37ll << 20));                     // 384 KB
  short* WoT = (short*)(ws + (37ll << 20) + 393216);           // 384 KB

  k_init<<<9728, 256, 0, stream>>>(W, Wo, nf, Wp, bp, WT, WoT, xh);
  for (int l = 0; l < 3; ++l) {
    k_gemm_h<<<dim3(128, 4), 256, 0, stream>>>(xh, WT + l * 65536, hT,
                                               a1 + l * 512, a2 + l * 512, s1, s2g);
    k_attn<<<dim3(64, 8), 256, 0, stream>>>(hT, s1, s2g, attn);
    if (l == 0)
      k_outproj<0, 1, 0><<<512, 256, 0, stream>>>(attn, WoT + l * 65536, bo + l * 128,
                                                  gamma + l * 128, beta + l * 128, xh, outp);
    else if (l == 1)
      k_outproj<1, 1, 0><<<512, 256, 0, stream>>>(attn, WoT + l * 65536, bo + l * 128,
                                                  gamma + l * 128, beta + l * 128, xh, outp);
    else
      k_outproj<1, 0, 1><<<512, 256, 0, stream>>>(attn, WoT + l * 65536, bo + l * 128,
                                                  gamma + l * 128, beta + l * 128, xh, outp);
  }
}